// Round 17
// baseline (206.418 us; speedup 1.0000x reference)
//
#include <hip/hip_runtime.h>
#include <hip/hip_bf16.h>
#include <math.h>

#define BB 8
#define NN 1024
#define CC 768
#define HH 8
#define HD 96
#define EE 24
#define NT (BB*NN)          // 8192 tokens
#define NSLOT (NT*HH)       // 65536 (token,h) slots
#define EC (EE*HD)          // 2304
#define CAPQ 8192           // per-expert bucket capacity
#define ASCALE 0.10206207261596575f  // 96^-0.5
#define AL2 0.14724446f              // ASCALE * log2(e)
#define DEFER_THR 11.5415603f        // 8 * log2(e)

typedef unsigned short u16;
typedef unsigned char u8;
typedef unsigned int u32;
typedef unsigned long long u64;
typedef __attribute__((ext_vector_type(8))) short s16x8;
typedef __attribute__((ext_vector_type(4))) float f32x4;
typedef __attribute__((ext_vector_type(16))) float f32x16;

__device__ __forceinline__ u16 f2b(float f) {  // RNE float->bf16 bits
  unsigned u = __builtin_bit_cast(unsigned, f);
  unsigned r = u + 0x7fffu + ((u >> 16) & 1u);
  return (u16)(r >> 16);
}

__device__ __forceinline__ float fexp2(float x) {  // native 2^x
  float r; asm("v_exp_f32 %0, %1" : "=v"(r) : "v"(x)); return r;
}

__device__ __forceinline__ u32 cvtpk(float a, float b) {  // HW RNE pack
  u32 d; asm("v_cvt_pk_bf16_f32 %0, %1, %2" : "=v"(d) : "v"(a), "v"(b)); return d;
}

__device__ __forceinline__ void gload16(const u16* g, u16* lds) {
  __builtin_amdgcn_global_load_lds(
      (const __attribute__((address_space(1))) void*)g,
      (__attribute__((address_space(3))) void*)lds, 16, 0, 0);
}

// bijective XCD remap (8 XCDs): contiguous logical chunks per XCD
__device__ __forceinline__ int xcd_remap(int bid, int nwg) {
  int q = nwg >> 3, r = nwg & 7;
  int xcd = bid & 7, idx = bid >> 3;
  return (xcd < r ? xcd * (q + 1) : r * (q + 1) + (xcd - r) * q) + idx;
}

// ws layout (bytes) — counters padded: one 64B cache line per counter
#define WS_CNT   0                             // 24 ints @ stride 16 (ws_i[e*16])
#define WS_IMP   1536                          // 24 f32 @ stride 16
#define WS_ZSUM  3072                          // 1 f32
#define WS_G     4096
#define WS_EID   (WS_G + NSLOT*4)
#define WS_KVK   (WS_EID + NSLOT)              // NT*128 u16 (K, padded+pre-swizzled)
#define WS_VT    (WS_KVK + NT*128*2)           // 96*NT u16 (V^T, in-block pre-swizzled)
#define WS_WIN   (WS_VT + (size_t)96*NT*2)
#define WS_WOUT  (WS_WIN + (size_t)EC*CC*2)
#define WS_WKV   (WS_WOUT + (size_t)CC*EC*2)
#define WS_QA    (WS_WKV + 192*CC*2)
#define WS_Z     (WS_QA + (size_t)NT*EC*2)
#define WS_XB    WS_Z                          // aliases z; xb dead before z memset
#define WS_BUCKET (WS_Z + (size_t)16*1024*1024) // aliases z tail; dead before z memset

// ---- gating: register-blocked fp32 GEMM (16 tok x 24 exp), 16-way k-split,
//      2-deep register-prefetch pipeline; softmax + top-8 + buckets; emits xb.
__global__ __launch_bounds__(256) void gate_kernel(
    const float* __restrict__ x, const float* __restrict__ Wg_all,
    const int* __restrict__ task_p, float* __restrict__ ws_f,
    int* __restrict__ ws_i, u8* __restrict__ eids, u16* __restrict__ xb,
    int* __restrict__ bucket)
{
  __shared__ float xs[16][68];
  __shared__ float wgt[24][68];
  __shared__ float scr[4][16][24];
  __shared__ float lgt[16][26];
  __shared__ float zlo[16];
  __shared__ int hist[EE];
  __shared__ int gbase[EE];

  int t = threadIdx.x;
  int w = t >> 6, l = t & 63;
  int pos = l & 15;
  int tg = pos >> 2, eg = pos & 3;
  int kq_low = (l >> 4) & 3;
  int cq = 16 * w + 4 * kq_low;
  int tok0 = blockIdx.x * 16;
  const float* Wg = Wg_all + (size_t)task_p[0] * CC * EE;

  if (t < EE) hist[t] = 0;

  int rr_ = t >> 4, cc_ = (t & 15) << 2;
  int wkk_[6], we_[6];
  #pragma unroll
  for (int i = 0; i < 6; i++) {
    int f = t + i * 256;
    wkk_[i] = f / 24; we_[i] = f - wkk_[i] * 24;
  }

  float acc[4][6];
  #pragma unroll
  for (int i = 0; i < 4; i++)
    #pragma unroll
    for (int j = 0; j < 6; j++) acc[i][j] = 0.f;

  float4 xv[2]; float wgv[2][6];
  #pragma unroll
  for (int p = 0; p < 2; p++) {
    int kb = p * 64;
    xv[p] = *(const float4*)&x[(size_t)(tok0 + rr_) * CC + kb + cc_];
    #pragma unroll
    for (int i = 0; i < 6; i++)
      wgv[p][i] = Wg[(size_t)(kb + wkk_[i]) * EE + we_[i]];
  }

  #pragma unroll
  for (int s = 0; s < 12; s++) {
    int sl = s & 1;
    __syncthreads();
    *(float4*)&xs[rr_][cc_] = xv[sl];
    {
      float4 v = xv[sl];
      u64 pk = (u64)f2b(v.x) | ((u64)f2b(v.y) << 16) |
               ((u64)f2b(v.z) << 32) | ((u64)f2b(v.w) << 48);
      *(u64*)&xb[(size_t)(tok0 + rr_) * CC + s * 64 + cc_] = pk;
    }
    #pragma unroll
    for (int i = 0; i < 6; i++) wgt[we_[i]][wkk_[i]] = wgv[sl][i];
    if (s + 2 < 12) {
      int kb = (s + 2) * 64;
      xv[sl] = *(const float4*)&x[(size_t)(tok0 + rr_) * CC + kb + cc_];
      #pragma unroll
      for (int i = 0; i < 6; i++)
        wgv[sl][i] = Wg[(size_t)(kb + wkk_[i]) * EE + we_[i]];
    }
    __syncthreads();
    float4 x4[4];
    #pragma unroll
    for (int i = 0; i < 4; i++) x4[i] = *(const float4*)&xs[tg * 4 + i][cq];
    #pragma unroll
    for (int j = 0; j < 6; j++) {
      float4 w4 = *(const float4*)&wgt[eg * 6 + j][cq];
      #pragma unroll
      for (int i = 0; i < 4; i++) {
        float a = acc[i][j];
        a = fmaf(x4[i].x, w4.x, a);
        a = fmaf(x4[i].y, w4.y, a);
        a = fmaf(x4[i].z, w4.z, a);
        a = fmaf(x4[i].w, w4.w, a);
        acc[i][j] = a;
      }
    }
  }
  #pragma unroll
  for (int i = 0; i < 4; i++)
    #pragma unroll
    for (int j = 0; j < 6; j++) {
      float v = acc[i][j];
      v += __shfl_xor(v, 16);
      v += __shfl_xor(v, 32);
      acc[i][j] = v;
    }
  if (l < 16) {
    #pragma unroll
    for (int i = 0; i < 4; i++)
      #pragma unroll
      for (int j = 0; j < 6; j++) scr[w][pos][i * 6 + j] = acc[i][j];
  }
  __syncthreads();
  if (w == 0 && l < 16) {
    #pragma unroll
    for (int i = 0; i < 4; i++)
      #pragma unroll
      for (int j = 0; j < 6; j++) {
        float s = scr[0][pos][i * 6 + j] + scr[1][pos][i * 6 + j] +
                  scr[2][pos][i * 6 + j] + scr[3][pos][i * 6 + j];
        lgt[tg * 4 + i][eg * 6 + j] = s;
      }
  }
  __syncthreads();

  int my_e[8], loc[8];
  if (t < 16) {
    int token = tok0 + t;
    float lg[EE];
    #pragma unroll
    for (int e = 0; e < EE; e++) lg[e] = lgt[t][e];
    float mx = lg[0];
    #pragma unroll
    for (int e = 1; e < EE; e++) mx = fmaxf(mx, lg[e]);
    float se = 0.f; float probs[EE];
    #pragma unroll
    for (int e = 0; e < EE; e++) { probs[e] = __expf(lg[e] - mx); se += probs[e]; }
    float inv = 1.f / se;
    #pragma unroll
    for (int e = 0; e < EE; e++) probs[e] *= inv;
    float lse = mx + __logf(se);
    zlo[t] = lse * lse;

    unsigned taken = 0u;
    float gsum = 0.f;
    float my_g[8];
    #pragma unroll
    for (int h = 0; h < HH; h++) {
      float best = -1.f; int bi = 0;
      #pragma unroll
      for (int e = 0; e < EE; e++) {
        bool ok = !((taken >> e) & 1u) && (probs[e] > best);
        best = ok ? probs[e] : best;
        bi   = ok ? e : bi;
      }
      taken |= 1u << bi;
      gsum += best;
      my_g[h] = best; my_e[h] = bi;
    }
    float ginv = 1.f / (gsum + 1e-6f);
    float4 g0, g1;
    g0.x = my_g[0] * ginv; g0.y = my_g[1] * ginv; g0.z = my_g[2] * ginv; g0.w = my_g[3] * ginv;
    g1.x = my_g[4] * ginv; g1.y = my_g[5] * ginv; g1.z = my_g[6] * ginv; g1.w = my_g[7] * ginv;
    float* gbuf = ws_f + WS_G / 4;
    *(float4*)&gbuf[(size_t)token * HH]     = g0;
    *(float4*)&gbuf[(size_t)token * HH + 4] = g1;
    u64 pk = 0;
    #pragma unroll
    for (int h = 0; h < HH; h++) pk |= (u64)(u8)my_e[h] << (8 * h);
    *(u64*)&eids[(size_t)token * HH] = pk;
    #pragma unroll
    for (int h = 0; h < HH; h++) loc[h] = atomicAdd(&hist[my_e[h]], 1);
    #pragma unroll
    for (int e = 0; e < EE; e++) lgt[t][e] = probs[e];
  }
  __syncthreads();
  if (t < EE) {
    float s = 0.f;
    #pragma unroll 8
    for (int rr = 0; rr < 16; rr++) s += lgt[rr][t];
    atomicAdd(ws_f + WS_IMP / 4 + t * 16, s);
    gbase[t] = atomicAdd(&ws_i[t * 16], hist[t]);
  } else if (t == 32) {
    float s = 0.f;
    #pragma unroll 8
    for (int rr = 0; rr < 16; rr++) s += zlo[rr];
    atomicAdd(ws_f + WS_ZSUM / 4, s);
  }
  __syncthreads();
  if (t < 16) {
    int token = tok0 + t;
    #pragma unroll
    for (int h = 0; h < HH; h++)
      bucket[my_e[h] * CAPQ + gbase[my_e[h]] + loc[h]] = token;
  }
}

// -------- batched transpose + f32->bf16 --------
__global__ __launch_bounds__(256) void transpose_kernel(
    const float* __restrict__ src, u16* __restrict__ dst,
    int R, int C, int sB, int dR, int dB)
{
  __shared__ float tile[32][33];
  int e = blockIdx.z;
  const float* s = src + (size_t)e * sB;
  int t = threadIdx.x;
  int tr = t >> 5, tc = t & 31;
  #pragma unroll
  for (int i = 0; i < 4; i++) {
    int r = blockIdx.x * 32 + tr + i * 8;
    int c = blockIdx.y * 32 + tc;
    tile[tr + i * 8][tc] = s[(size_t)r * C + c];
  }
  __syncthreads();
  #pragma unroll
  for (int i = 0; i < 4; i++) {
    int sc = blockIdx.y * 32 + tr + i * 8;
    int sr = blockIdx.x * 32 + tc;
    dst[(size_t)e * dB + (size_t)sc * dR + sr] = f2b(tile[tc][tr + i * 8]);
  }
}

// -------- dense MFMA GEMM (oproj), bf16 A/B, gload_lds, XCD-swizzled --------
template<int BM, int BN, bool OUT_F32>
__global__ __launch_bounds__(256) void gemm_kernel(
    const u16* __restrict__ A, const u16* __restrict__ Bt,
    void* __restrict__ Cp, int M, int N, int K)
{
  constexpr int WM = BM / 2, WN = BN / 2;
  constexpr int FM = WM / 16, FN = WN / 16;
  __shared__ u16 As[BM][64];
  __shared__ u16 Bs[BN][64];
  int t = threadIdx.x;
  int w = t >> 6, l = t & 63;
  int lr = l & 15, lg = l >> 4;
  int wr = w >> 1, wc = w & 1;
  int nwg = gridDim.x * gridDim.y;
  int logical = xcd_remap(blockIdx.y * gridDim.x + blockIdx.x, nwg);
  int col0 = (logical % gridDim.x) * BN, row0 = (logical / gridDim.x) * BM;

  f32x4 acc[FM][FN];
  #pragma unroll
  for (int i = 0; i < FM; i++)
    #pragma unroll
    for (int j = 0; j < FN; j++) acc[i][j] = (f32x4)(0.f);

  int sr = t >> 3;
  int sc = t & 7;
  for (int kb = 0; kb < K; kb += 64) {
    __syncthreads();
    #pragma unroll
    for (int i = 0; i < BM / 32; i++) {
      int rr = i * 32 + sr;
      int ch = sc ^ (rr & 7);
      gload16(A + (size_t)(row0 + rr) * K + kb + ch * 8, &As[rr][sc * 8]);
    }
    #pragma unroll
    for (int i = 0; i < BN / 32; i++) {
      int rr = i * 32 + sr;
      int ch = sc ^ (rr & 7);
      gload16(Bt + (size_t)(col0 + rr) * K + kb + ch * 8, &Bs[rr][sc * 8]);
    }
    __syncthreads();
    #pragma unroll
    for (int ks = 0; ks < 2; ks++) {
      s16x8 af[FM], bf[FN];
      #pragma unroll
      for (int i = 0; i < FM; i++)
        af[i] = *(const s16x8*)&As[wr * WM + i * 16 + lr][8 * ((ks * 4 + lg) ^ (lr & 7))];
      #pragma unroll
      for (int j = 0; j < FN; j++)
        bf[j] = *(const s16x8*)&Bs[wc * WN + j * 16 + lr][8 * ((ks * 4 + lg) ^ (lr & 7))];
      #pragma unroll
      for (int i = 0; i < FM; i++)
        #pragma unroll
        for (int j = 0; j < FN; j++)
          acc[i][j] = __builtin_amdgcn_mfma_f32_16x16x32_bf16(af[i], bf[j], acc[i][j], 0, 0, 0);
    }
  }
  #pragma unroll
  for (int i = 0; i < FM; i++)
    #pragma unroll
    for (int j = 0; j < FN; j++)
      #pragma unroll
      for (int reg = 0; reg < 4; reg++) {
        int rr = row0 + wr * WM + i * 16 + lg * 4 + reg;
        int cc = col0 + wc * WN + j * 16 + lr;
        if (OUT_F32) ((float*)Cp)[(size_t)rr * N + cc] = acc[i][j][reg];
        else ((u16*)Cp)[(size_t)rr * N + cc] = f2b(acc[i][j][reg]);
      }
}

// -------- gathered q projection: per-expert tiles, 128 rows x 96 cols, K=768
__global__ __launch_bounds__(256) void qproj_kernel(
    const u16* __restrict__ xb, const u16* __restrict__ winT,
    const int* __restrict__ ws_i, const int* __restrict__ bucket,
    u16* __restrict__ qall)
{
  int e = blockIdx.y;
  int t0 = blockIdx.x * 128;
  int cnt = ws_i[e * 16];
  if (t0 >= cnt) return;
  __shared__ u16 As[128][64];
  __shared__ u16 Bs[96][64];
  __shared__ int tok_s[128];
  int t = threadIdx.x;
  if (t < 128) tok_s[t] = bucket[e * CAPQ + min(t0 + t, cnt - 1)];
  __syncthreads();
  int w = t >> 6, l = t & 63;
  int lr = l & 15, lg = l >> 4;
  int wr = w >> 1, wc = w & 1;
  const u16* Bt = winT + (size_t)e * HD * CC;

  f32x4 acc[4][3];
  #pragma unroll
  for (int i = 0; i < 4; i++)
    #pragma unroll
    for (int j = 0; j < 3; j++) acc[i][j] = (f32x4)(0.f);

  int sr = t >> 3, sc = t & 7;
  int atok[4];
  #pragma unroll
  for (int i = 0; i < 4; i++) atok[i] = tok_s[i * 32 + sr];

  for (int kb = 0; kb < CC; kb += 64) {
    __syncthreads();
    #pragma unroll
    for (int i = 0; i < 4; i++) {
      int rr = i * 32 + sr;
      int ch = sc ^ (rr & 7);
      gload16(xb + (size_t)atok[i] * CC + kb + ch * 8, &As[rr][sc * 8]);
    }
    #pragma unroll
    for (int i = 0; i < 3; i++) {
      int rr = i * 32 + sr;
      int ch = sc ^ (rr & 7);
      gload16(Bt + (size_t)rr * CC + kb + ch * 8, &Bs[rr][sc * 8]);
    }
    __syncthreads();
    #pragma unroll
    for (int ks = 0; ks < 2; ks++) {
      s16x8 af[4], bf[3];
      #pragma unroll
      for (int i = 0; i < 4; i++)
        af[i] = *(const s16x8*)&As[wr * 64 + i * 16 + lr][8 * ((ks * 4 + lg) ^ (lr & 7))];
      #pragma unroll
      for (int j = 0; j < 3; j++)
        bf[j] = *(const s16x8*)&Bs[wc * 48 + j * 16 + lr][8 * ((ks * 4 + lg) ^ (lr & 7))];
      #pragma unroll
      for (int i = 0; i < 4; i++)
        #pragma unroll
        for (int j = 0; j < 3; j++)
          acc[i][j] = __builtin_amdgcn_mfma_f32_16x16x32_bf16(af[i], bf[j], acc[i][j], 0, 0, 0);
    }
  }
  #pragma unroll
  for (int i = 0; i < 4; i++)
    #pragma unroll
    for (int reg = 0; reg < 4; reg++) {
      int rr = wr * 64 + i * 16 + lg * 4 + reg;
      if (t0 + rr < cnt) {
        int tok = tok_s[rr];
        u16* qp = qall + (size_t)tok * EC + e * HD + wc * 48;
        #pragma unroll
        for (int j = 0; j < 3; j++)
          qp[j * 16 + lr] = f2b(acc[i][j][reg]);
      }
    }
}

// -------- kv projection -> kvbk (padded 128, pre-swizzled K) + vtb (V^T, pre-swizzled)
__global__ __launch_bounds__(256) void kvproj_kernel(
    const u16* __restrict__ xb, const u16* __restrict__ wkvT,
    u16* __restrict__ kvbk, u16* __restrict__ vtb)
{
  __shared__ u16 As[128][64];
  __shared__ u16 Bs[64][64];
  int t = threadIdx.x;
  int w = t >> 6, l = t & 63;
  int lr = l & 15, lg = l >> 4;
  int wr = w >> 1, wc = w & 1;
  int nwg = gridDim.x * gridDim.y;
  int logical = xcd_remap(blockIdx.y * gridDim.x + blockIdx.x, nwg);
  int col0 = (logical % gridDim.x) * 64, row0 = (logical / gridDim.x) * 128;

  f32x4 acc[4][2];
  #pragma unroll
  for (int i = 0; i < 4; i++)
    #pragma unroll
    for (int j = 0; j < 2; j++) acc[i][j] = (f32x4)(0.f);

  int sr = t >> 3, sc = t & 7;
  for (int kb = 0; kb < CC; kb += 64) {
    __syncthreads();
    #pragma unroll
    for (int i = 0; i < 4; i++) {
      int rr = i * 32 + sr;
      int ch = sc ^ (rr & 7);
      gload16(xb + (size_t)(row0 + rr) * CC + kb + ch * 8, &As[rr][sc * 8]);
    }
    #pragma unroll
    for (int i = 0; i < 2; i++) {
      int rr = i * 32 + sr;
      int ch = sc ^ (rr & 7);
      gload16(wkvT + (size_t)(col0 + rr) * CC + kb + ch * 8, &Bs[rr][sc * 8]);
    }
    __syncthreads();
    #pragma unroll
    for (int ks = 0; ks < 2; ks++) {
      s16x8 af[4], bf[2];
      #pragma unroll
      for (int i = 0; i < 4; i++)
        af[i] = *(const s16x8*)&As[wr * 64 + i * 16 + lr][8 * ((ks * 4 + lg) ^ (lr & 7))];
      #pragma unroll
      for (int j = 0; j < 2; j++)
        bf[j] = *(const s16x8*)&Bs[wc * 32 + j * 16 + lr][8 * ((ks * 4 + lg) ^ (lr & 7))];
      #pragma unroll
      for (int i = 0; i < 4; i++)
        #pragma unroll
        for (int j = 0; j < 2; j++)
          acc[i][j] = __builtin_amdgcn_mfma_f32_16x16x32_bf16(af[i], bf[j], acc[i][j], 0, 0, 0);
    }
  }
  #pragma unroll
  for (int i = 0; i < 4; i++)
    #pragma unroll
    for (int j = 0; j < 2; j++) {
      int cb = col0 + wc * 32 + j * 16 + lr;
      int rb = row0 + wr * 64 + i * 16 + lg * 4;
      if (cb < 96) {
        int ch = cb >> 3, ci = cb & 7;
        #pragma unroll
        for (int reg = 0; reg < 4; reg++) {
          int tok = rb + reg;
          kvbk[(size_t)tok * 128 + 8 * (ch ^ (tok & 7)) + ci] = f2b(acc[i][j][reg]);
        }
      } else {
        int d = cb - 96;
        u64 pk = (u64)f2b(acc[i][j][0]) | ((u64)f2b(acc[i][j][1]) << 16) |
                 ((u64)f2b(acc[i][j][2]) << 32) | ((u64)f2b(acc[i][j][3]) << 48);
        int blkbase = rb & ~63;
        int ch = (rb & 63) >> 3;
        *(u64*)&vtb[(size_t)d * NT + blkbase + 8 * (ch ^ (d & 7)) + (rb & 7)] = pk;
      }
    }
}

// ---- flash attention: 32x32x16 MFMA, 4 waves = 4 heads (z splits 8 heads) ----
// single-buffered LDS (28 KB) -> 4-5 blocks/CU; cross-block TLP hides drains.
__global__ __launch_bounds__(256, 4) void attn_kernel(
    const u16* __restrict__ qall, const u16* __restrict__ kvbk,
    const u16* __restrict__ vtb, const u8* __restrict__ eids,
    const float* __restrict__ gbuf, u16* __restrict__ z)
{
  __shared__ u16 Ks[64][128];   // 16 KB
  __shared__ u16 Vt[96][64];    // 12 KB
  int b = blockIdx.y;
  int tok0 = blockIdx.x * 32;
  int t = threadIdx.x;
  int w = t >> 6, l = t & 63;
  int h = blockIdx.z * 4 + w;
  int lo = l & 31, hi = l >> 5;

  s16x8 qf[6];
  {
    int tok = b * NN + tok0 + lo;
    int e = eids[tok * HH + h];
    const u16* qp = qall + (size_t)tok * EC + e * HD + hi * 8;
    #pragma unroll
    for (int ks = 0; ks < 6; ks++)
      qf[ks] = *(const s16x8*)(qp + ks * 16);
  }

  const u16* kvwin = kvbk + (size_t)(b * NN) * 128;
  const u16* vwin  = vtb + (size_t)(b * NN);

  f32x16 o0 = (f32x16)(0.f), o1 = (f32x16)(0.f), o2 = (f32x16)(0.f);
  float m = -1e30f, lsum = 0.f;   // m in log2 units

  for (int jt = 0; jt < 16; jt++) {
    int j0 = jt * 64;
    __syncthreads();             // previous compute done reading LDS
    {
      const u16* kb_ = kvwin + (size_t)j0 * 128;
      #pragma unroll
      for (int k2 = 0; k2 < 4; k2++) {
        int c = t + k2 * 256;
        gload16(kb_ + c * 8, &Ks[0][0] + c * 8);
      }
      const u16* vb_ = vwin + j0;
      #pragma unroll
      for (int k2 = 0; k2 < 3; k2++) {
        int c = t + k2 * 256;
        gload16(vb_ + (size_t)(c >> 3) * NT + (c & 7) * 8, &Vt[0][0] + c * 8);
      }
    }
    __syncthreads();             // staging complete (vmcnt drained by compiler)

    f32x16 s0 = (f32x16)(0.f), s1 = (f32x16)(0.f);
    __builtin_amdgcn_s_setprio(1);
    #pragma unroll
    for (int ks = 0; ks < 6; ks++) {
      int pos = 8 * ((2 * ks + hi) ^ (lo & 7));
      s16x8 a0 = *(const s16x8*)&Ks[lo][pos];
      s16x8 a1 = *(const s16x8*)&Ks[32 + lo][pos];
      s0 = __builtin_amdgcn_mfma_f32_32x32x16_bf16(a0, qf[ks], s0, 0, 0, 0);
      s1 = __builtin_amdgcn_mfma_f32_32x32x16_bf16(a1, qf[ks], s1, 0, 0, 0);
    }
    __builtin_amdgcn_s_setprio(0);

    float pm = fmaxf(s0[0], s0[1]);
    #pragma unroll
    for (int rg = 2; rg < 16; rg += 2) pm = fmaxf(pm, fmaxf(s0[rg], s0[rg + 1]));
    #pragma unroll
    for (int rg = 0; rg < 16; rg += 2) pm = fmaxf(pm, fmaxf(s1[rg], s1[rg + 1]));
    pm = fmaxf(pm, __shfl_xor(pm, 32));
    pm *= AL2;

    if (!__all(pm - m <= DEFER_THR)) {
      float mn = fmaxf(m, pm);
      float al = fexp2(m - mn);
      m = mn; lsum *= al;
      #pragma unroll
      for (int rg = 0; rg < 16; rg++) {
        int qrow = (rg & 3) + 8 * (rg >> 2) + 4 * hi;
        float alr = __shfl(al, qrow);
        o0[rg] *= alr; o1[rg] *= alr; o2[rg] *= alr;
      }
    }

    float ts = 0.f;
    u32 wpk[2][4][2];
    #pragma unroll
    for (int kb2 = 0; kb2 < 2; kb2++)
      #pragma unroll
      for (int rr = 0; rr < 4; rr++)
        #pragma unroll
        for (int pp = 0; pp < 2; pp++) {
          float sA = kb2 ? s1[rr * 4 + 2 * pp]     : s0[rr * 4 + 2 * pp];
          float sB = kb2 ? s1[rr * 4 + 2 * pp + 1] : s0[rr * 4 + 2 * pp + 1];
          float eA = fexp2(fmaf(sA, AL2, -m));
          float eB = fexp2(fmaf(sB, AL2, -m));
          ts += eA + eB;
          wpk[kb2][rr][pp] = cvtpk(eA, eB);
        }
    lsum += ts;

    s16x8 pa[4];
    #pragma unroll
    for (int ks = 0; ks < 4; ks++) {
      int kb2 = ks >> 1;
      int rlo = (ks & 1) * 2, rhi = rlo + 1;
      u32 own_lo0 = wpk[kb2][rlo][0], own_lo1 = wpk[kb2][rlo][1];
      u32 own_hi0 = wpk[kb2][rhi][0], own_hi1 = wpk[kb2][rhi][1];
      u32 send0 = hi ? own_lo0 : own_hi0;
      u32 send1 = hi ? own_lo1 : own_hi1;
      u32 recv0 = (u32)__shfl_xor((int)send0, 32);
      u32 recv1 = (u32)__shfl_xor((int)send1, 32);
      union { s16x8 v; u32 u[4]; } pu;
      pu.u[0] = hi ? recv0 : own_lo0;
      pu.u[1] = hi ? recv1 : own_lo1;
      pu.u[2] = hi ? own_hi0 : recv0;
      pu.u[3] = hi ? own_hi1 : recv1;
      pa[ks] = pu.v;
    }

    __builtin_amdgcn_s_setprio(1);
    #pragma unroll
    for (int ks = 0; ks < 4; ks++) {
      int pos = 8 * ((2 * ks + hi) ^ (lo & 7));
      s16x8 v0 = *(const s16x8*)&Vt[lo][pos];
      s16x8 v1 = *(const s16x8*)&Vt[32 + lo][pos];
      s16x8 v2 = *(const s16x8*)&Vt[64 + lo][pos];
      o0 = __builtin_amdgcn_mfma_f32_32x32x16_bf16(pa[ks], v0, o0, 0, 0, 0);
      o1 = __builtin_amdgcn_mfma_f32_32x32x16_bf16(pa[ks], v1, o1, 0, 0, 0);
      o2 = __builtin_amdgcn_mfma_f32_32x32x16_bf16(pa[ks], v2, o2, 0, 0, 0);
    }
    __builtin_amdgcn_s_setprio(0);
  }

  float lt = lsum + __shfl_xor(lsum, 32);
  #pragma unroll
  for (int rg = 0; rg < 16; rg++) {
    int qrow = (rg & 3) + 8 * (rg >> 2) + 4 * hi;
    float lv = __shfl(lt, qrow);
    int tok = b * NN + tok0 + qrow;
    int slot = tok * HH + h;
    float scl = gbuf[slot] / lv;
    int e = eids[slot];
    u16* zp = z + (size_t)tok * EC + e * HD + lo;
    zp[0]  = f2b(o0[rg] * scl);
    zp[32] = f2b(o1[rg] * scl);
    zp[64] = f2b(o2[rg] * scl);
  }
}

// ---------------- aux loss ----------------
__global__ void aux_kernel(const float* __restrict__ ws_f,
                           const int* __restrict__ ws_i, float* __restrict__ out)
{
  if (threadIdx.x == 0 && blockIdx.x == 0) {
    float sw = 0.f;
    for (int e = 0; e < EE; e++) {
      float imp = ws_f[WS_IMP / 4 + e * 16] / (float)NT;
      float load = (float)ws_i[e * 16] / (float)(NT * HH);
      sw += imp * load;
    }
    float zl = ws_f[WS_ZSUM / 4] / (float)NT;
    out[(size_t)NT * CC] = 0.1f * ((float)EE * sw) + 0.001f * zl;
  }
}

extern "C" void kernel_launch(void* const* d_in, const int* in_sizes, int n_in,
                              void* d_out, int out_size, void* d_ws, size_t ws_size,
                              hipStream_t stream)
{
  const float* x    = (const float*)d_in[0];
  const float* Wg   = (const float*)d_in[1];
  const float* Win  = (const float*)d_in[2];
  const float* Wout = (const float*)d_in[3];
  const float* Wkv  = (const float*)d_in[4];
  const int*   task = (const int*)d_in[5];
  float* out = (float*)d_out;
  float* ws_f = (float*)d_ws;
  int*   ws_i = (int*)d_ws;
  u8*  eids = (u8*)((char*)d_ws + WS_EID);
  u16* kvbk = (u16*)((char*)d_ws + WS_KVK);
  u16* vtb  = (u16*)((char*)d_ws + WS_VT);
  u16* winT = (u16*)((char*)d_ws + WS_WIN);
  u16* woutT= (u16*)((char*)d_ws + WS_WOUT);
  u16* wkvT = (u16*)((char*)d_ws + WS_WKV);
  u16* qall = (u16*)((char*)d_ws + WS_QA);
  u16* z    = (u16*)((char*)d_ws + WS_Z);
  u16* xb   = (u16*)((char*)d_ws + WS_XB);
  int* bucket = (int*)((char*)d_ws + WS_BUCKET);

  hipMemsetAsync(d_ws, 0, 4096, stream);

  transpose_kernel<<<dim3(CC/32, HD/32, EE), 256, 0, stream>>>(Win, winT, CC, HD, CC*HD, CC, HD*CC);
  transpose_kernel<<<dim3(HD/32, CC/32, EE), 256, 0, stream>>>(Wout, woutT, HD, CC, HD*CC, EC, HD);
  transpose_kernel<<<dim3(CC/32, 192/32, 1), 256, 0, stream>>>(Wkv, wkvT, CC, 192, 0, CC, 0);

  gate_kernel<<<NT / 16, 256, 0, stream>>>(x, Wg, task, ws_f, ws_i, eids, xb, bucket);

  kvproj_kernel<<<dim3(3, NT/128), 256, 0, stream>>>(xb, wkvT, kvbk, vtb);
  qproj_kernel<<<dim3(NT/128, EE), 256, 0, stream>>>(xb, winT, ws_i, bucket, qall);

  hipMemsetAsync(z, 0, (size_t)NT * EC * 2, stream);   // xb+bucket dead; z aliases them

  attn_kernel<<<dim3(NN/32, BB, 2), 256, 0, stream>>>(qall, kvbk, vtb, eids, ws_f + WS_G/4, z);

  gemm_kernel<128, 64, true><<<dim3(CC/64, NT/128), 256, 0, stream>>>(
      z, woutT, out, NT, CC, EC);

  aux_kernel<<<1, 64, 0, stream>>>(ws_f, ws_i, out);
}

// Round 18
// 173.159 us; speedup vs baseline: 1.1921x; 1.1921x over previous
//
#include <hip/hip_runtime.h>
#include <hip/hip_bf16.h>
#include <math.h>

#define BB 8
#define NN 1024
#define CC 768
#define HH 8
#define HD 96
#define EE 24
#define NT (BB*NN)          // 8192 tokens
#define NSLOT (NT*HH)       // 65536 (token,h) slots
#define EC (EE*HD)          // 2304
#define CAPQ 8192           // per-expert bucket capacity
#define ASCALE 0.10206207261596575f  // 96^-0.5
#define AL2 0.14724446f              // ASCALE * log2(e)
#define DEFER_THR 11.5415603f        // 8 * log2(e)

typedef unsigned short u16;
typedef unsigned char u8;
typedef unsigned int u32;
typedef unsigned long long u64;
typedef __attribute__((ext_vector_type(8))) short s16x8;
typedef __attribute__((ext_vector_type(4))) float f32x4;
typedef __attribute__((ext_vector_type(16))) float f32x16;

__device__ __forceinline__ u16 f2b(float f) {  // RNE float->bf16 bits
  unsigned u = __builtin_bit_cast(unsigned, f);
  unsigned r = u + 0x7fffu + ((u >> 16) & 1u);
  return (u16)(r >> 16);
}

__device__ __forceinline__ float fexp2(float x) {  // native 2^x
  float r; asm("v_exp_f32 %0, %1" : "=v"(r) : "v"(x)); return r;
}

__device__ __forceinline__ u32 cvtpk(float a, float b) {  // HW RNE pack
  u32 d; asm("v_cvt_pk_bf16_f32 %0, %1, %2" : "=v"(d) : "v"(a), "v"(b)); return d;
}

__device__ __forceinline__ void gload16(const u16* g, u16* lds) {
  __builtin_amdgcn_global_load_lds(
      (const __attribute__((address_space(1))) void*)g,
      (__attribute__((address_space(3))) void*)lds, 16, 0, 0);
}

// bijective XCD remap (8 XCDs): contiguous logical chunks per XCD
__device__ __forceinline__ int xcd_remap(int bid, int nwg) {
  int q = nwg >> 3, r = nwg & 7;
  int xcd = bid & 7, idx = bid >> 3;
  return (xcd < r ? xcd * (q + 1) : r * (q + 1) + (xcd - r) * q) + idx;
}

// ws layout (bytes) — counters padded: one 64B cache line per counter
#define WS_CNT   0                             // 24 ints @ stride 16 (ws_i[e*16])
#define WS_IMP   1536                          // 24 f32 @ stride 16
#define WS_ZSUM  3072                          // 1 f32
#define WS_G     4096
#define WS_EID   (WS_G + NSLOT*4)
#define WS_KVK   (WS_EID + NSLOT)              // NT*128 u16 (K, padded+pre-swizzled)
#define WS_VT    (WS_KVK + NT*128*2)           // 96*NT u16 (V^T, in-block pre-swizzled)
#define WS_WIN   (WS_VT + (size_t)96*NT*2)
#define WS_WOUT  (WS_WIN + (size_t)EC*CC*2)
#define WS_WKV   (WS_WOUT + (size_t)CC*EC*2)
#define WS_QA    (WS_WKV + 192*CC*2)
#define WS_Z     (WS_QA + (size_t)NT*EC*2)
#define WS_XB    WS_Z                          // aliases z; xb dead before z memset
#define WS_BUCKET (WS_Z + (size_t)16*1024*1024) // aliases z tail; dead before z memset

// ---- gating: register-blocked fp32 GEMM (16 tok x 24 exp), 16-way k-split,
//      2-deep register-prefetch pipeline; softmax + top-8 + buckets; emits xb.
__global__ __launch_bounds__(256) void gate_kernel(
    const float* __restrict__ x, const float* __restrict__ Wg_all,
    const int* __restrict__ task_p, float* __restrict__ ws_f,
    int* __restrict__ ws_i, u8* __restrict__ eids, u16* __restrict__ xb,
    int* __restrict__ bucket)
{
  __shared__ float xs[16][68];
  __shared__ float wgt[24][68];
  __shared__ float scr[4][16][24];
  __shared__ float lgt[16][26];
  __shared__ float zlo[16];
  __shared__ int hist[EE];
  __shared__ int gbase[EE];

  int t = threadIdx.x;
  int w = t >> 6, l = t & 63;
  int pos = l & 15;
  int tg = pos >> 2, eg = pos & 3;
  int kq_low = (l >> 4) & 3;
  int cq = 16 * w + 4 * kq_low;
  int tok0 = blockIdx.x * 16;
  const float* Wg = Wg_all + (size_t)task_p[0] * CC * EE;

  if (t < EE) hist[t] = 0;

  int rr_ = t >> 4, cc_ = (t & 15) << 2;
  int wkk_[6], we_[6];
  #pragma unroll
  for (int i = 0; i < 6; i++) {
    int f = t + i * 256;
    wkk_[i] = f / 24; we_[i] = f - wkk_[i] * 24;
  }

  float acc[4][6];
  #pragma unroll
  for (int i = 0; i < 4; i++)
    #pragma unroll
    for (int j = 0; j < 6; j++) acc[i][j] = 0.f;

  float4 xv[2]; float wgv[2][6];
  #pragma unroll
  for (int p = 0; p < 2; p++) {
    int kb = p * 64;
    xv[p] = *(const float4*)&x[(size_t)(tok0 + rr_) * CC + kb + cc_];
    #pragma unroll
    for (int i = 0; i < 6; i++)
      wgv[p][i] = Wg[(size_t)(kb + wkk_[i]) * EE + we_[i]];
  }

  #pragma unroll
  for (int s = 0; s < 12; s++) {
    int sl = s & 1;
    __syncthreads();
    *(float4*)&xs[rr_][cc_] = xv[sl];
    {
      float4 v = xv[sl];
      u64 pk = (u64)f2b(v.x) | ((u64)f2b(v.y) << 16) |
               ((u64)f2b(v.z) << 32) | ((u64)f2b(v.w) << 48);
      *(u64*)&xb[(size_t)(tok0 + rr_) * CC + s * 64 + cc_] = pk;
    }
    #pragma unroll
    for (int i = 0; i < 6; i++) wgt[we_[i]][wkk_[i]] = wgv[sl][i];
    if (s + 2 < 12) {
      int kb = (s + 2) * 64;
      xv[sl] = *(const float4*)&x[(size_t)(tok0 + rr_) * CC + kb + cc_];
      #pragma unroll
      for (int i = 0; i < 6; i++)
        wgv[sl][i] = Wg[(size_t)(kb + wkk_[i]) * EE + we_[i]];
    }
    __syncthreads();
    float4 x4[4];
    #pragma unroll
    for (int i = 0; i < 4; i++) x4[i] = *(const float4*)&xs[tg * 4 + i][cq];
    #pragma unroll
    for (int j = 0; j < 6; j++) {
      float4 w4 = *(const float4*)&wgt[eg * 6 + j][cq];
      #pragma unroll
      for (int i = 0; i < 4; i++) {
        float a = acc[i][j];
        a = fmaf(x4[i].x, w4.x, a);
        a = fmaf(x4[i].y, w4.y, a);
        a = fmaf(x4[i].z, w4.z, a);
        a = fmaf(x4[i].w, w4.w, a);
        acc[i][j] = a;
      }
    }
  }
  #pragma unroll
  for (int i = 0; i < 4; i++)
    #pragma unroll
    for (int j = 0; j < 6; j++) {
      float v = acc[i][j];
      v += __shfl_xor(v, 16);
      v += __shfl_xor(v, 32);
      acc[i][j] = v;
    }
  if (l < 16) {
    #pragma unroll
    for (int i = 0; i < 4; i++)
      #pragma unroll
      for (int j = 0; j < 6; j++) scr[w][pos][i * 6 + j] = acc[i][j];
  }
  __syncthreads();
  if (w == 0 && l < 16) {
    #pragma unroll
    for (int i = 0; i < 4; i++)
      #pragma unroll
      for (int j = 0; j < 6; j++) {
        float s = scr[0][pos][i * 6 + j] + scr[1][pos][i * 6 + j] +
                  scr[2][pos][i * 6 + j] + scr[3][pos][i * 6 + j];
        lgt[tg * 4 + i][eg * 6 + j] = s;
      }
  }
  __syncthreads();

  int my_e[8], loc[8];
  if (t < 16) {
    int token = tok0 + t;
    float lg[EE];
    #pragma unroll
    for (int e = 0; e < EE; e++) lg[e] = lgt[t][e];
    float mx = lg[0];
    #pragma unroll
    for (int e = 1; e < EE; e++) mx = fmaxf(mx, lg[e]);
    float se = 0.f; float probs[EE];
    #pragma unroll
    for (int e = 0; e < EE; e++) { probs[e] = __expf(lg[e] - mx); se += probs[e]; }
    float inv = 1.f / se;
    #pragma unroll
    for (int e = 0; e < EE; e++) probs[e] *= inv;
    float lse = mx + __logf(se);
    zlo[t] = lse * lse;

    unsigned taken = 0u;
    float gsum = 0.f;
    float my_g[8];
    #pragma unroll
    for (int h = 0; h < HH; h++) {
      float best = -1.f; int bi = 0;
      #pragma unroll
      for (int e = 0; e < EE; e++) {
        bool ok = !((taken >> e) & 1u) && (probs[e] > best);
        best = ok ? probs[e] : best;
        bi   = ok ? e : bi;
      }
      taken |= 1u << bi;
      gsum += best;
      my_g[h] = best; my_e[h] = bi;
    }
    float ginv = 1.f / (gsum + 1e-6f);
    float4 g0, g1;
    g0.x = my_g[0] * ginv; g0.y = my_g[1] * ginv; g0.z = my_g[2] * ginv; g0.w = my_g[3] * ginv;
    g1.x = my_g[4] * ginv; g1.y = my_g[5] * ginv; g1.z = my_g[6] * ginv; g1.w = my_g[7] * ginv;
    float* gbuf = ws_f + WS_G / 4;
    *(float4*)&gbuf[(size_t)token * HH]     = g0;
    *(float4*)&gbuf[(size_t)token * HH + 4] = g1;
    u64 pk = 0;
    #pragma unroll
    for (int h = 0; h < HH; h++) pk |= (u64)(u8)my_e[h] << (8 * h);
    *(u64*)&eids[(size_t)token * HH] = pk;
    #pragma unroll
    for (int h = 0; h < HH; h++) loc[h] = atomicAdd(&hist[my_e[h]], 1);
    #pragma unroll
    for (int e = 0; e < EE; e++) lgt[t][e] = probs[e];
  }
  __syncthreads();
  if (t < EE) {
    float s = 0.f;
    #pragma unroll 8
    for (int rr = 0; rr < 16; rr++) s += lgt[rr][t];
    atomicAdd(ws_f + WS_IMP / 4 + t * 16, s);
    gbase[t] = atomicAdd(&ws_i[t * 16], hist[t]);
  } else if (t == 32) {
    float s = 0.f;
    #pragma unroll 8
    for (int rr = 0; rr < 16; rr++) s += zlo[rr];
    atomicAdd(ws_f + WS_ZSUM / 4, s);
  }
  __syncthreads();
  if (t < 16) {
    int token = tok0 + t;
    #pragma unroll
    for (int h = 0; h < HH; h++)
      bucket[my_e[h] * CAPQ + gbase[my_e[h]] + loc[h]] = token;
  }
}

// -------- batched transpose + f32->bf16 --------
__global__ __launch_bounds__(256) void transpose_kernel(
    const float* __restrict__ src, u16* __restrict__ dst,
    int R, int C, int sB, int dR, int dB)
{
  __shared__ float tile[32][33];
  int e = blockIdx.z;
  const float* s = src + (size_t)e * sB;
  int t = threadIdx.x;
  int tr = t >> 5, tc = t & 31;
  #pragma unroll
  for (int i = 0; i < 4; i++) {
    int r = blockIdx.x * 32 + tr + i * 8;
    int c = blockIdx.y * 32 + tc;
    tile[tr + i * 8][tc] = s[(size_t)r * C + c];
  }
  __syncthreads();
  #pragma unroll
  for (int i = 0; i < 4; i++) {
    int sc = blockIdx.y * 32 + tr + i * 8;
    int sr = blockIdx.x * 32 + tc;
    dst[(size_t)e * dB + (size_t)sc * dR + sr] = f2b(tile[tc][tr + i * 8]);
  }
}

// -------- dense MFMA GEMM (oproj), bf16 A/B, gload_lds, XCD-swizzled --------
template<int BM, int BN, bool OUT_F32>
__global__ __launch_bounds__(256) void gemm_kernel(
    const u16* __restrict__ A, const u16* __restrict__ Bt,
    void* __restrict__ Cp, int M, int N, int K)
{
  constexpr int WM = BM / 2, WN = BN / 2;
  constexpr int FM = WM / 16, FN = WN / 16;
  __shared__ u16 As[BM][64];
  __shared__ u16 Bs[BN][64];
  int t = threadIdx.x;
  int w = t >> 6, l = t & 63;
  int lr = l & 15, lg = l >> 4;
  int wr = w >> 1, wc = w & 1;
  int nwg = gridDim.x * gridDim.y;
  int logical = xcd_remap(blockIdx.y * gridDim.x + blockIdx.x, nwg);
  int col0 = (logical % gridDim.x) * BN, row0 = (logical / gridDim.x) * BM;

  f32x4 acc[FM][FN];
  #pragma unroll
  for (int i = 0; i < FM; i++)
    #pragma unroll
    for (int j = 0; j < FN; j++) acc[i][j] = (f32x4)(0.f);

  int sr = t >> 3;
  int sc = t & 7;
  for (int kb = 0; kb < K; kb += 64) {
    __syncthreads();
    #pragma unroll
    for (int i = 0; i < BM / 32; i++) {
      int rr = i * 32 + sr;
      int ch = sc ^ (rr & 7);
      gload16(A + (size_t)(row0 + rr) * K + kb + ch * 8, &As[rr][sc * 8]);
    }
    #pragma unroll
    for (int i = 0; i < BN / 32; i++) {
      int rr = i * 32 + sr;
      int ch = sc ^ (rr & 7);
      gload16(Bt + (size_t)(col0 + rr) * K + kb + ch * 8, &Bs[rr][sc * 8]);
    }
    __syncthreads();
    #pragma unroll
    for (int ks = 0; ks < 2; ks++) {
      s16x8 af[FM], bf[FN];
      #pragma unroll
      for (int i = 0; i < FM; i++)
        af[i] = *(const s16x8*)&As[wr * WM + i * 16 + lr][8 * ((ks * 4 + lg) ^ (lr & 7))];
      #pragma unroll
      for (int j = 0; j < FN; j++)
        bf[j] = *(const s16x8*)&Bs[wc * WN + j * 16 + lr][8 * ((ks * 4 + lg) ^ (lr & 7))];
      #pragma unroll
      for (int i = 0; i < FM; i++)
        #pragma unroll
        for (int j = 0; j < FN; j++)
          acc[i][j] = __builtin_amdgcn_mfma_f32_16x16x32_bf16(af[i], bf[j], acc[i][j], 0, 0, 0);
    }
  }
  #pragma unroll
  for (int i = 0; i < FM; i++)
    #pragma unroll
    for (int j = 0; j < FN; j++)
      #pragma unroll
      for (int reg = 0; reg < 4; reg++) {
        int rr = row0 + wr * WM + i * 16 + lg * 4 + reg;
        int cc = col0 + wc * WN + j * 16 + lr;
        if (OUT_F32) ((float*)Cp)[(size_t)rr * N + cc] = acc[i][j][reg];
        else ((u16*)Cp)[(size_t)rr * N + cc] = f2b(acc[i][j][reg]);
      }
}

// -------- gathered q projection: per-expert tiles, 128 rows x 96 cols, K=768
__global__ __launch_bounds__(256) void qproj_kernel(
    const u16* __restrict__ xb, const u16* __restrict__ winT,
    const int* __restrict__ ws_i, const int* __restrict__ bucket,
    u16* __restrict__ qall)
{
  int e = blockIdx.y;
  int t0 = blockIdx.x * 128;
  int cnt = ws_i[e * 16];
  if (t0 >= cnt) return;
  __shared__ u16 As[128][64];
  __shared__ u16 Bs[96][64];
  __shared__ int tok_s[128];
  int t = threadIdx.x;
  if (t < 128) tok_s[t] = bucket[e * CAPQ + min(t0 + t, cnt - 1)];
  __syncthreads();
  int w = t >> 6, l = t & 63;
  int lr = l & 15, lg = l >> 4;
  int wr = w >> 1, wc = w & 1;
  const u16* Bt = winT + (size_t)e * HD * CC;

  f32x4 acc[4][3];
  #pragma unroll
  for (int i = 0; i < 4; i++)
    #pragma unroll
    for (int j = 0; j < 3; j++) acc[i][j] = (f32x4)(0.f);

  int sr = t >> 3, sc = t & 7;
  int atok[4];
  #pragma unroll
  for (int i = 0; i < 4; i++) atok[i] = tok_s[i * 32 + sr];

  for (int kb = 0; kb < CC; kb += 64) {
    __syncthreads();
    #pragma unroll
    for (int i = 0; i < 4; i++) {
      int rr = i * 32 + sr;
      int ch = sc ^ (rr & 7);
      gload16(xb + (size_t)atok[i] * CC + kb + ch * 8, &As[rr][sc * 8]);
    }
    #pragma unroll
    for (int i = 0; i < 3; i++) {
      int rr = i * 32 + sr;
      int ch = sc ^ (rr & 7);
      gload16(Bt + (size_t)rr * CC + kb + ch * 8, &Bs[rr][sc * 8]);
    }
    __syncthreads();
    #pragma unroll
    for (int ks = 0; ks < 2; ks++) {
      s16x8 af[4], bf[3];
      #pragma unroll
      for (int i = 0; i < 4; i++)
        af[i] = *(const s16x8*)&As[wr * 64 + i * 16 + lr][8 * ((ks * 4 + lg) ^ (lr & 7))];
      #pragma unroll
      for (int j = 0; j < 3; j++)
        bf[j] = *(const s16x8*)&Bs[wc * 48 + j * 16 + lr][8 * ((ks * 4 + lg) ^ (lr & 7))];
      #pragma unroll
      for (int i = 0; i < 4; i++)
        #pragma unroll
        for (int j = 0; j < 3; j++)
          acc[i][j] = __builtin_amdgcn_mfma_f32_16x16x32_bf16(af[i], bf[j], acc[i][j], 0, 0, 0);
    }
  }
  #pragma unroll
  for (int i = 0; i < 4; i++)
    #pragma unroll
    for (int reg = 0; reg < 4; reg++) {
      int rr = wr * 64 + i * 16 + lg * 4 + reg;
      if (t0 + rr < cnt) {
        int tok = tok_s[rr];
        u16* qp = qall + (size_t)tok * EC + e * HD + wc * 48;
        #pragma unroll
        for (int j = 0; j < 3; j++)
          qp[j * 16 + lr] = f2b(acc[i][j][reg]);
      }
    }
}

// -------- kv projection -> kvbk (padded 128, pre-swizzled K) + vtb (V^T, pre-swizzled)
__global__ __launch_bounds__(256) void kvproj_kernel(
    const u16* __restrict__ xb, const u16* __restrict__ wkvT,
    u16* __restrict__ kvbk, u16* __restrict__ vtb)
{
  __shared__ u16 As[128][64];
  __shared__ u16 Bs[64][64];
  int t = threadIdx.x;
  int w = t >> 6, l = t & 63;
  int lr = l & 15, lg = l >> 4;
  int wr = w >> 1, wc = w & 1;
  int nwg = gridDim.x * gridDim.y;
  int logical = xcd_remap(blockIdx.y * gridDim.x + blockIdx.x, nwg);
  int col0 = (logical % gridDim.x) * 64, row0 = (logical / gridDim.x) * 128;

  f32x4 acc[4][2];
  #pragma unroll
  for (int i = 0; i < 4; i++)
    #pragma unroll
    for (int j = 0; j < 2; j++) acc[i][j] = (f32x4)(0.f);

  int sr = t >> 3, sc = t & 7;
  for (int kb = 0; kb < CC; kb += 64) {
    __syncthreads();
    #pragma unroll
    for (int i = 0; i < 4; i++) {
      int rr = i * 32 + sr;
      int ch = sc ^ (rr & 7);
      gload16(xb + (size_t)(row0 + rr) * CC + kb + ch * 8, &As[rr][sc * 8]);
    }
    #pragma unroll
    for (int i = 0; i < 2; i++) {
      int rr = i * 32 + sr;
      int ch = sc ^ (rr & 7);
      gload16(wkvT + (size_t)(col0 + rr) * CC + kb + ch * 8, &Bs[rr][sc * 8]);
    }
    __syncthreads();
    #pragma unroll
    for (int ks = 0; ks < 2; ks++) {
      s16x8 af[4], bf[2];
      #pragma unroll
      for (int i = 0; i < 4; i++)
        af[i] = *(const s16x8*)&As[wr * 64 + i * 16 + lr][8 * ((ks * 4 + lg) ^ (lr & 7))];
      #pragma unroll
      for (int j = 0; j < 2; j++)
        bf[j] = *(const s16x8*)&Bs[wc * 32 + j * 16 + lr][8 * ((ks * 4 + lg) ^ (lr & 7))];
      #pragma unroll
      for (int i = 0; i < 4; i++)
        #pragma unroll
        for (int j = 0; j < 2; j++)
          acc[i][j] = __builtin_amdgcn_mfma_f32_16x16x32_bf16(af[i], bf[j], acc[i][j], 0, 0, 0);
    }
  }
  #pragma unroll
  for (int i = 0; i < 4; i++)
    #pragma unroll
    for (int j = 0; j < 2; j++) {
      int cb = col0 + wc * 32 + j * 16 + lr;
      int rb = row0 + wr * 64 + i * 16 + lg * 4;
      if (cb < 96) {
        int ch = cb >> 3, ci = cb & 7;
        #pragma unroll
        for (int reg = 0; reg < 4; reg++) {
          int tok = rb + reg;
          kvbk[(size_t)tok * 128 + 8 * (ch ^ (tok & 7)) + ci] = f2b(acc[i][j][reg]);
        }
      } else {
        int d = cb - 96;
        u64 pk = (u64)f2b(acc[i][j][0]) | ((u64)f2b(acc[i][j][1]) << 16) |
                 ((u64)f2b(acc[i][j][2]) << 32) | ((u64)f2b(acc[i][j][3]) << 48);
        int blkbase = rb & ~63;
        int ch = (rb & 63) >> 3;
        *(u64*)&vtb[(size_t)d * NT + blkbase + 8 * (ch ^ (d & 7)) + (rb & 7)] = pk;
      }
    }
}

// ---- flash attention: 32x32x16 MFMA, 4 waves = 4 heads (z splits 8 heads) ----
__global__ __launch_bounds__(256, 2) void attn_kernel(
    const u16* __restrict__ qall, const u16* __restrict__ kvbk,
    const u16* __restrict__ vtb, const u8* __restrict__ eids,
    const float* __restrict__ gbuf, u16* __restrict__ z)
{
  __shared__ u16 Ks[2][64][128];
  __shared__ u16 Vt[2][96][64];
  int b = blockIdx.y;
  int tok0 = blockIdx.x * 32;
  int t = threadIdx.x;
  int w = t >> 6, l = t & 63;
  int h = blockIdx.z * 4 + w;
  int lo = l & 31, hi = l >> 5;

  s16x8 qf[6];
  {
    int tok = b * NN + tok0 + lo;
    int e = eids[tok * HH + h];
    const u16* qp = qall + (size_t)tok * EC + e * HD + hi * 8;
    #pragma unroll
    for (int ks = 0; ks < 6; ks++)
      qf[ks] = *(const s16x8*)(qp + ks * 16);
  }

  const u16* kvwin = kvbk + (size_t)(b * NN) * 128;
  const u16* vwin  = vtb + (size_t)(b * NN);

  f32x16 o0 = (f32x16)(0.f), o1 = (f32x16)(0.f), o2 = (f32x16)(0.f);
  float m = -1e30f, lsum = 0.f;   // m in log2 units

  #pragma unroll
  for (int k2 = 0; k2 < 4; k2++) {
    int c = t + k2 * 256;
    gload16(kvwin + c * 8, &Ks[0][0][0] + c * 8);
  }
  #pragma unroll
  for (int k2 = 0; k2 < 3; k2++) {
    int c = t + k2 * 256;
    gload16(vwin + (size_t)(c >> 3) * NT + (c & 7) * 8, &Vt[0][0][0] + c * 8);
  }

  for (int jt = 0; jt < 16; jt++) {
    __syncthreads();
    if (jt < 15) {
      int j0 = (jt + 1) * 64;
      int nb = (jt + 1) & 1;
      const u16* kb_ = kvwin + (size_t)j0 * 128;
      #pragma unroll
      for (int k2 = 0; k2 < 4; k2++) {
        int c = t + k2 * 256;
        gload16(kb_ + c * 8, &Ks[nb][0][0] + c * 8);
      }
      const u16* vb_ = vwin + j0;
      #pragma unroll
      for (int k2 = 0; k2 < 3; k2++) {
        int c = t + k2 * 256;
        gload16(vb_ + (size_t)(c >> 3) * NT + (c & 7) * 8, &Vt[nb][0][0] + c * 8);
      }
    }
    int buf = jt & 1;

    f32x16 s0 = (f32x16)(0.f), s1 = (f32x16)(0.f);
    #pragma unroll
    for (int ks = 0; ks < 6; ks++) {
      int pos = 8 * ((2 * ks + hi) ^ (lo & 7));
      s16x8 a0 = *(const s16x8*)&Ks[buf][lo][pos];
      s16x8 a1 = *(const s16x8*)&Ks[buf][32 + lo][pos];
      s0 = __builtin_amdgcn_mfma_f32_32x32x16_bf16(a0, qf[ks], s0, 0, 0, 0);
      s1 = __builtin_amdgcn_mfma_f32_32x32x16_bf16(a1, qf[ks], s1, 0, 0, 0);
    }

    float pm = fmaxf(s0[0], s0[1]);
    #pragma unroll
    for (int rg = 2; rg < 16; rg += 2) pm = fmaxf(pm, fmaxf(s0[rg], s0[rg + 1]));
    #pragma unroll
    for (int rg = 0; rg < 16; rg += 2) pm = fmaxf(pm, fmaxf(s1[rg], s1[rg + 1]));
    pm = fmaxf(pm, __shfl_xor(pm, 32));
    pm *= AL2;

    if (!__all(pm - m <= DEFER_THR)) {
      float mn = fmaxf(m, pm);
      float al = fexp2(m - mn);
      m = mn; lsum *= al;
      #pragma unroll
      for (int rg = 0; rg < 16; rg++) {
        int qrow = (rg & 3) + 8 * (rg >> 2) + 4 * hi;
        float alr = __shfl(al, qrow);
        o0[rg] *= alr; o1[rg] *= alr; o2[rg] *= alr;
      }
    }

    float ts = 0.f;
    u32 wpk[2][4][2];
    #pragma unroll
    for (int kb2 = 0; kb2 < 2; kb2++)
      #pragma unroll
      for (int rr = 0; rr < 4; rr++)
        #pragma unroll
        for (int pp = 0; pp < 2; pp++) {
          float sA = kb2 ? s1[rr * 4 + 2 * pp]     : s0[rr * 4 + 2 * pp];
          float sB = kb2 ? s1[rr * 4 + 2 * pp + 1] : s0[rr * 4 + 2 * pp + 1];
          float eA = fexp2(fmaf(sA, AL2, -m));
          float eB = fexp2(fmaf(sB, AL2, -m));
          ts += eA + eB;
          wpk[kb2][rr][pp] = cvtpk(eA, eB);
        }
    lsum += ts;

    s16x8 pa[4];
    #pragma unroll
    for (int ks = 0; ks < 4; ks++) {
      int kb2 = ks >> 1;
      int rlo = (ks & 1) * 2, rhi = rlo + 1;
      u32 own_lo0 = wpk[kb2][rlo][0], own_lo1 = wpk[kb2][rlo][1];
      u32 own_hi0 = wpk[kb2][rhi][0], own_hi1 = wpk[kb2][rhi][1];
      u32 send0 = hi ? own_lo0 : own_hi0;
      u32 send1 = hi ? own_lo1 : own_hi1;
      u32 recv0 = (u32)__shfl_xor((int)send0, 32);
      u32 recv1 = (u32)__shfl_xor((int)send1, 32);
      union { s16x8 v; u32 u[4]; } pu;
      pu.u[0] = hi ? recv0 : own_lo0;
      pu.u[1] = hi ? recv1 : own_lo1;
      pu.u[2] = hi ? own_hi0 : recv0;
      pu.u[3] = hi ? own_hi1 : recv1;
      pa[ks] = pu.v;
    }

    #pragma unroll
    for (int ks = 0; ks < 4; ks++) {
      int pos = 8 * ((2 * ks + hi) ^ (lo & 7));
      s16x8 v0 = *(const s16x8*)&Vt[buf][lo][pos];
      s16x8 v1 = *(const s16x8*)&Vt[buf][32 + lo][pos];
      s16x8 v2 = *(const s16x8*)&Vt[buf][64 + lo][pos];
      o0 = __builtin_amdgcn_mfma_f32_32x32x16_bf16(pa[ks], v0, o0, 0, 0, 0);
      o1 = __builtin_amdgcn_mfma_f32_32x32x16_bf16(pa[ks], v1, o1, 0, 0, 0);
      o2 = __builtin_amdgcn_mfma_f32_32x32x16_bf16(pa[ks], v2, o2, 0, 0, 0);
    }
  }

  float lt = lsum + __shfl_xor(lsum, 32);
  #pragma unroll
  for (int rg = 0; rg < 16; rg++) {
    int qrow = (rg & 3) + 8 * (rg >> 2) + 4 * hi;
    float lv = __shfl(lt, qrow);
    int tok = b * NN + tok0 + qrow;
    int slot = tok * HH + h;
    float scl = gbuf[slot] / lv;
    int e = eids[slot];
    u16* zp = z + (size_t)tok * EC + e * HD + lo;
    zp[0]  = f2b(o0[rg] * scl);
    zp[32] = f2b(o1[rg] * scl);
    zp[64] = f2b(o2[rg] * scl);
  }
}

// ---------------- aux loss ----------------
__global__ void aux_kernel(const float* __restrict__ ws_f,
                           const int* __restrict__ ws_i, float* __restrict__ out)
{
  if (threadIdx.x == 0 && blockIdx.x == 0) {
    float sw = 0.f;
    for (int e = 0; e < EE; e++) {
      float imp = ws_f[WS_IMP / 4 + e * 16] / (float)NT;
      float load = (float)ws_i[e * 16] / (float)(NT * HH);
      sw += imp * load;
    }
    float zl = ws_f[WS_ZSUM / 4] / (float)NT;
    out[(size_t)NT * CC] = 0.1f * ((float)EE * sw) + 0.001f * zl;
  }
}

extern "C" void kernel_launch(void* const* d_in, const int* in_sizes, int n_in,
                              void* d_out, int out_size, void* d_ws, size_t ws_size,
                              hipStream_t stream)
{
  const float* x    = (const float*)d_in[0];
  const float* Wg   = (const float*)d_in[1];
  const float* Win  = (const float*)d_in[2];
  const float* Wout = (const float*)d_in[3];
  const float* Wkv  = (const float*)d_in[4];
  const int*   task = (const int*)d_in[5];
  float* out = (float*)d_out;
  float* ws_f = (float*)d_ws;
  int*   ws_i = (int*)d_ws;
  u8*  eids = (u8*)((char*)d_ws + WS_EID);
  u16* kvbk = (u16*)((char*)d_ws + WS_KVK);
  u16* vtb  = (u16*)((char*)d_ws + WS_VT);
  u16* winT = (u16*)((char*)d_ws + WS_WIN);
  u16* woutT= (u16*)((char*)d_ws + WS_WOUT);
  u16* wkvT = (u16*)((char*)d_ws + WS_WKV);
  u16* qall = (u16*)((char*)d_ws + WS_QA);
  u16* z    = (u16*)((char*)d_ws + WS_Z);
  u16* xb   = (u16*)((char*)d_ws + WS_XB);
  int* bucket = (int*)((char*)d_ws + WS_BUCKET);

  hipMemsetAsync(d_ws, 0, 4096, stream);

  transpose_kernel<<<dim3(CC/32, HD/32, EE), 256, 0, stream>>>(Win, winT, CC, HD, CC*HD, CC, HD*CC);
  transpose_kernel<<<dim3(HD/32, CC/32, EE), 256, 0, stream>>>(Wout, woutT, HD, CC, HD*CC, EC, HD);
  transpose_kernel<<<dim3(CC/32, 192/32, 1), 256, 0, stream>>>(Wkv, wkvT, CC, 192, 0, CC, 0);

  gate_kernel<<<NT / 16, 256, 0, stream>>>(x, Wg, task, ws_f, ws_i, eids, xb, bucket);

  kvproj_kernel<<<dim3(3, NT/128), 256, 0, stream>>>(xb, wkvT, kvbk, vtb);
  qproj_kernel<<<dim3(NT/128, EE), 256, 0, stream>>>(xb, winT, ws_i, bucket, qall);

  hipMemsetAsync(z, 0, (size_t)NT * EC * 2, stream);   // xb+bucket dead; z aliases them

  attn_kernel<<<dim3(NN/32, BB, 2), 256, 0, stream>>>(qall, kvbk, vtb, eids, ws_f + WS_G/4, z);

  gemm_kernel<128, 64, true><<<dim3(CC/64, NT/128), 256, 0, stream>>>(
      z, woutT, out, NT, CC, EC);

  aux_kernel<<<1, 64, 0, stream>>>(ws_f, ws_i, out);
}

// Round 19
// 166.050 us; speedup vs baseline: 1.2431x; 1.0428x over previous
//
#include <hip/hip_runtime.h>
#include <hip/hip_bf16.h>
#include <math.h>

#define BB 8
#define NN 1024
#define CC 768
#define HH 8
#define HD 96
#define EE 24
#define NT (BB*NN)          // 8192 tokens
#define NSLOT (NT*HH)       // 65536 (token,h) slots
#define EC (EE*HD)          // 2304
#define CAPQ 8192           // per-expert bucket capacity
#define ASCALE 0.10206207261596575f  // 96^-0.5
#define AL2 0.14724446f              // ASCALE * log2(e)
#define DEFER_THR 11.5415603f        // 8 * log2(e)

typedef unsigned short u16;
typedef unsigned char u8;
typedef unsigned int u32;
typedef unsigned long long u64;
typedef __attribute__((ext_vector_type(8))) short s16x8;
typedef __attribute__((ext_vector_type(4))) float f32x4;
typedef __attribute__((ext_vector_type(16))) float f32x16;

__device__ __forceinline__ u16 f2b(float f) {  // RNE float->bf16 bits
  unsigned u = __builtin_bit_cast(unsigned, f);
  unsigned r = u + 0x7fffu + ((u >> 16) & 1u);
  return (u16)(r >> 16);
}

__device__ __forceinline__ float fexp2(float x) {  // native 2^x
  float r; asm("v_exp_f32 %0, %1" : "=v"(r) : "v"(x)); return r;
}

__device__ __forceinline__ u32 cvtpk(float a, float b) {  // HW RNE pack
  u32 d; asm("v_cvt_pk_bf16_f32 %0, %1, %2" : "=v"(d) : "v"(a), "v"(b)); return d;
}

__device__ __forceinline__ void gload16(const u16* g, u16* lds) {
  __builtin_amdgcn_global_load_lds(
      (const __attribute__((address_space(1))) void*)g,
      (__attribute__((address_space(3))) void*)lds, 16, 0, 0);
}

// bijective XCD remap (8 XCDs): contiguous logical chunks per XCD
__device__ __forceinline__ int xcd_remap(int bid, int nwg) {
  int q = nwg >> 3, r = nwg & 7;
  int xcd = bid & 7, idx = bid >> 3;
  return (xcd < r ? xcd * (q + 1) : r * (q + 1) + (xcd - r) * q) + idx;
}

// ws layout (bytes) — counters padded: one 64B cache line per counter
#define WS_CNT   0                             // 24 ints @ stride 16 (ws_i[e*16])
#define WS_IMP   1536                          // 24 f32 @ stride 16
#define WS_ZSUM  3072                          // 1 f32
#define WS_G     4096
#define WS_EID   (WS_G + NSLOT*4)
#define WS_KVK   (WS_EID + NSLOT)              // NT*128 u16 (K, padded+pre-swizzled)
#define WS_VT    (WS_KVK + NT*128*2)           // 96*NT u16 (V^T, in-block pre-swizzled)
#define WS_WIN   (WS_VT + (size_t)96*NT*2)
#define WS_WOUT  (WS_WIN + (size_t)EC*CC*2)
#define WS_WKV   (WS_WOUT + (size_t)CC*EC*2)
#define WS_QA    (WS_WKV + 192*CC*2)
#define WS_Z     (WS_QA + (size_t)NT*EC*2)
#define WS_XB    WS_Z                          // aliases z; xb dead before attn
#define WS_BUCKET (WS_Z + (size_t)16*1024*1024) // aliases z tail; dead before attn

// ---- gating: register-blocked fp32 GEMM (16 tok x 24 exp), 16-way k-split,
//      2-deep register-prefetch pipeline; softmax + top-8 + buckets; emits xb.
__global__ __launch_bounds__(256) void gate_kernel(
    const float* __restrict__ x, const float* __restrict__ Wg_all,
    const int* __restrict__ task_p, float* __restrict__ ws_f,
    int* __restrict__ ws_i, u8* __restrict__ eids, u16* __restrict__ xb,
    int* __restrict__ bucket)
{
  __shared__ float xs[16][68];
  __shared__ float wgt[24][68];
  __shared__ float scr[4][16][24];
  __shared__ float lgt[16][26];
  __shared__ float zlo[16];
  __shared__ int hist[EE];
  __shared__ int gbase[EE];

  int t = threadIdx.x;
  int w = t >> 6, l = t & 63;
  int pos = l & 15;
  int tg = pos >> 2, eg = pos & 3;
  int kq_low = (l >> 4) & 3;
  int cq = 16 * w + 4 * kq_low;
  int tok0 = blockIdx.x * 16;
  const float* Wg = Wg_all + (size_t)task_p[0] * CC * EE;

  if (t < EE) hist[t] = 0;

  int rr_ = t >> 4, cc_ = (t & 15) << 2;
  int wkk_[6], we_[6];
  #pragma unroll
  for (int i = 0; i < 6; i++) {
    int f = t + i * 256;
    wkk_[i] = f / 24; we_[i] = f - wkk_[i] * 24;
  }

  float acc[4][6];
  #pragma unroll
  for (int i = 0; i < 4; i++)
    #pragma unroll
    for (int j = 0; j < 6; j++) acc[i][j] = 0.f;

  float4 xv[2]; float wgv[2][6];
  #pragma unroll
  for (int p = 0; p < 2; p++) {
    int kb = p * 64;
    xv[p] = *(const float4*)&x[(size_t)(tok0 + rr_) * CC + kb + cc_];
    #pragma unroll
    for (int i = 0; i < 6; i++)
      wgv[p][i] = Wg[(size_t)(kb + wkk_[i]) * EE + we_[i]];
  }

  #pragma unroll
  for (int s = 0; s < 12; s++) {
    int sl = s & 1;
    __syncthreads();
    *(float4*)&xs[rr_][cc_] = xv[sl];
    {
      float4 v = xv[sl];
      u64 pk = (u64)f2b(v.x) | ((u64)f2b(v.y) << 16) |
               ((u64)f2b(v.z) << 32) | ((u64)f2b(v.w) << 48);
      *(u64*)&xb[(size_t)(tok0 + rr_) * CC + s * 64 + cc_] = pk;
    }
    #pragma unroll
    for (int i = 0; i < 6; i++) wgt[we_[i]][wkk_[i]] = wgv[sl][i];
    if (s + 2 < 12) {
      int kb = (s + 2) * 64;
      xv[sl] = *(const float4*)&x[(size_t)(tok0 + rr_) * CC + kb + cc_];
      #pragma unroll
      for (int i = 0; i < 6; i++)
        wgv[sl][i] = Wg[(size_t)(kb + wkk_[i]) * EE + we_[i]];
    }
    __syncthreads();
    float4 x4[4];
    #pragma unroll
    for (int i = 0; i < 4; i++) x4[i] = *(const float4*)&xs[tg * 4 + i][cq];
    #pragma unroll
    for (int j = 0; j < 6; j++) {
      float4 w4 = *(const float4*)&wgt[eg * 6 + j][cq];
      #pragma unroll
      for (int i = 0; i < 4; i++) {
        float a = acc[i][j];
        a = fmaf(x4[i].x, w4.x, a);
        a = fmaf(x4[i].y, w4.y, a);
        a = fmaf(x4[i].z, w4.z, a);
        a = fmaf(x4[i].w, w4.w, a);
        acc[i][j] = a;
      }
    }
  }
  #pragma unroll
  for (int i = 0; i < 4; i++)
    #pragma unroll
    for (int j = 0; j < 6; j++) {
      float v = acc[i][j];
      v += __shfl_xor(v, 16);
      v += __shfl_xor(v, 32);
      acc[i][j] = v;
    }
  if (l < 16) {
    #pragma unroll
    for (int i = 0; i < 4; i++)
      #pragma unroll
      for (int j = 0; j < 6; j++) scr[w][pos][i * 6 + j] = acc[i][j];
  }
  __syncthreads();
  if (w == 0 && l < 16) {
    #pragma unroll
    for (int i = 0; i < 4; i++)
      #pragma unroll
      for (int j = 0; j < 6; j++) {
        float s = scr[0][pos][i * 6 + j] + scr[1][pos][i * 6 + j] +
                  scr[2][pos][i * 6 + j] + scr[3][pos][i * 6 + j];
        lgt[tg * 4 + i][eg * 6 + j] = s;
      }
  }
  __syncthreads();

  int my_e[8], loc[8];
  if (t < 16) {
    int token = tok0 + t;
    float lg[EE];
    #pragma unroll
    for (int e = 0; e < EE; e++) lg[e] = lgt[t][e];
    float mx = lg[0];
    #pragma unroll
    for (int e = 1; e < EE; e++) mx = fmaxf(mx, lg[e]);
    float se = 0.f; float probs[EE];
    #pragma unroll
    for (int e = 0; e < EE; e++) { probs[e] = __expf(lg[e] - mx); se += probs[e]; }
    float inv = 1.f / se;
    #pragma unroll
    for (int e = 0; e < EE; e++) probs[e] *= inv;
    float lse = mx + __logf(se);
    zlo[t] = lse * lse;

    unsigned taken = 0u;
    float gsum = 0.f;
    float my_g[8];
    #pragma unroll
    for (int h = 0; h < HH; h++) {
      float best = -1.f; int bi = 0;
      #pragma unroll
      for (int e = 0; e < EE; e++) {
        bool ok = !((taken >> e) & 1u) && (probs[e] > best);
        best = ok ? probs[e] : best;
        bi   = ok ? e : bi;
      }
      taken |= 1u << bi;
      gsum += best;
      my_g[h] = best; my_e[h] = bi;
    }
    float ginv = 1.f / (gsum + 1e-6f);
    float4 g0, g1;
    g0.x = my_g[0] * ginv; g0.y = my_g[1] * ginv; g0.z = my_g[2] * ginv; g0.w = my_g[3] * ginv;
    g1.x = my_g[4] * ginv; g1.y = my_g[5] * ginv; g1.z = my_g[6] * ginv; g1.w = my_g[7] * ginv;
    float* gbuf = ws_f + WS_G / 4;
    *(float4*)&gbuf[(size_t)token * HH]     = g0;
    *(float4*)&gbuf[(size_t)token * HH + 4] = g1;
    u64 pk = 0;
    #pragma unroll
    for (int h = 0; h < HH; h++) pk |= (u64)(u8)my_e[h] << (8 * h);
    *(u64*)&eids[(size_t)token * HH] = pk;
    #pragma unroll
    for (int h = 0; h < HH; h++) loc[h] = atomicAdd(&hist[my_e[h]], 1);
    #pragma unroll
    for (int e = 0; e < EE; e++) lgt[t][e] = probs[e];
  }
  __syncthreads();
  if (t < EE) {
    float s = 0.f;
    #pragma unroll 8
    for (int rr = 0; rr < 16; rr++) s += lgt[rr][t];
    atomicAdd(ws_f + WS_IMP / 4 + t * 16, s);
    gbase[t] = atomicAdd(&ws_i[t * 16], hist[t]);
  } else if (t == 32) {
    float s = 0.f;
    #pragma unroll 8
    for (int rr = 0; rr < 16; rr++) s += zlo[rr];
    atomicAdd(ws_f + WS_ZSUM / 4, s);
  }
  __syncthreads();
  if (t < 16) {
    int token = tok0 + t;
    #pragma unroll
    for (int h = 0; h < HH; h++)
      bucket[my_e[h] * CAPQ + gbase[my_e[h]] + loc[h]] = token;
  }
}

// -------- batched transpose + f32->bf16 --------
__global__ __launch_bounds__(256) void transpose_kernel(
    const float* __restrict__ src, u16* __restrict__ dst,
    int R, int C, int sB, int dR, int dB)
{
  __shared__ float tile[32][33];
  int e = blockIdx.z;
  const float* s = src + (size_t)e * sB;
  int t = threadIdx.x;
  int tr = t >> 5, tc = t & 31;
  #pragma unroll
  for (int i = 0; i < 4; i++) {
    int r = blockIdx.x * 32 + tr + i * 8;
    int c = blockIdx.y * 32 + tc;
    tile[tr + i * 8][tc] = s[(size_t)r * C + c];
  }
  __syncthreads();
  #pragma unroll
  for (int i = 0; i < 4; i++) {
    int sc = blockIdx.y * 32 + tr + i * 8;
    int sr = blockIdx.x * 32 + tc;
    dst[(size_t)e * dB + (size_t)sc * dR + sr] = f2b(tile[tc][tr + i * 8]);
  }
}

// -------- dense MFMA GEMM (oproj), bf16 A/B, gload_lds, XCD-swizzled --------
template<int BM, int BN, bool OUT_F32>
__global__ __launch_bounds__(256) void gemm_kernel(
    const u16* __restrict__ A, const u16* __restrict__ Bt,
    void* __restrict__ Cp, int M, int N, int K)
{
  constexpr int WM = BM / 2, WN = BN / 2;
  constexpr int FM = WM / 16, FN = WN / 16;
  __shared__ u16 As[BM][64];
  __shared__ u16 Bs[BN][64];
  int t = threadIdx.x;
  int w = t >> 6, l = t & 63;
  int lr = l & 15, lg = l >> 4;
  int wr = w >> 1, wc = w & 1;
  int nwg = gridDim.x * gridDim.y;
  int logical = xcd_remap(blockIdx.y * gridDim.x + blockIdx.x, nwg);
  int col0 = (logical % gridDim.x) * BN, row0 = (logical / gridDim.x) * BM;

  f32x4 acc[FM][FN];
  #pragma unroll
  for (int i = 0; i < FM; i++)
    #pragma unroll
    for (int j = 0; j < FN; j++) acc[i][j] = (f32x4)(0.f);

  int sr = t >> 3;
  int sc = t & 7;
  for (int kb = 0; kb < K; kb += 64) {
    __syncthreads();
    #pragma unroll
    for (int i = 0; i < BM / 32; i++) {
      int rr = i * 32 + sr;
      int ch = sc ^ (rr & 7);
      gload16(A + (size_t)(row0 + rr) * K + kb + ch * 8, &As[rr][sc * 8]);
    }
    #pragma unroll
    for (int i = 0; i < BN / 32; i++) {
      int rr = i * 32 + sr;
      int ch = sc ^ (rr & 7);
      gload16(Bt + (size_t)(col0 + rr) * K + kb + ch * 8, &Bs[rr][sc * 8]);
    }
    __syncthreads();
    #pragma unroll
    for (int ks = 0; ks < 2; ks++) {
      s16x8 af[FM], bf[FN];
      #pragma unroll
      for (int i = 0; i < FM; i++)
        af[i] = *(const s16x8*)&As[wr * WM + i * 16 + lr][8 * ((ks * 4 + lg) ^ (lr & 7))];
      #pragma unroll
      for (int j = 0; j < FN; j++)
        bf[j] = *(const s16x8*)&Bs[wc * WN + j * 16 + lr][8 * ((ks * 4 + lg) ^ (lr & 7))];
      #pragma unroll
      for (int i = 0; i < FM; i++)
        #pragma unroll
        for (int j = 0; j < FN; j++)
          acc[i][j] = __builtin_amdgcn_mfma_f32_16x16x32_bf16(af[i], bf[j], acc[i][j], 0, 0, 0);
    }
  }
  #pragma unroll
  for (int i = 0; i < FM; i++)
    #pragma unroll
    for (int j = 0; j < FN; j++)
      #pragma unroll
      for (int reg = 0; reg < 4; reg++) {
        int rr = row0 + wr * WM + i * 16 + lg * 4 + reg;
        int cc = col0 + wc * WN + j * 16 + lr;
        if (OUT_F32) ((float*)Cp)[(size_t)rr * N + cc] = acc[i][j][reg];
        else ((u16*)Cp)[(size_t)rr * N + cc] = f2b(acc[i][j][reg]);
      }
}

// -------- gathered q projection: per-expert tiles, 128 rows x 96 cols, K=768
__global__ __launch_bounds__(256) void qproj_kernel(
    const u16* __restrict__ xb, const u16* __restrict__ winT,
    const int* __restrict__ ws_i, const int* __restrict__ bucket,
    u16* __restrict__ qall)
{
  int e = blockIdx.y;
  int t0 = blockIdx.x * 128;
  int cnt = ws_i[e * 16];
  if (t0 >= cnt) return;
  __shared__ u16 As[128][64];
  __shared__ u16 Bs[96][64];
  __shared__ int tok_s[128];
  int t = threadIdx.x;
  if (t < 128) tok_s[t] = bucket[e * CAPQ + min(t0 + t, cnt - 1)];
  __syncthreads();
  int w = t >> 6, l = t & 63;
  int lr = l & 15, lg = l >> 4;
  int wr = w >> 1, wc = w & 1;
  const u16* Bt = winT + (size_t)e * HD * CC;

  f32x4 acc[4][3];
  #pragma unroll
  for (int i = 0; i < 4; i++)
    #pragma unroll
    for (int j = 0; j < 3; j++) acc[i][j] = (f32x4)(0.f);

  int sr = t >> 3, sc = t & 7;
  int atok[4];
  #pragma unroll
  for (int i = 0; i < 4; i++) atok[i] = tok_s[i * 32 + sr];

  for (int kb = 0; kb < CC; kb += 64) {
    __syncthreads();
    #pragma unroll
    for (int i = 0; i < 4; i++) {
      int rr = i * 32 + sr;
      int ch = sc ^ (rr & 7);
      gload16(xb + (size_t)atok[i] * CC + kb + ch * 8, &As[rr][sc * 8]);
    }
    #pragma unroll
    for (int i = 0; i < 3; i++) {
      int rr = i * 32 + sr;
      int ch = sc ^ (rr & 7);
      gload16(Bt + (size_t)rr * CC + kb + ch * 8, &Bs[rr][sc * 8]);
    }
    __syncthreads();
    #pragma unroll
    for (int ks = 0; ks < 2; ks++) {
      s16x8 af[4], bf[3];
      #pragma unroll
      for (int i = 0; i < 4; i++)
        af[i] = *(const s16x8*)&As[wr * 64 + i * 16 + lr][8 * ((ks * 4 + lg) ^ (lr & 7))];
      #pragma unroll
      for (int j = 0; j < 3; j++)
        bf[j] = *(const s16x8*)&Bs[wc * 48 + j * 16 + lr][8 * ((ks * 4 + lg) ^ (lr & 7))];
      #pragma unroll
      for (int i = 0; i < 4; i++)
        #pragma unroll
        for (int j = 0; j < 3; j++)
          acc[i][j] = __builtin_amdgcn_mfma_f32_16x16x32_bf16(af[i], bf[j], acc[i][j], 0, 0, 0);
    }
  }
  #pragma unroll
  for (int i = 0; i < 4; i++)
    #pragma unroll
    for (int reg = 0; reg < 4; reg++) {
      int rr = wr * 64 + i * 16 + lg * 4 + reg;
      if (t0 + rr < cnt) {
        int tok = tok_s[rr];
        u16* qp = qall + (size_t)tok * EC + e * HD + wc * 48;
        #pragma unroll
        for (int j = 0; j < 3; j++)
          qp[j * 16 + lr] = f2b(acc[i][j][reg]);
      }
    }
}

// -------- kv projection -> kvbk (padded 128, pre-swizzled K) + vtb (V^T, pre-swizzled)
__global__ __launch_bounds__(256) void kvproj_kernel(
    const u16* __restrict__ xb, const u16* __restrict__ wkvT,
    u16* __restrict__ kvbk, u16* __restrict__ vtb)
{
  __shared__ u16 As[128][64];
  __shared__ u16 Bs[64][64];
  int t = threadIdx.x;
  int w = t >> 6, l = t & 63;
  int lr = l & 15, lg = l >> 4;
  int wr = w >> 1, wc = w & 1;
  int nwg = gridDim.x * gridDim.y;
  int logical = xcd_remap(blockIdx.y * gridDim.x + blockIdx.x, nwg);
  int col0 = (logical % gridDim.x) * 64, row0 = (logical / gridDim.x) * 128;

  f32x4 acc[4][2];
  #pragma unroll
  for (int i = 0; i < 4; i++)
    #pragma unroll
    for (int j = 0; j < 2; j++) acc[i][j] = (f32x4)(0.f);

  int sr = t >> 3, sc = t & 7;
  for (int kb = 0; kb < CC; kb += 64) {
    __syncthreads();
    #pragma unroll
    for (int i = 0; i < 4; i++) {
      int rr = i * 32 + sr;
      int ch = sc ^ (rr & 7);
      gload16(xb + (size_t)(row0 + rr) * CC + kb + ch * 8, &As[rr][sc * 8]);
    }
    #pragma unroll
    for (int i = 0; i < 2; i++) {
      int rr = i * 32 + sr;
      int ch = sc ^ (rr & 7);
      gload16(wkvT + (size_t)(col0 + rr) * CC + kb + ch * 8, &Bs[rr][sc * 8]);
    }
    __syncthreads();
    #pragma unroll
    for (int ks = 0; ks < 2; ks++) {
      s16x8 af[4], bf[2];
      #pragma unroll
      for (int i = 0; i < 4; i++)
        af[i] = *(const s16x8*)&As[wr * 64 + i * 16 + lr][8 * ((ks * 4 + lg) ^ (lr & 7))];
      #pragma unroll
      for (int j = 0; j < 2; j++)
        bf[j] = *(const s16x8*)&Bs[wc * 32 + j * 16 + lr][8 * ((ks * 4 + lg) ^ (lr & 7))];
      #pragma unroll
      for (int i = 0; i < 4; i++)
        #pragma unroll
        for (int j = 0; j < 2; j++)
          acc[i][j] = __builtin_amdgcn_mfma_f32_16x16x32_bf16(af[i], bf[j], acc[i][j], 0, 0, 0);
    }
  }
  #pragma unroll
  for (int i = 0; i < 4; i++)
    #pragma unroll
    for (int j = 0; j < 2; j++) {
      int cb = col0 + wc * 32 + j * 16 + lr;
      int rb = row0 + wr * 64 + i * 16 + lg * 4;
      if (cb < 96) {
        int ch = cb >> 3, ci = cb & 7;
        #pragma unroll
        for (int reg = 0; reg < 4; reg++) {
          int tok = rb + reg;
          kvbk[(size_t)tok * 128 + 8 * (ch ^ (tok & 7)) + ci] = f2b(acc[i][j][reg]);
        }
      } else {
        int d = cb - 96;
        u64 pk = (u64)f2b(acc[i][j][0]) | ((u64)f2b(acc[i][j][1]) << 16) |
                 ((u64)f2b(acc[i][j][2]) << 32) | ((u64)f2b(acc[i][j][3]) << 48);
        int blkbase = rb & ~63;
        int ch = (rb & 63) >> 3;
        *(u64*)&vtb[(size_t)d * NT + blkbase + 8 * (ch ^ (d & 7)) + (rb & 7)] = pk;
      }
    }
}

// ---- flash attention: 32x32x16 MFMA, 4 waves = 4 heads (z splits 8 heads) ----
// blockIdx.z==0 blocks also zero-fill the 16 unselected expert slots of z
// (replaces the 37.7 MB memset; selected slots written by both z-halves).
__global__ __launch_bounds__(256, 2) void attn_kernel(
    const u16* __restrict__ qall, const u16* __restrict__ kvbk,
    const u16* __restrict__ vtb, const u8* __restrict__ eids,
    const float* __restrict__ gbuf, u16* __restrict__ z)
{
  __shared__ u16 Ks[2][64][128];
  __shared__ u16 Vt[2][96][64];
  int b = blockIdx.y;
  int tok0 = blockIdx.x * 32;
  int t = threadIdx.x;
  int w = t >> 6, l = t & 63;
  int h = blockIdx.z * 4 + w;
  int lo = l & 31, hi = l >> 5;

  s16x8 qf[6];
  {
    int tok = b * NN + tok0 + lo;
    int e = eids[tok * HH + h];
    const u16* qp = qall + (size_t)tok * EC + e * HD + hi * 8;
    #pragma unroll
    for (int ks = 0; ks < 6; ks++)
      qf[ks] = *(const s16x8*)(qp + ks * 16);
  }

  // zero unselected expert slots (z=0 blocks only; disjoint from all writes)
  if (blockIdx.z == 0) {
    int tk = t >> 3, s8 = t & 7;
    int tok = b * NN + tok0 + tk;
    u64 pk = *(const u64*)&eids[(size_t)tok * HH];
    u32 msk = 0;
    #pragma unroll
    for (int hh = 0; hh < 8; hh++) msk |= 1u << ((pk >> (8 * hh)) & 255u);
    u64* zrow = (u64*)(z + (size_t)tok * EC);
    #pragma unroll
    for (int e = 0; e < EE; e++) {
      if (!((msk >> e) & 1u)) {
        u64* p = zrow + e * 24 + s8 * 3;
        p[0] = 0; p[1] = 0; p[2] = 0;
      }
    }
  }

  const u16* kvwin = kvbk + (size_t)(b * NN) * 128;
  const u16* vwin  = vtb + (size_t)(b * NN);

  f32x16 o0 = (f32x16)(0.f), o1 = (f32x16)(0.f), o2 = (f32x16)(0.f);
  float m = -1e30f, lsum = 0.f;   // m in log2 units

  #pragma unroll
  for (int k2 = 0; k2 < 4; k2++) {
    int c = t + k2 * 256;
    gload16(kvwin + c * 8, &Ks[0][0][0] + c * 8);
  }
  #pragma unroll
  for (int k2 = 0; k2 < 3; k2++) {
    int c = t + k2 * 256;
    gload16(vwin + (size_t)(c >> 3) * NT + (c & 7) * 8, &Vt[0][0][0] + c * 8);
  }

  for (int jt = 0; jt < 16; jt++) {
    __syncthreads();
    if (jt < 15) {
      int j0 = (jt + 1) * 64;
      int nb = (jt + 1) & 1;
      const u16* kb_ = kvwin + (size_t)j0 * 128;
      #pragma unroll
      for (int k2 = 0; k2 < 4; k2++) {
        int c = t + k2 * 256;
        gload16(kb_ + c * 8, &Ks[nb][0][0] + c * 8);
      }
      const u16* vb_ = vwin + j0;
      #pragma unroll
      for (int k2 = 0; k2 < 3; k2++) {
        int c = t + k2 * 256;
        gload16(vb_ + (size_t)(c >> 3) * NT + (c & 7) * 8, &Vt[nb][0][0] + c * 8);
      }
    }
    int buf = jt & 1;

    f32x16 s0 = (f32x16)(0.f), s1 = (f32x16)(0.f);
    #pragma unroll
    for (int ks = 0; ks < 6; ks++) {
      int pos = 8 * ((2 * ks + hi) ^ (lo & 7));
      s16x8 a0 = *(const s16x8*)&Ks[buf][lo][pos];
      s16x8 a1 = *(const s16x8*)&Ks[buf][32 + lo][pos];
      s0 = __builtin_amdgcn_mfma_f32_32x32x16_bf16(a0, qf[ks], s0, 0, 0, 0);
      s1 = __builtin_amdgcn_mfma_f32_32x32x16_bf16(a1, qf[ks], s1, 0, 0, 0);
    }

    float pm = fmaxf(s0[0], s0[1]);
    #pragma unroll
    for (int rg = 2; rg < 16; rg += 2) pm = fmaxf(pm, fmaxf(s0[rg], s0[rg + 1]));
    #pragma unroll
    for (int rg = 0; rg < 16; rg += 2) pm = fmaxf(pm, fmaxf(s1[rg], s1[rg + 1]));
    pm = fmaxf(pm, __shfl_xor(pm, 32));
    pm *= AL2;

    if (!__all(pm - m <= DEFER_THR)) {
      float mn = fmaxf(m, pm);
      float al = fexp2(m - mn);
      m = mn; lsum *= al;
      #pragma unroll
      for (int rg = 0; rg < 16; rg++) {
        int qrow = (rg & 3) + 8 * (rg >> 2) + 4 * hi;
        float alr = __shfl(al, qrow);
        o0[rg] *= alr; o1[rg] *= alr; o2[rg] *= alr;
      }
    }

    float ts = 0.f;
    u32 wpk[2][4][2];
    #pragma unroll
    for (int kb2 = 0; kb2 < 2; kb2++)
      #pragma unroll
      for (int rr = 0; rr < 4; rr++)
        #pragma unroll
        for (int pp = 0; pp < 2; pp++) {
          float sA = kb2 ? s1[rr * 4 + 2 * pp]     : s0[rr * 4 + 2 * pp];
          float sB = kb2 ? s1[rr * 4 + 2 * pp + 1] : s0[rr * 4 + 2 * pp + 1];
          float eA = fexp2(fmaf(sA, AL2, -m));
          float eB = fexp2(fmaf(sB, AL2, -m));
          ts += eA + eB;
          wpk[kb2][rr][pp] = cvtpk(eA, eB);
        }
    lsum += ts;

    s16x8 pa[4];
    #pragma unroll
    for (int ks = 0; ks < 4; ks++) {
      int kb2 = ks >> 1;
      int rlo = (ks & 1) * 2, rhi = rlo + 1;
      u32 own_lo0 = wpk[kb2][rlo][0], own_lo1 = wpk[kb2][rlo][1];
      u32 own_hi0 = wpk[kb2][rhi][0], own_hi1 = wpk[kb2][rhi][1];
      u32 send0 = hi ? own_lo0 : own_hi0;
      u32 send1 = hi ? own_lo1 : own_hi1;
      u32 recv0 = (u32)__shfl_xor((int)send0, 32);
      u32 recv1 = (u32)__shfl_xor((int)send1, 32);
      union { s16x8 v; u32 u[4]; } pu;
      pu.u[0] = hi ? recv0 : own_lo0;
      pu.u[1] = hi ? recv1 : own_lo1;
      pu.u[2] = hi ? own_hi0 : recv0;
      pu.u[3] = hi ? own_hi1 : recv1;
      pa[ks] = pu.v;
    }

    #pragma unroll
    for (int ks = 0; ks < 4; ks++) {
      int pos = 8 * ((2 * ks + hi) ^ (lo & 7));
      s16x8 v0 = *(const s16x8*)&Vt[buf][lo][pos];
      s16x8 v1 = *(const s16x8*)&Vt[buf][32 + lo][pos];
      s16x8 v2 = *(const s16x8*)&Vt[buf][64 + lo][pos];
      o0 = __builtin_amdgcn_mfma_f32_32x32x16_bf16(pa[ks], v0, o0, 0, 0, 0);
      o1 = __builtin_amdgcn_mfma_f32_32x32x16_bf16(pa[ks], v1, o1, 0, 0, 0);
      o2 = __builtin_amdgcn_mfma_f32_32x32x16_bf16(pa[ks], v2, o2, 0, 0, 0);
    }
  }

  float lt = lsum + __shfl_xor(lsum, 32);
  #pragma unroll
  for (int rg = 0; rg < 16; rg++) {
    int qrow = (rg & 3) + 8 * (rg >> 2) + 4 * hi;
    float lv = __shfl(lt, qrow);
    int tok = b * NN + tok0 + qrow;
    int slot = tok * HH + h;
    float scl = gbuf[slot] / lv;
    int e = eids[slot];
    u16* zp = z + (size_t)tok * EC + e * HD + lo;
    zp[0]  = f2b(o0[rg] * scl);
    zp[32] = f2b(o1[rg] * scl);
    zp[64] = f2b(o2[rg] * scl);
  }
}

// ---------------- aux loss ----------------
__global__ void aux_kernel(const float* __restrict__ ws_f,
                           const int* __restrict__ ws_i, float* __restrict__ out)
{
  if (threadIdx.x == 0 && blockIdx.x == 0) {
    float sw = 0.f;
    for (int e = 0; e < EE; e++) {
      float imp = ws_f[WS_IMP / 4 + e * 16] / (float)NT;
      float load = (float)ws_i[e * 16] / (float)(NT * HH);
      sw += imp * load;
    }
    float zl = ws_f[WS_ZSUM / 4] / (float)NT;
    out[(size_t)NT * CC] = 0.1f * ((float)EE * sw) + 0.001f * zl;
  }
}

extern "C" void kernel_launch(void* const* d_in, const int* in_sizes, int n_in,
                              void* d_out, int out_size, void* d_ws, size_t ws_size,
                              hipStream_t stream)
{
  const float* x    = (const float*)d_in[0];
  const float* Wg   = (const float*)d_in[1];
  const float* Win  = (const float*)d_in[2];
  const float* Wout = (const float*)d_in[3];
  const float* Wkv  = (const float*)d_in[4];
  const int*   task = (const int*)d_in[5];
  float* out = (float*)d_out;
  float* ws_f = (float*)d_ws;
  int*   ws_i = (int*)d_ws;
  u8*  eids = (u8*)((char*)d_ws + WS_EID);
  u16* kvbk = (u16*)((char*)d_ws + WS_KVK);
  u16* vtb  = (u16*)((char*)d_ws + WS_VT);
  u16* winT = (u16*)((char*)d_ws + WS_WIN);
  u16* woutT= (u16*)((char*)d_ws + WS_WOUT);
  u16* wkvT = (u16*)((char*)d_ws + WS_WKV);
  u16* qall = (u16*)((char*)d_ws + WS_QA);
  u16* z    = (u16*)((char*)d_ws + WS_Z);
  u16* xb   = (u16*)((char*)d_ws + WS_XB);
  int* bucket = (int*)((char*)d_ws + WS_BUCKET);

  hipMemsetAsync(d_ws, 0, 4096, stream);

  transpose_kernel<<<dim3(CC/32, HD/32, EE), 256, 0, stream>>>(Win, winT, CC, HD, CC*HD, CC, HD*CC);
  transpose_kernel<<<dim3(HD/32, CC/32, EE), 256, 0, stream>>>(Wout, woutT, HD, CC, HD*CC, EC, HD);
  transpose_kernel<<<dim3(CC/32, 192/32, 1), 256, 0, stream>>>(Wkv, wkvT, CC, 192, 0, CC, 0);

  gate_kernel<<<NT / 16, 256, 0, stream>>>(x, Wg, task, ws_f, ws_i, eids, xb, bucket);

  kvproj_kernel<<<dim3(3, NT/128), 256, 0, stream>>>(xb, wkvT, kvbk, vtb);
  qproj_kernel<<<dim3(NT/128, EE), 256, 0, stream>>>(xb, winT, ws_i, bucket, qall);

  // z zero-fill folded into attn (z=0 blocks); xb/bucket dead by attn time.
  attn_kernel<<<dim3(NN/32, BB, 2), 256, 0, stream>>>(qall, kvbk, vtb, eids, ws_f + WS_G/4, z);

  gemm_kernel<128, 64, true><<<dim3(CC/64, NT/128), 256, 0, stream>>>(
      z, woutT, out, NT, CC, EC);

  aux_kernel<<<1, 64, 0, stream>>>(ws_f, ws_i, out);
}

// Round 20
// 165.613 us; speedup vs baseline: 1.2464x; 1.0026x over previous
//
#include <hip/hip_runtime.h>
#include <hip/hip_bf16.h>
#include <math.h>

#define BB 8
#define NN 1024
#define CC 768
#define HH 8
#define HD 96
#define EE 24
#define NT (BB*NN)          // 8192 tokens
#define NSLOT (NT*HH)       // 65536 (token,h) slots
#define EC (EE*HD)          // 2304
#define CAPQ 8192           // per-expert bucket capacity
#define ASCALE 0.10206207261596575f  // 96^-0.5
#define AL2 0.14724446f              // ASCALE * log2(e)
#define DEFER_THR 11.5415603f        // 8 * log2(e)

typedef unsigned short u16;
typedef unsigned char u8;
typedef unsigned int u32;
typedef unsigned long long u64;
typedef __attribute__((ext_vector_type(8))) short s16x8;
typedef __attribute__((ext_vector_type(4))) float f32x4;
typedef __attribute__((ext_vector_type(16))) float f32x16;

__device__ __forceinline__ u16 f2b(float f) {  // RNE float->bf16 bits
  unsigned u = __builtin_bit_cast(unsigned, f);
  unsigned r = u + 0x7fffu + ((u >> 16) & 1u);
  return (u16)(r >> 16);
}

__device__ __forceinline__ float fexp2(float x) {  // native 2^x
  float r; asm("v_exp_f32 %0, %1" : "=v"(r) : "v"(x)); return r;
}

__device__ __forceinline__ u32 cvtpk(float a, float b) {  // HW RNE pack
  u32 d; asm("v_cvt_pk_bf16_f32 %0, %1, %2" : "=v"(d) : "v"(a), "v"(b)); return d;
}

__device__ __forceinline__ void gload16(const u16* g, u16* lds) {
  __builtin_amdgcn_global_load_lds(
      (const __attribute__((address_space(1))) void*)g,
      (__attribute__((address_space(3))) void*)lds, 16, 0, 0);
}

// bijective XCD remap (8 XCDs): contiguous logical chunks per XCD
__device__ __forceinline__ int xcd_remap(int bid, int nwg) {
  int q = nwg >> 3, r = nwg & 7;
  int xcd = bid & 7, idx = bid >> 3;
  return (xcd < r ? xcd * (q + 1) : r * (q + 1) + (xcd - r) * q) + idx;
}

// ws layout (bytes) — counters padded: one 64B cache line per counter
#define WS_CNT   0                             // 24 ints @ stride 16 (ws_i[e*16])
#define WS_IMP   1536                          // 24 f32 @ stride 16
#define WS_ZSUM  3072                          // 1 f32
#define WS_G     4096
#define WS_EID   (WS_G + NSLOT*4)
#define WS_KVK   (WS_EID + NSLOT)              // NT*128 u16 (K, padded+pre-swizzled)
#define WS_VT    (WS_KVK + NT*128*2)           // 96*NT u16 (V^T, in-block pre-swizzled)
#define WS_WIN   (WS_VT + (size_t)96*NT*2)
#define WS_WOUT  (WS_WIN + (size_t)EC*CC*2)
#define WS_WKV   (WS_WOUT + (size_t)CC*EC*2)
#define WS_QA    (WS_WKV + 192*CC*2)
#define WS_Z     (WS_QA + (size_t)NT*EC*2)
#define WS_XB    WS_Z                          // aliases z; xb dead before attn
#define WS_BUCKET (WS_Z + (size_t)16*1024*1024) // aliases z tail; dead before attn

// ---- gating: register-blocked fp32 GEMM (16 tok x 24 exp), 16-way k-split,
//      2-deep register-prefetch pipeline; softmax + top-8 + buckets; emits xb.
__global__ __launch_bounds__(256) void gate_kernel(
    const float* __restrict__ x, const float* __restrict__ Wg_all,
    const int* __restrict__ task_p, float* __restrict__ ws_f,
    int* __restrict__ ws_i, u8* __restrict__ eids, u16* __restrict__ xb,
    int* __restrict__ bucket)
{
  __shared__ float xs[16][68];
  __shared__ float wgt[24][68];
  __shared__ float scr[4][16][24];
  __shared__ float lgt[16][26];
  __shared__ float zlo[16];
  __shared__ int hist[EE];
  __shared__ int gbase[EE];

  int t = threadIdx.x;
  int w = t >> 6, l = t & 63;
  int pos = l & 15;
  int tg = pos >> 2, eg = pos & 3;
  int kq_low = (l >> 4) & 3;
  int cq = 16 * w + 4 * kq_low;
  int tok0 = blockIdx.x * 16;
  const float* Wg = Wg_all + (size_t)task_p[0] * CC * EE;

  if (t < EE) hist[t] = 0;

  int rr_ = t >> 4, cc_ = (t & 15) << 2;
  int wkk_[6], we_[6];
  #pragma unroll
  for (int i = 0; i < 6; i++) {
    int f = t + i * 256;
    wkk_[i] = f / 24; we_[i] = f - wkk_[i] * 24;
  }

  float acc[4][6];
  #pragma unroll
  for (int i = 0; i < 4; i++)
    #pragma unroll
    for (int j = 0; j < 6; j++) acc[i][j] = 0.f;

  float4 xv[2]; float wgv[2][6];
  #pragma unroll
  for (int p = 0; p < 2; p++) {
    int kb = p * 64;
    xv[p] = *(const float4*)&x[(size_t)(tok0 + rr_) * CC + kb + cc_];
    #pragma unroll
    for (int i = 0; i < 6; i++)
      wgv[p][i] = Wg[(size_t)(kb + wkk_[i]) * EE + we_[i]];
  }

  #pragma unroll
  for (int s = 0; s < 12; s++) {
    int sl = s & 1;
    __syncthreads();
    *(float4*)&xs[rr_][cc_] = xv[sl];
    {
      float4 v = xv[sl];
      u64 pk = (u64)f2b(v.x) | ((u64)f2b(v.y) << 16) |
               ((u64)f2b(v.z) << 32) | ((u64)f2b(v.w) << 48);
      *(u64*)&xb[(size_t)(tok0 + rr_) * CC + s * 64 + cc_] = pk;
    }
    #pragma unroll
    for (int i = 0; i < 6; i++) wgt[we_[i]][wkk_[i]] = wgv[sl][i];
    if (s + 2 < 12) {
      int kb = (s + 2) * 64;
      xv[sl] = *(const float4*)&x[(size_t)(tok0 + rr_) * CC + kb + cc_];
      #pragma unroll
      for (int i = 0; i < 6; i++)
        wgv[sl][i] = Wg[(size_t)(kb + wkk_[i]) * EE + we_[i]];
    }
    __syncthreads();
    float4 x4[4];
    #pragma unroll
    for (int i = 0; i < 4; i++) x4[i] = *(const float4*)&xs[tg * 4 + i][cq];
    #pragma unroll
    for (int j = 0; j < 6; j++) {
      float4 w4 = *(const float4*)&wgt[eg * 6 + j][cq];
      #pragma unroll
      for (int i = 0; i < 4; i++) {
        float a = acc[i][j];
        a = fmaf(x4[i].x, w4.x, a);
        a = fmaf(x4[i].y, w4.y, a);
        a = fmaf(x4[i].z, w4.z, a);
        a = fmaf(x4[i].w, w4.w, a);
        acc[i][j] = a;
      }
    }
  }
  #pragma unroll
  for (int i = 0; i < 4; i++)
    #pragma unroll
    for (int j = 0; j < 6; j++) {
      float v = acc[i][j];
      v += __shfl_xor(v, 16);
      v += __shfl_xor(v, 32);
      acc[i][j] = v;
    }
  if (l < 16) {
    #pragma unroll
    for (int i = 0; i < 4; i++)
      #pragma unroll
      for (int j = 0; j < 6; j++) scr[w][pos][i * 6 + j] = acc[i][j];
  }
  __syncthreads();
  if (w == 0 && l < 16) {
    #pragma unroll
    for (int i = 0; i < 4; i++)
      #pragma unroll
      for (int j = 0; j < 6; j++) {
        float s = scr[0][pos][i * 6 + j] + scr[1][pos][i * 6 + j] +
                  scr[2][pos][i * 6 + j] + scr[3][pos][i * 6 + j];
        lgt[tg * 4 + i][eg * 6 + j] = s;
      }
  }
  __syncthreads();

  int my_e[8], loc[8];
  if (t < 16) {
    int token = tok0 + t;
    float lg[EE];
    #pragma unroll
    for (int e = 0; e < EE; e++) lg[e] = lgt[t][e];
    float mx = lg[0];
    #pragma unroll
    for (int e = 1; e < EE; e++) mx = fmaxf(mx, lg[e]);
    float se = 0.f; float probs[EE];
    #pragma unroll
    for (int e = 0; e < EE; e++) { probs[e] = __expf(lg[e] - mx); se += probs[e]; }
    float inv = 1.f / se;
    #pragma unroll
    for (int e = 0; e < EE; e++) probs[e] *= inv;
    float lse = mx + __logf(se);
    zlo[t] = lse * lse;

    unsigned taken = 0u;
    float gsum = 0.f;
    float my_g[8];
    #pragma unroll
    for (int h = 0; h < HH; h++) {
      float best = -1.f; int bi = 0;
      #pragma unroll
      for (int e = 0; e < EE; e++) {
        bool ok = !((taken >> e) & 1u) && (probs[e] > best);
        best = ok ? probs[e] : best;
        bi   = ok ? e : bi;
      }
      taken |= 1u << bi;
      gsum += best;
      my_g[h] = best; my_e[h] = bi;
    }
    float ginv = 1.f / (gsum + 1e-6f);
    float4 g0, g1;
    g0.x = my_g[0] * ginv; g0.y = my_g[1] * ginv; g0.z = my_g[2] * ginv; g0.w = my_g[3] * ginv;
    g1.x = my_g[4] * ginv; g1.y = my_g[5] * ginv; g1.z = my_g[6] * ginv; g1.w = my_g[7] * ginv;
    float* gbuf = ws_f + WS_G / 4;
    *(float4*)&gbuf[(size_t)token * HH]     = g0;
    *(float4*)&gbuf[(size_t)token * HH + 4] = g1;
    u64 pk = 0;
    #pragma unroll
    for (int h = 0; h < HH; h++) pk |= (u64)(u8)my_e[h] << (8 * h);
    *(u64*)&eids[(size_t)token * HH] = pk;
    #pragma unroll
    for (int h = 0; h < HH; h++) loc[h] = atomicAdd(&hist[my_e[h]], 1);
    #pragma unroll
    for (int e = 0; e < EE; e++) lgt[t][e] = probs[e];
  }
  __syncthreads();
  if (t < EE) {
    float s = 0.f;
    #pragma unroll 8
    for (int rr = 0; rr < 16; rr++) s += lgt[rr][t];
    atomicAdd(ws_f + WS_IMP / 4 + t * 16, s);
    gbase[t] = atomicAdd(&ws_i[t * 16], hist[t]);
  } else if (t == 32) {
    float s = 0.f;
    #pragma unroll 8
    for (int rr = 0; rr < 16; rr++) s += zlo[rr];
    atomicAdd(ws_f + WS_ZSUM / 4, s);
  }
  __syncthreads();
  if (t < 16) {
    int token = tok0 + t;
    #pragma unroll
    for (int h = 0; h < HH; h++)
      bucket[my_e[h] * CAPQ + gbase[my_e[h]] + loc[h]] = token;
  }
}

// -------- batched transpose + f32->bf16 --------
__global__ __launch_bounds__(256) void transpose_kernel(
    const float* __restrict__ src, u16* __restrict__ dst,
    int R, int C, int sB, int dR, int dB)
{
  __shared__ float tile[32][33];
  int e = blockIdx.z;
  const float* s = src + (size_t)e * sB;
  int t = threadIdx.x;
  int tr = t >> 5, tc = t & 31;
  #pragma unroll
  for (int i = 0; i < 4; i++) {
    int r = blockIdx.x * 32 + tr + i * 8;
    int c = blockIdx.y * 32 + tc;
    tile[tr + i * 8][tc] = s[(size_t)r * C + c];
  }
  __syncthreads();
  #pragma unroll
  for (int i = 0; i < 4; i++) {
    int sc = blockIdx.y * 32 + tr + i * 8;
    int sr = blockIdx.x * 32 + tc;
    dst[(size_t)e * dB + (size_t)sc * dR + sr] = f2b(tile[tc][tr + i * 8]);
  }
}

// -------- dense MFMA GEMM (oproj), bf16 A/B, gload_lds, XCD-swizzled --------
template<int BM, int BN, bool OUT_F32>
__global__ __launch_bounds__(256) void gemm_kernel(
    const u16* __restrict__ A, const u16* __restrict__ Bt,
    void* __restrict__ Cp, int M, int N, int K)
{
  constexpr int WM = BM / 2, WN = BN / 2;
  constexpr int FM = WM / 16, FN = WN / 16;
  __shared__ u16 As[BM][64];
  __shared__ u16 Bs[BN][64];
  int t = threadIdx.x;
  int w = t >> 6, l = t & 63;
  int lr = l & 15, lg = l >> 4;
  int wr = w >> 1, wc = w & 1;
  int nwg = gridDim.x * gridDim.y;
  int logical = xcd_remap(blockIdx.y * gridDim.x + blockIdx.x, nwg);
  int col0 = (logical % gridDim.x) * BN, row0 = (logical / gridDim.x) * BM;

  f32x4 acc[FM][FN];
  #pragma unroll
  for (int i = 0; i < FM; i++)
    #pragma unroll
    for (int j = 0; j < FN; j++) acc[i][j] = (f32x4)(0.f);

  int sr = t >> 3;
  int sc = t & 7;
  for (int kb = 0; kb < K; kb += 64) {
    __syncthreads();
    #pragma unroll
    for (int i = 0; i < BM / 32; i++) {
      int rr = i * 32 + sr;
      int ch = sc ^ (rr & 7);
      gload16(A + (size_t)(row0 + rr) * K + kb + ch * 8, &As[rr][sc * 8]);
    }
    #pragma unroll
    for (int i = 0; i < BN / 32; i++) {
      int rr = i * 32 + sr;
      int ch = sc ^ (rr & 7);
      gload16(Bt + (size_t)(col0 + rr) * K + kb + ch * 8, &Bs[rr][sc * 8]);
    }
    __syncthreads();
    #pragma unroll
    for (int ks = 0; ks < 2; ks++) {
      s16x8 af[FM], bf[FN];
      #pragma unroll
      for (int i = 0; i < FM; i++)
        af[i] = *(const s16x8*)&As[wr * WM + i * 16 + lr][8 * ((ks * 4 + lg) ^ (lr & 7))];
      #pragma unroll
      for (int j = 0; j < FN; j++)
        bf[j] = *(const s16x8*)&Bs[wc * WN + j * 16 + lr][8 * ((ks * 4 + lg) ^ (lr & 7))];
      #pragma unroll
      for (int i = 0; i < FM; i++)
        #pragma unroll
        for (int j = 0; j < FN; j++)
          acc[i][j] = __builtin_amdgcn_mfma_f32_16x16x32_bf16(af[i], bf[j], acc[i][j], 0, 0, 0);
    }
  }
  #pragma unroll
  for (int i = 0; i < FM; i++)
    #pragma unroll
    for (int j = 0; j < FN; j++)
      #pragma unroll
      for (int reg = 0; reg < 4; reg++) {
        int rr = row0 + wr * WM + i * 16 + lg * 4 + reg;
        int cc = col0 + wc * WN + j * 16 + lr;
        if (OUT_F32) ((float*)Cp)[(size_t)rr * N + cc] = acc[i][j][reg];
        else ((u16*)Cp)[(size_t)rr * N + cc] = f2b(acc[i][j][reg]);
      }
}

// -------- gathered q projection: per-expert tiles, 128 rows x 96 cols, K=768
__global__ __launch_bounds__(256) void qproj_kernel(
    const u16* __restrict__ xb, const u16* __restrict__ winT,
    const int* __restrict__ ws_i, const int* __restrict__ bucket,
    u16* __restrict__ qall)
{
  int e = blockIdx.y;
  int t0 = blockIdx.x * 128;
  int cnt = ws_i[e * 16];
  if (t0 >= cnt) return;
  __shared__ u16 As[128][64];
  __shared__ u16 Bs[96][64];
  __shared__ int tok_s[128];
  int t = threadIdx.x;
  if (t < 128) tok_s[t] = bucket[e * CAPQ + min(t0 + t, cnt - 1)];
  __syncthreads();
  int w = t >> 6, l = t & 63;
  int lr = l & 15, lg = l >> 4;
  int wr = w >> 1, wc = w & 1;
  const u16* Bt = winT + (size_t)e * HD * CC;

  f32x4 acc[4][3];
  #pragma unroll
  for (int i = 0; i < 4; i++)
    #pragma unroll
    for (int j = 0; j < 3; j++) acc[i][j] = (f32x4)(0.f);

  int sr = t >> 3, sc = t & 7;
  int atok[4];
  #pragma unroll
  for (int i = 0; i < 4; i++) atok[i] = tok_s[i * 32 + sr];

  for (int kb = 0; kb < CC; kb += 64) {
    __syncthreads();
    #pragma unroll
    for (int i = 0; i < 4; i++) {
      int rr = i * 32 + sr;
      int ch = sc ^ (rr & 7);
      gload16(xb + (size_t)atok[i] * CC + kb + ch * 8, &As[rr][sc * 8]);
    }
    #pragma unroll
    for (int i = 0; i < 3; i++) {
      int rr = i * 32 + sr;
      int ch = sc ^ (rr & 7);
      gload16(Bt + (size_t)rr * CC + kb + ch * 8, &Bs[rr][sc * 8]);
    }
    __syncthreads();
    #pragma unroll
    for (int ks = 0; ks < 2; ks++) {
      s16x8 af[4], bf[3];
      #pragma unroll
      for (int i = 0; i < 4; i++)
        af[i] = *(const s16x8*)&As[wr * 64 + i * 16 + lr][8 * ((ks * 4 + lg) ^ (lr & 7))];
      #pragma unroll
      for (int j = 0; j < 3; j++)
        bf[j] = *(const s16x8*)&Bs[wc * 48 + j * 16 + lr][8 * ((ks * 4 + lg) ^ (lr & 7))];
      #pragma unroll
      for (int i = 0; i < 4; i++)
        #pragma unroll
        for (int j = 0; j < 3; j++)
          acc[i][j] = __builtin_amdgcn_mfma_f32_16x16x32_bf16(af[i], bf[j], acc[i][j], 0, 0, 0);
    }
  }
  #pragma unroll
  for (int i = 0; i < 4; i++)
    #pragma unroll
    for (int reg = 0; reg < 4; reg++) {
      int rr = wr * 64 + i * 16 + lg * 4 + reg;
      if (t0 + rr < cnt) {
        int tok = tok_s[rr];
        u16* qp = qall + (size_t)tok * EC + e * HD + wc * 48;
        #pragma unroll
        for (int j = 0; j < 3; j++)
          qp[j * 16 + lr] = f2b(acc[i][j][reg]);
      }
    }
}

// -------- kv projection -> kvbk (padded 128, pre-swizzled K) + vtb (V^T, pre-swizzled)
__global__ __launch_bounds__(256) void kvproj_kernel(
    const u16* __restrict__ xb, const u16* __restrict__ wkvT,
    u16* __restrict__ kvbk, u16* __restrict__ vtb)
{
  __shared__ u16 As[128][64];
  __shared__ u16 Bs[64][64];
  int t = threadIdx.x;
  int w = t >> 6, l = t & 63;
  int lr = l & 15, lg = l >> 4;
  int wr = w >> 1, wc = w & 1;
  int nwg = gridDim.x * gridDim.y;
  int logical = xcd_remap(blockIdx.y * gridDim.x + blockIdx.x, nwg);
  int col0 = (logical % gridDim.x) * 64, row0 = (logical / gridDim.x) * 128;

  f32x4 acc[4][2];
  #pragma unroll
  for (int i = 0; i < 4; i++)
    #pragma unroll
    for (int j = 0; j < 2; j++) acc[i][j] = (f32x4)(0.f);

  int sr = t >> 3, sc = t & 7;
  for (int kb = 0; kb < CC; kb += 64) {
    __syncthreads();
    #pragma unroll
    for (int i = 0; i < 4; i++) {
      int rr = i * 32 + sr;
      int ch = sc ^ (rr & 7);
      gload16(xb + (size_t)(row0 + rr) * CC + kb + ch * 8, &As[rr][sc * 8]);
    }
    #pragma unroll
    for (int i = 0; i < 2; i++) {
      int rr = i * 32 + sr;
      int ch = sc ^ (rr & 7);
      gload16(wkvT + (size_t)(col0 + rr) * CC + kb + ch * 8, &Bs[rr][sc * 8]);
    }
    __syncthreads();
    #pragma unroll
    for (int ks = 0; ks < 2; ks++) {
      s16x8 af[4], bf[2];
      #pragma unroll
      for (int i = 0; i < 4; i++)
        af[i] = *(const s16x8*)&As[wr * 64 + i * 16 + lr][8 * ((ks * 4 + lg) ^ (lr & 7))];
      #pragma unroll
      for (int j = 0; j < 2; j++)
        bf[j] = *(const s16x8*)&Bs[wc * 32 + j * 16 + lr][8 * ((ks * 4 + lg) ^ (lr & 7))];
      #pragma unroll
      for (int i = 0; i < 4; i++)
        #pragma unroll
        for (int j = 0; j < 2; j++)
          acc[i][j] = __builtin_amdgcn_mfma_f32_16x16x32_bf16(af[i], bf[j], acc[i][j], 0, 0, 0);
    }
  }
  #pragma unroll
  for (int i = 0; i < 4; i++)
    #pragma unroll
    for (int j = 0; j < 2; j++) {
      int cb = col0 + wc * 32 + j * 16 + lr;
      int rb = row0 + wr * 64 + i * 16 + lg * 4;
      if (cb < 96) {
        int ch = cb >> 3, ci = cb & 7;
        #pragma unroll
        for (int reg = 0; reg < 4; reg++) {
          int tok = rb + reg;
          kvbk[(size_t)tok * 128 + 8 * (ch ^ (tok & 7)) + ci] = f2b(acc[i][j][reg]);
        }
      } else {
        int d = cb - 96;
        u64 pk = (u64)f2b(acc[i][j][0]) | ((u64)f2b(acc[i][j][1]) << 16) |
                 ((u64)f2b(acc[i][j][2]) << 32) | ((u64)f2b(acc[i][j][3]) << 48);
        int blkbase = rb & ~63;
        int ch = (rb & 63) >> 3;
        *(u64*)&vtb[(size_t)d * NT + blkbase + 8 * (ch ^ (d & 7)) + (rb & 7)] = pk;
      }
    }
}

// ---- flash attention: 32x32x16 MFMA, 8 waves = 8 heads, 32 tokens/block ----
// single block per (tok0,b): K/V staged once for all heads; 2 blocks/CU.
// first 256 threads also zero-fill the 16 unselected expert slots of z.
__global__ __launch_bounds__(512, 2) void attn_kernel(
    const u16* __restrict__ qall, const u16* __restrict__ kvbk,
    const u16* __restrict__ vtb, const u8* __restrict__ eids,
    const float* __restrict__ gbuf, u16* __restrict__ z)
{
  __shared__ u16 Ks[2][64][128];
  __shared__ u16 Vt[2][96][64];
  int b = blockIdx.y;
  int tok0 = blockIdx.x * 32;
  int t = threadIdx.x;
  int w = t >> 6, l = t & 63;
  int h = w;                    // wave = head (8 waves)
  int lo = l & 31, hi = l >> 5;

  s16x8 qf[6];
  {
    int tok = b * NN + tok0 + lo;
    int e = eids[tok * HH + h];
    const u16* qp = qall + (size_t)tok * EC + e * HD + hi * 8;
    #pragma unroll
    for (int ks = 0; ks < 6; ks++)
      qf[ks] = *(const s16x8*)(qp + ks * 16);
  }

  // zero unselected expert slots (first 256 threads; disjoint from all writes)
  if (t < 256) {
    int tk = t >> 3, s8 = t & 7;
    int tok = b * NN + tok0 + tk;
    u64 pk = *(const u64*)&eids[(size_t)tok * HH];
    u32 msk = 0;
    #pragma unroll
    for (int hh = 0; hh < 8; hh++) msk |= 1u << ((pk >> (8 * hh)) & 255u);
    u64* zrow = (u64*)(z + (size_t)tok * EC);
    #pragma unroll
    for (int e = 0; e < EE; e++) {
      if (!((msk >> e) & 1u)) {
        u64* p = zrow + e * 24 + s8 * 3;
        p[0] = 0; p[1] = 0; p[2] = 0;
      }
    }
  }

  const u16* kvwin = kvbk + (size_t)(b * NN) * 128;
  const u16* vwin  = vtb + (size_t)(b * NN);

  f32x16 o0 = (f32x16)(0.f), o1 = (f32x16)(0.f), o2 = (f32x16)(0.f);
  float m = -1e30f, lsum = 0.f;   // m in log2 units

  // prologue: stage tile 0 (1024 K-chunks + 768 V-chunks over 512 threads)
  #pragma unroll
  for (int k2 = 0; k2 < 2; k2++) {
    int c = t + k2 * 512;
    gload16(kvwin + c * 8, &Ks[0][0][0] + c * 8);
  }
  {
    int c = t;
    gload16(vwin + (size_t)(c >> 3) * NT + (c & 7) * 8, &Vt[0][0][0] + c * 8);
    if (t < 256) {
      int c2 = t + 512;
      gload16(vwin + (size_t)(c2 >> 3) * NT + (c2 & 7) * 8, &Vt[0][0][0] + c2 * 8);
    }
  }

  for (int jt = 0; jt < 16; jt++) {
    __syncthreads();
    if (jt < 15) {
      int j0 = (jt + 1) * 64;
      int nb = (jt + 1) & 1;
      const u16* kb_ = kvwin + (size_t)j0 * 128;
      #pragma unroll
      for (int k2 = 0; k2 < 2; k2++) {
        int c = t + k2 * 512;
        gload16(kb_ + c * 8, &Ks[nb][0][0] + c * 8);
      }
      const u16* vb_ = vwin + j0;
      {
        int c = t;
        gload16(vb_ + (size_t)(c >> 3) * NT + (c & 7) * 8, &Vt[nb][0][0] + c * 8);
        if (t < 256) {
          int c2 = t + 512;
          gload16(vb_ + (size_t)(c2 >> 3) * NT + (c2 & 7) * 8, &Vt[nb][0][0] + c2 * 8);
        }
      }
    }
    int buf = jt & 1;

    f32x16 s0 = (f32x16)(0.f), s1 = (f32x16)(0.f);
    #pragma unroll
    for (int ks = 0; ks < 6; ks++) {
      int pos = 8 * ((2 * ks + hi) ^ (lo & 7));
      s16x8 a0 = *(const s16x8*)&Ks[buf][lo][pos];
      s16x8 a1 = *(const s16x8*)&Ks[buf][32 + lo][pos];
      s0 = __builtin_amdgcn_mfma_f32_32x32x16_bf16(a0, qf[ks], s0, 0, 0, 0);
      s1 = __builtin_amdgcn_mfma_f32_32x32x16_bf16(a1, qf[ks], s1, 0, 0, 0);
    }

    float pm = fmaxf(s0[0], s0[1]);
    #pragma unroll
    for (int rg = 2; rg < 16; rg += 2) pm = fmaxf(pm, fmaxf(s0[rg], s0[rg + 1]));
    #pragma unroll
    for (int rg = 0; rg < 16; rg += 2) pm = fmaxf(pm, fmaxf(s1[rg], s1[rg + 1]));
    pm = fmaxf(pm, __shfl_xor(pm, 32));
    pm *= AL2;

    if (!__all(pm - m <= DEFER_THR)) {
      float mn = fmaxf(m, pm);
      float al = fexp2(m - mn);
      m = mn; lsum *= al;
      #pragma unroll
      for (int rg = 0; rg < 16; rg++) {
        int qrow = (rg & 3) + 8 * (rg >> 2) + 4 * hi;
        float alr = __shfl(al, qrow);
        o0[rg] *= alr; o1[rg] *= alr; o2[rg] *= alr;
      }
    }

    float ts = 0.f;
    u32 wpk[2][4][2];
    #pragma unroll
    for (int kb2 = 0; kb2 < 2; kb2++)
      #pragma unroll
      for (int rr = 0; rr < 4; rr++)
        #pragma unroll
        for (int pp = 0; pp < 2; pp++) {
          float sA = kb2 ? s1[rr * 4 + 2 * pp]     : s0[rr * 4 + 2 * pp];
          float sB = kb2 ? s1[rr * 4 + 2 * pp + 1] : s0[rr * 4 + 2 * pp + 1];
          float eA = fexp2(fmaf(sA, AL2, -m));
          float eB = fexp2(fmaf(sB, AL2, -m));
          ts += eA + eB;
          wpk[kb2][rr][pp] = cvtpk(eA, eB);
        }
    lsum += ts;

    s16x8 pa[4];
    #pragma unroll
    for (int ks = 0; ks < 4; ks++) {
      int kb2 = ks >> 1;
      int rlo = (ks & 1) * 2, rhi = rlo + 1;
      u32 own_lo0 = wpk[kb2][rlo][0], own_lo1 = wpk[kb2][rlo][1];
      u32 own_hi0 = wpk[kb2][rhi][0], own_hi1 = wpk[kb2][rhi][1];
      u32 send0 = hi ? own_lo0 : own_hi0;
      u32 send1 = hi ? own_lo1 : own_hi1;
      u32 recv0 = (u32)__shfl_xor((int)send0, 32);
      u32 recv1 = (u32)__shfl_xor((int)send1, 32);
      union { s16x8 v; u32 u[4]; } pu;
      pu.u[0] = hi ? recv0 : own_lo0;
      pu.u[1] = hi ? recv1 : own_lo1;
      pu.u[2] = hi ? own_hi0 : recv0;
      pu.u[3] = hi ? own_hi1 : recv1;
      pa[ks] = pu.v;
    }

    #pragma unroll
    for (int ks = 0; ks < 4; ks++) {
      int pos = 8 * ((2 * ks + hi) ^ (lo & 7));
      s16x8 v0 = *(const s16x8*)&Vt[buf][lo][pos];
      s16x8 v1 = *(const s16x8*)&Vt[buf][32 + lo][pos];
      s16x8 v2 = *(const s16x8*)&Vt[buf][64 + lo][pos];
      o0 = __builtin_amdgcn_mfma_f32_32x32x16_bf16(pa[ks], v0, o0, 0, 0, 0);
      o1 = __builtin_amdgcn_mfma_f32_32x32x16_bf16(pa[ks], v1, o1, 0, 0, 0);
      o2 = __builtin_amdgcn_mfma_f32_32x32x16_bf16(pa[ks], v2, o2, 0, 0, 0);
    }
  }

  float lt = lsum + __shfl_xor(lsum, 32);
  #pragma unroll
  for (int rg = 0; rg < 16; rg++) {
    int qrow = (rg & 3) + 8 * (rg >> 2) + 4 * hi;
    float lv = __shfl(lt, qrow);
    int tok = b * NN + tok0 + qrow;
    int slot = tok * HH + h;
    float scl = gbuf[slot] / lv;
    int e = eids[slot];
    u16* zp = z + (size_t)tok * EC + e * HD + lo;
    zp[0]  = f2b(o0[rg] * scl);
    zp[32] = f2b(o1[rg] * scl);
    zp[64] = f2b(o2[rg] * scl);
  }
}

// ---------------- aux loss ----------------
__global__ void aux_kernel(const float* __restrict__ ws_f,
                           const int* __restrict__ ws_i, float* __restrict__ out)
{
  if (threadIdx.x == 0 && blockIdx.x == 0) {
    float sw = 0.f;
    for (int e = 0; e < EE; e++) {
      float imp = ws_f[WS_IMP / 4 + e * 16] / (float)NT;
      float load = (float)ws_i[e * 16] / (float)(NT * HH);
      sw += imp * load;
    }
    float zl = ws_f[WS_ZSUM / 4] / (float)NT;
    out[(size_t)NT * CC] = 0.1f * ((float)EE * sw) + 0.001f * zl;
  }
}

extern "C" void kernel_launch(void* const* d_in, const int* in_sizes, int n_in,
                              void* d_out, int out_size, void* d_ws, size_t ws_size,
                              hipStream_t stream)
{
  const float* x    = (const float*)d_in[0];
  const float* Wg   = (const float*)d_in[1];
  const float* Win  = (const float*)d_in[2];
  const float* Wout = (const float*)d_in[3];
  const float* Wkv  = (const float*)d_in[4];
  const int*   task = (const int*)d_in[5];
  float* out = (float*)d_out;
  float* ws_f = (float*)d_ws;
  int*   ws_i = (int*)d_ws;
  u8*  eids = (u8*)((char*)d_ws + WS_EID);
  u16* kvbk = (u16*)((char*)d_ws + WS_KVK);
  u16* vtb  = (u16*)((char*)d_ws + WS_VT);
  u16* winT = (u16*)((char*)d_ws + WS_WIN);
  u16* woutT= (u16*)((char*)d_ws + WS_WOUT);
  u16* wkvT = (u16*)((char*)d_ws + WS_WKV);
  u16* qall = (u16*)((char*)d_ws + WS_QA);
  u16* z    = (u16*)((char*)d_ws + WS_Z);
  u16* xb   = (u16*)((char*)d_ws + WS_XB);
  int* bucket = (int*)((char*)d_ws + WS_BUCKET);

  hipMemsetAsync(d_ws, 0, 4096, stream);

  transpose_kernel<<<dim3(CC/32, HD/32, EE), 256, 0, stream>>>(Win, winT, CC, HD, CC*HD, CC, HD*CC);
  transpose_kernel<<<dim3(HD/32, CC/32, EE), 256, 0, stream>>>(Wout, woutT, HD, CC, HD*CC, EC, HD);
  transpose_kernel<<<dim3(CC/32, 192/32, 1), 256, 0, stream>>>(Wkv, wkvT, CC, 192, 0, CC, 0);

  gate_kernel<<<NT / 16, 256, 0, stream>>>(x, Wg, task, ws_f, ws_i, eids, xb, bucket);

  kvproj_kernel<<<dim3(3, NT/128), 256, 0, stream>>>(xb, wkvT, kvbk, vtb);
  qproj_kernel<<<dim3(NT/128, EE), 256, 0, stream>>>(xb, winT, ws_i, bucket, qall);

  // z zero-fill folded into attn; xb/bucket dead by attn time.
  attn_kernel<<<dim3(NN/32, BB), 512, 0, stream>>>(qall, kvbk, vtb, eids, ws_f + WS_G/4, z);

  gemm_kernel<128, 64, true><<<dim3(CC/64, NT/128), 256, 0, stream>>>(
      z, woutT, out, NT, CC, EC);

  aux_kernel<<<1, 64, 0, stream>>>(ws_f, ws_i, out);
}

// Round 21
// 157.317 us; speedup vs baseline: 1.3121x; 1.0527x over previous
//
#include <hip/hip_runtime.h>
#include <hip/hip_bf16.h>
#include <math.h>

#define BB 8
#define NN 1024
#define CC 768
#define HH 8
#define HD 96
#define EE 24
#define NT (BB*NN)          // 8192 tokens
#define NSLOT (NT*HH)       // 65536 (token,h) slots
#define EC (EE*HD)          // 2304
#define CAPQ 8192           // per-expert bucket capacity
#define ASCALE 0.10206207261596575f  // 96^-0.5
#define AL2 0.14724446f              // ASCALE * log2(e)
#define DEFER_THR 11.5415603f        // 8 * log2(e)

typedef unsigned short u16;
typedef unsigned char u8;
typedef unsigned int u32;
typedef unsigned long long u64;
typedef __attribute__((ext_vector_type(8))) short s16x8;
typedef __attribute__((ext_vector_type(4))) float f32x4;
typedef __attribute__((ext_vector_type(16))) float f32x16;

__device__ __forceinline__ u16 f2b(float f) {  // RNE float->bf16 bits
  unsigned u = __builtin_bit_cast(unsigned, f);
  unsigned r = u + 0x7fffu + ((u >> 16) & 1u);
  return (u16)(r >> 16);
}

__device__ __forceinline__ float fexp2(float x) {  // native 2^x
  float r; asm("v_exp_f32 %0, %1" : "=v"(r) : "v"(x)); return r;
}

__device__ __forceinline__ u32 cvtpk(float a, float b) {  // HW RNE pack
  u32 d; asm("v_cvt_pk_bf16_f32 %0, %1, %2" : "=v"(d) : "v"(a), "v"(b)); return d;
}

__device__ __forceinline__ void gload16(const u16* g, u16* lds) {
  __builtin_amdgcn_global_load_lds(
      (const __attribute__((address_space(1))) void*)g,
      (__attribute__((address_space(3))) void*)lds, 16, 0, 0);
}

// bijective XCD remap (8 XCDs): contiguous logical chunks per XCD
__device__ __forceinline__ int xcd_remap(int bid, int nwg) {
  int q = nwg >> 3, r = nwg & 7;
  int xcd = bid & 7, idx = bid >> 3;
  return (xcd < r ? xcd * (q + 1) : r * (q + 1) + (xcd - r) * q) + idx;
}

// ws layout (bytes) — counters padded: one 64B cache line per counter
#define WS_CNT   0                             // 24 ints @ stride 16 (ws_i[e*16])
#define WS_IMP   1536                          // 24 f32 @ stride 16
#define WS_ZSUM  3072                          // 1 f32
#define WS_G     4096
#define WS_EID   (WS_G + NSLOT*4)
#define WS_KVK   (WS_EID + NSLOT)              // NT*128 u16 (K, padded+pre-swizzled)
#define WS_VT    (WS_KVK + NT*128*2)           // 96*NT u16 (V^T, in-block pre-swizzled)
#define WS_WIN   (WS_VT + (size_t)96*NT*2)
#define WS_WOUT  (WS_WIN + (size_t)EC*CC*2)
#define WS_WKV   (WS_WOUT + (size_t)CC*EC*2)
#define WS_QA    (WS_WKV + 192*CC*2)
#define WS_Z     (WS_QA + (size_t)NT*EC*2)
#define WS_XB    WS_Z                          // aliases z; xb dead before attn
#define WS_BUCKET (WS_Z + (size_t)16*1024*1024) // aliases z tail; dead before attn

// ---- gating: register-blocked fp32 GEMM (16 tok x 24 exp), 16-way k-split,
//      2-deep register-prefetch pipeline; softmax + top-8 + buckets; emits xb.
__global__ __launch_bounds__(256) void gate_kernel(
    const float* __restrict__ x, const float* __restrict__ Wg_all,
    const int* __restrict__ task_p, float* __restrict__ ws_f,
    int* __restrict__ ws_i, u8* __restrict__ eids, u16* __restrict__ xb,
    int* __restrict__ bucket)
{
  __shared__ float xs[16][68];
  __shared__ float wgt[24][68];
  __shared__ float scr[4][16][24];
  __shared__ float lgt[16][26];
  __shared__ float zlo[16];
  __shared__ int hist[EE];
  __shared__ int gbase[EE];

  int t = threadIdx.x;
  int w = t >> 6, l = t & 63;
  int pos = l & 15;
  int tg = pos >> 2, eg = pos & 3;
  int kq_low = (l >> 4) & 3;
  int cq = 16 * w + 4 * kq_low;
  int tok0 = blockIdx.x * 16;
  const float* Wg = Wg_all + (size_t)task_p[0] * CC * EE;

  if (t < EE) hist[t] = 0;

  int rr_ = t >> 4, cc_ = (t & 15) << 2;
  int wkk_[6], we_[6];
  #pragma unroll
  for (int i = 0; i < 6; i++) {
    int f = t + i * 256;
    wkk_[i] = f / 24; we_[i] = f - wkk_[i] * 24;
  }

  float acc[4][6];
  #pragma unroll
  for (int i = 0; i < 4; i++)
    #pragma unroll
    for (int j = 0; j < 6; j++) acc[i][j] = 0.f;

  float4 xv[2]; float wgv[2][6];
  #pragma unroll
  for (int p = 0; p < 2; p++) {
    int kb = p * 64;
    xv[p] = *(const float4*)&x[(size_t)(tok0 + rr_) * CC + kb + cc_];
    #pragma unroll
    for (int i = 0; i < 6; i++)
      wgv[p][i] = Wg[(size_t)(kb + wkk_[i]) * EE + we_[i]];
  }

  #pragma unroll
  for (int s = 0; s < 12; s++) {
    int sl = s & 1;
    __syncthreads();
    *(float4*)&xs[rr_][cc_] = xv[sl];
    {
      float4 v = xv[sl];
      u64 pk = (u64)f2b(v.x) | ((u64)f2b(v.y) << 16) |
               ((u64)f2b(v.z) << 32) | ((u64)f2b(v.w) << 48);
      *(u64*)&xb[(size_t)(tok0 + rr_) * CC + s * 64 + cc_] = pk;
    }
    #pragma unroll
    for (int i = 0; i < 6; i++) wgt[we_[i]][wkk_[i]] = wgv[sl][i];
    if (s + 2 < 12) {
      int kb = (s + 2) * 64;
      xv[sl] = *(const float4*)&x[(size_t)(tok0 + rr_) * CC + kb + cc_];
      #pragma unroll
      for (int i = 0; i < 6; i++)
        wgv[sl][i] = Wg[(size_t)(kb + wkk_[i]) * EE + we_[i]];
    }
    __syncthreads();
    float4 x4[4];
    #pragma unroll
    for (int i = 0; i < 4; i++) x4[i] = *(const float4*)&xs[tg * 4 + i][cq];
    #pragma unroll
    for (int j = 0; j < 6; j++) {
      float4 w4 = *(const float4*)&wgt[eg * 6 + j][cq];
      #pragma unroll
      for (int i = 0; i < 4; i++) {
        float a = acc[i][j];
        a = fmaf(x4[i].x, w4.x, a);
        a = fmaf(x4[i].y, w4.y, a);
        a = fmaf(x4[i].z, w4.z, a);
        a = fmaf(x4[i].w, w4.w, a);
        acc[i][j] = a;
      }
    }
  }
  #pragma unroll
  for (int i = 0; i < 4; i++)
    #pragma unroll
    for (int j = 0; j < 6; j++) {
      float v = acc[i][j];
      v += __shfl_xor(v, 16);
      v += __shfl_xor(v, 32);
      acc[i][j] = v;
    }
  if (l < 16) {
    #pragma unroll
    for (int i = 0; i < 4; i++)
      #pragma unroll
      for (int j = 0; j < 6; j++) scr[w][pos][i * 6 + j] = acc[i][j];
  }
  __syncthreads();
  if (w == 0 && l < 16) {
    #pragma unroll
    for (int i = 0; i < 4; i++)
      #pragma unroll
      for (int j = 0; j < 6; j++) {
        float s = scr[0][pos][i * 6 + j] + scr[1][pos][i * 6 + j] +
                  scr[2][pos][i * 6 + j] + scr[3][pos][i * 6 + j];
        lgt[tg * 4 + i][eg * 6 + j] = s;
      }
  }
  __syncthreads();

  int my_e[8], loc[8];
  if (t < 16) {
    int token = tok0 + t;
    float lg[EE];
    #pragma unroll
    for (int e = 0; e < EE; e++) lg[e] = lgt[t][e];
    float mx = lg[0];
    #pragma unroll
    for (int e = 1; e < EE; e++) mx = fmaxf(mx, lg[e]);
    float se = 0.f; float probs[EE];
    #pragma unroll
    for (int e = 0; e < EE; e++) { probs[e] = __expf(lg[e] - mx); se += probs[e]; }
    float inv = 1.f / se;
    #pragma unroll
    for (int e = 0; e < EE; e++) probs[e] *= inv;
    float lse = mx + __logf(se);
    zlo[t] = lse * lse;

    unsigned taken = 0u;
    float gsum = 0.f;
    float my_g[8];
    #pragma unroll
    for (int h = 0; h < HH; h++) {
      float best = -1.f; int bi = 0;
      #pragma unroll
      for (int e = 0; e < EE; e++) {
        bool ok = !((taken >> e) & 1u) && (probs[e] > best);
        best = ok ? probs[e] : best;
        bi   = ok ? e : bi;
      }
      taken |= 1u << bi;
      gsum += best;
      my_g[h] = best; my_e[h] = bi;
    }
    float ginv = 1.f / (gsum + 1e-6f);
    float4 g0, g1;
    g0.x = my_g[0] * ginv; g0.y = my_g[1] * ginv; g0.z = my_g[2] * ginv; g0.w = my_g[3] * ginv;
    g1.x = my_g[4] * ginv; g1.y = my_g[5] * ginv; g1.z = my_g[6] * ginv; g1.w = my_g[7] * ginv;
    float* gbuf = ws_f + WS_G / 4;
    *(float4*)&gbuf[(size_t)token * HH]     = g0;
    *(float4*)&gbuf[(size_t)token * HH + 4] = g1;
    u64 pk = 0;
    #pragma unroll
    for (int h = 0; h < HH; h++) pk |= (u64)(u8)my_e[h] << (8 * h);
    *(u64*)&eids[(size_t)token * HH] = pk;
    #pragma unroll
    for (int h = 0; h < HH; h++) loc[h] = atomicAdd(&hist[my_e[h]], 1);
    #pragma unroll
    for (int e = 0; e < EE; e++) lgt[t][e] = probs[e];
  }
  __syncthreads();
  if (t < EE) {
    float s = 0.f;
    #pragma unroll 8
    for (int rr = 0; rr < 16; rr++) s += lgt[rr][t];
    atomicAdd(ws_f + WS_IMP / 4 + t * 16, s);
    gbase[t] = atomicAdd(&ws_i[t * 16], hist[t]);
  } else if (t == 32) {
    float s = 0.f;
    #pragma unroll 8
    for (int rr = 0; rr < 16; rr++) s += zlo[rr];
    atomicAdd(ws_f + WS_ZSUM / 4, s);
  }
  __syncthreads();
  if (t < 16) {
    int token = tok0 + t;
    #pragma unroll
    for (int h = 0; h < HH; h++)
      bucket[my_e[h] * CAPQ + gbase[my_e[h]] + loc[h]] = token;
  }
}

// -------- batched transpose + f32->bf16 --------
__global__ __launch_bounds__(256) void transpose_kernel(
    const float* __restrict__ src, u16* __restrict__ dst,
    int R, int C, int sB, int dR, int dB)
{
  __shared__ float tile[32][33];
  int e = blockIdx.z;
  const float* s = src + (size_t)e * sB;
  int t = threadIdx.x;
  int tr = t >> 5, tc = t & 31;
  #pragma unroll
  for (int i = 0; i < 4; i++) {
    int r = blockIdx.x * 32 + tr + i * 8;
    int c = blockIdx.y * 32 + tc;
    tile[tr + i * 8][tc] = s[(size_t)r * C + c];
  }
  __syncthreads();
  #pragma unroll
  for (int i = 0; i < 4; i++) {
    int sc = blockIdx.y * 32 + tr + i * 8;
    int sr = blockIdx.x * 32 + tc;
    dst[(size_t)e * dB + (size_t)sc * dR + sr] = f2b(tile[tc][tr + i * 8]);
  }
}

// -------- dense MFMA GEMM (oproj), bf16 A/B, gload_lds, XCD-swizzled --------
template<int BM, int BN, bool OUT_F32>
__global__ __launch_bounds__(256) void gemm_kernel(
    const u16* __restrict__ A, const u16* __restrict__ Bt,
    void* __restrict__ Cp, int M, int N, int K)
{
  constexpr int WM = BM / 2, WN = BN / 2;
  constexpr int FM = WM / 16, FN = WN / 16;
  __shared__ u16 As[BM][64];
  __shared__ u16 Bs[BN][64];
  int t = threadIdx.x;
  int w = t >> 6, l = t & 63;
  int lr = l & 15, lg = l >> 4;
  int wr = w >> 1, wc = w & 1;
  int nwg = gridDim.x * gridDim.y;
  int logical = xcd_remap(blockIdx.y * gridDim.x + blockIdx.x, nwg);
  int col0 = (logical % gridDim.x) * BN, row0 = (logical / gridDim.x) * BM;

  f32x4 acc[FM][FN];
  #pragma unroll
  for (int i = 0; i < FM; i++)
    #pragma unroll
    for (int j = 0; j < FN; j++) acc[i][j] = (f32x4)(0.f);

  int sr = t >> 3;
  int sc = t & 7;
  for (int kb = 0; kb < K; kb += 64) {
    __syncthreads();
    #pragma unroll
    for (int i = 0; i < BM / 32; i++) {
      int rr = i * 32 + sr;
      int ch = sc ^ (rr & 7);
      gload16(A + (size_t)(row0 + rr) * K + kb + ch * 8, &As[rr][sc * 8]);
    }
    #pragma unroll
    for (int i = 0; i < BN / 32; i++) {
      int rr = i * 32 + sr;
      int ch = sc ^ (rr & 7);
      gload16(Bt + (size_t)(col0 + rr) * K + kb + ch * 8, &Bs[rr][sc * 8]);
    }
    __syncthreads();
    #pragma unroll
    for (int ks = 0; ks < 2; ks++) {
      s16x8 af[FM], bf[FN];
      #pragma unroll
      for (int i = 0; i < FM; i++)
        af[i] = *(const s16x8*)&As[wr * WM + i * 16 + lr][8 * ((ks * 4 + lg) ^ (lr & 7))];
      #pragma unroll
      for (int j = 0; j < FN; j++)
        bf[j] = *(const s16x8*)&Bs[wc * WN + j * 16 + lr][8 * ((ks * 4 + lg) ^ (lr & 7))];
      #pragma unroll
      for (int i = 0; i < FM; i++)
        #pragma unroll
        for (int j = 0; j < FN; j++)
          acc[i][j] = __builtin_amdgcn_mfma_f32_16x16x32_bf16(af[i], bf[j], acc[i][j], 0, 0, 0);
    }
  }
  #pragma unroll
  for (int i = 0; i < FM; i++)
    #pragma unroll
    for (int j = 0; j < FN; j++)
      #pragma unroll
      for (int reg = 0; reg < 4; reg++) {
        int rr = row0 + wr * WM + i * 16 + lg * 4 + reg;
        int cc = col0 + wc * WN + j * 16 + lr;
        if (OUT_F32) ((float*)Cp)[(size_t)rr * N + cc] = acc[i][j][reg];
        else ((u16*)Cp)[(size_t)rr * N + cc] = f2b(acc[i][j][reg]);
      }
}

// -------- fused projection kernel: blocks 0..191 = kvproj, 192..1727 = qproj
#define KVP_NWG 192
__global__ __launch_bounds__(256) void proj_kernel(
    const u16* __restrict__ xb, const u16* __restrict__ wkvT,
    const u16* __restrict__ winT, const int* __restrict__ ws_i,
    const int* __restrict__ bucket, u16* __restrict__ kvbk,
    u16* __restrict__ vtb, u16* __restrict__ qall)
{
  __shared__ u16 As[128][64];
  __shared__ u16 Bs[96][64];
  __shared__ int tok_s[128];
  int t = threadIdx.x;
  int w = t >> 6, l = t & 63;
  int lr = l & 15, lg = l >> 4;
  int wr = w >> 1, wc = w & 1;
  int sr = t >> 3, sc = t & 7;
  int bid = blockIdx.x;

  if (bid < KVP_NWG) {
    // ---------------- kvproj body ----------------
    int logical = xcd_remap(bid, KVP_NWG);
    int col0 = (logical % 3) * 64, row0 = (logical / 3) * 128;

    f32x4 acc[4][2];
    #pragma unroll
    for (int i = 0; i < 4; i++)
      #pragma unroll
      for (int j = 0; j < 2; j++) acc[i][j] = (f32x4)(0.f);

    for (int kb = 0; kb < CC; kb += 64) {
      __syncthreads();
      #pragma unroll
      for (int i = 0; i < 4; i++) {
        int rr = i * 32 + sr;
        int ch = sc ^ (rr & 7);
        gload16(xb + (size_t)(row0 + rr) * CC + kb + ch * 8, &As[rr][sc * 8]);
      }
      #pragma unroll
      for (int i = 0; i < 2; i++) {
        int rr = i * 32 + sr;
        int ch = sc ^ (rr & 7);
        gload16(wkvT + (size_t)(col0 + rr) * CC + kb + ch * 8, &Bs[rr][sc * 8]);
      }
      __syncthreads();
      #pragma unroll
      for (int ks = 0; ks < 2; ks++) {
        s16x8 af[4], bf[2];
        #pragma unroll
        for (int i = 0; i < 4; i++)
          af[i] = *(const s16x8*)&As[wr * 64 + i * 16 + lr][8 * ((ks * 4 + lg) ^ (lr & 7))];
        #pragma unroll
        for (int j = 0; j < 2; j++)
          bf[j] = *(const s16x8*)&Bs[wc * 32 + j * 16 + lr][8 * ((ks * 4 + lg) ^ (lr & 7))];
        #pragma unroll
        for (int i = 0; i < 4; i++)
          #pragma unroll
          for (int j = 0; j < 2; j++)
            acc[i][j] = __builtin_amdgcn_mfma_f32_16x16x32_bf16(af[i], bf[j], acc[i][j], 0, 0, 0);
      }
    }
    #pragma unroll
    for (int i = 0; i < 4; i++)
      #pragma unroll
      for (int j = 0; j < 2; j++) {
        int cb = col0 + wc * 32 + j * 16 + lr;
        int rb = row0 + wr * 64 + i * 16 + lg * 4;
        if (cb < 96) {
          int ch = cb >> 3, ci = cb & 7;
          #pragma unroll
          for (int reg = 0; reg < 4; reg++) {
            int tok = rb + reg;
            kvbk[(size_t)tok * 128 + 8 * (ch ^ (tok & 7)) + ci] = f2b(acc[i][j][reg]);
          }
        } else {
          int d = cb - 96;
          u64 pk = (u64)f2b(acc[i][j][0]) | ((u64)f2b(acc[i][j][1]) << 16) |
                   ((u64)f2b(acc[i][j][2]) << 32) | ((u64)f2b(acc[i][j][3]) << 48);
          int blkbase = rb & ~63;
          int ch = (rb & 63) >> 3;
          *(u64*)&vtb[(size_t)d * NT + blkbase + 8 * (ch ^ (d & 7)) + (rb & 7)] = pk;
        }
      }
  } else {
    // ---------------- qproj body ----------------
    int qbid = bid - KVP_NWG;
    int e = qbid >> 6;
    int t0 = (qbid & 63) * 128;
    int cnt = ws_i[e * 16];
    if (t0 >= cnt) return;
    if (t < 128) tok_s[t] = bucket[e * CAPQ + min(t0 + t, cnt - 1)];
    __syncthreads();
    const u16* Bt = winT + (size_t)e * HD * CC;

    f32x4 acc[4][3];
    #pragma unroll
    for (int i = 0; i < 4; i++)
      #pragma unroll
      for (int j = 0; j < 3; j++) acc[i][j] = (f32x4)(0.f);

    int atok[4];
    #pragma unroll
    for (int i = 0; i < 4; i++) atok[i] = tok_s[i * 32 + sr];

    for (int kb = 0; kb < CC; kb += 64) {
      __syncthreads();
      #pragma unroll
      for (int i = 0; i < 4; i++) {
        int rr = i * 32 + sr;
        int ch = sc ^ (rr & 7);
        gload16(xb + (size_t)atok[i] * CC + kb + ch * 8, &As[rr][sc * 8]);
      }
      #pragma unroll
      for (int i = 0; i < 3; i++) {
        int rr = i * 32 + sr;
        int ch = sc ^ (rr & 7);
        gload16(Bt + (size_t)rr * CC + kb + ch * 8, &Bs[rr][sc * 8]);
      }
      __syncthreads();
      #pragma unroll
      for (int ks = 0; ks < 2; ks++) {
        s16x8 af[4], bf[3];
        #pragma unroll
        for (int i = 0; i < 4; i++)
          af[i] = *(const s16x8*)&As[wr * 64 + i * 16 + lr][8 * ((ks * 4 + lg) ^ (lr & 7))];
        #pragma unroll
        for (int j = 0; j < 3; j++)
          bf[j] = *(const s16x8*)&Bs[wc * 48 + j * 16 + lr][8 * ((ks * 4 + lg) ^ (lr & 7))];
        #pragma unroll
        for (int i = 0; i < 4; i++)
          #pragma unroll
          for (int j = 0; j < 3; j++)
            acc[i][j] = __builtin_amdgcn_mfma_f32_16x16x32_bf16(af[i], bf[j], acc[i][j], 0, 0, 0);
      }
    }
    #pragma unroll
    for (int i = 0; i < 4; i++)
      #pragma unroll
      for (int reg = 0; reg < 4; reg++) {
        int rr = wr * 64 + i * 16 + lg * 4 + reg;
        if (t0 + rr < cnt) {
          int tok = tok_s[rr];
          u16* qp = qall + (size_t)tok * EC + e * HD + wc * 48;
          #pragma unroll
          for (int j = 0; j < 3; j++)
            qp[j * 16 + lr] = f2b(acc[i][j][reg]);
        }
      }
  }
}

// ---- flash attention: 32x32x16 MFMA, 8 waves = 8 heads, 32 tokens/block ----
__global__ __launch_bounds__(512, 2) void attn_kernel(
    const u16* __restrict__ qall, const u16* __restrict__ kvbk,
    const u16* __restrict__ vtb, const u8* __restrict__ eids,
    const float* __restrict__ gbuf, u16* __restrict__ z)
{
  __shared__ u16 Ks[2][64][128];
  __shared__ u16 Vt[2][96][64];
  int b = blockIdx.y;
  int tok0 = blockIdx.x * 32;
  int t = threadIdx.x;
  int w = t >> 6, l = t & 63;
  int h = w;                    // wave = head (8 waves)
  int lo = l & 31, hi = l >> 5;

  s16x8 qf[6];
  {
    int tok = b * NN + tok0 + lo;
    int e = eids[tok * HH + h];
    const u16* qp = qall + (size_t)tok * EC + e * HD + hi * 8;
    #pragma unroll
    for (int ks = 0; ks < 6; ks++)
      qf[ks] = *(const s16x8*)(qp + ks * 16);
  }

  // zero unselected expert slots (first 256 threads; disjoint from all writes)
  if (t < 256) {
    int tk = t >> 3, s8 = t & 7;
    int tok = b * NN + tok0 + tk;
    u64 pk = *(const u64*)&eids[(size_t)tok * HH];
    u32 msk = 0;
    #pragma unroll
    for (int hh = 0; hh < 8; hh++) msk |= 1u << ((pk >> (8 * hh)) & 255u);
    u64* zrow = (u64*)(z + (size_t)tok * EC);
    #pragma unroll
    for (int e = 0; e < EE; e++) {
      if (!((msk >> e) & 1u)) {
        u64* p = zrow + e * 24 + s8 * 3;
        p[0] = 0; p[1] = 0; p[2] = 0;
      }
    }
  }

  const u16* kvwin = kvbk + (size_t)(b * NN) * 128;
  const u16* vwin  = vtb + (size_t)(b * NN);

  f32x16 o0 = (f32x16)(0.f), o1 = (f32x16)(0.f), o2 = (f32x16)(0.f);
  float m = -1e30f, lsum = 0.f;   // m in log2 units

  #pragma unroll
  for (int k2 = 0; k2 < 2; k2++) {
    int c = t + k2 * 512;
    gload16(kvwin + c * 8, &Ks[0][0][0] + c * 8);
  }
  {
    int c = t;
    gload16(vwin + (size_t)(c >> 3) * NT + (c & 7) * 8, &Vt[0][0][0] + c * 8);
    if (t < 256) {
      int c2 = t + 512;
      gload16(vwin + (size_t)(c2 >> 3) * NT + (c2 & 7) * 8, &Vt[0][0][0] + c2 * 8);
    }
  }

  for (int jt = 0; jt < 16; jt++) {
    __syncthreads();
    if (jt < 15) {
      int j0 = (jt + 1) * 64;
      int nb = (jt + 1) & 1;
      const u16* kb_ = kvwin + (size_t)j0 * 128;
      #pragma unroll
      for (int k2 = 0; k2 < 2; k2++) {
        int c = t + k2 * 512;
        gload16(kb_ + c * 8, &Ks[nb][0][0] + c * 8);
      }
      const u16* vb_ = vwin + j0;
      {
        int c = t;
        gload16(vb_ + (size_t)(c >> 3) * NT + (c & 7) * 8, &Vt[nb][0][0] + c * 8);
        if (t < 256) {
          int c2 = t + 512;
          gload16(vb_ + (size_t)(c2 >> 3) * NT + (c2 & 7) * 8, &Vt[nb][0][0] + c2 * 8);
        }
      }
    }
    int buf = jt & 1;

    f32x16 s0 = (f32x16)(0.f), s1 = (f32x16)(0.f);
    #pragma unroll
    for (int ks = 0; ks < 6; ks++) {
      int pos = 8 * ((2 * ks + hi) ^ (lo & 7));
      s16x8 a0 = *(const s16x8*)&Ks[buf][lo][pos];
      s16x8 a1 = *(const s16x8*)&Ks[buf][32 + lo][pos];
      s0 = __builtin_amdgcn_mfma_f32_32x32x16_bf16(a0, qf[ks], s0, 0, 0, 0);
      s1 = __builtin_amdgcn_mfma_f32_32x32x16_bf16(a1, qf[ks], s1, 0, 0, 0);
    }

    float pm = fmaxf(s0[0], s0[1]);
    #pragma unroll
    for (int rg = 2; rg < 16; rg += 2) pm = fmaxf(pm, fmaxf(s0[rg], s0[rg + 1]));
    #pragma unroll
    for (int rg = 0; rg < 16; rg += 2) pm = fmaxf(pm, fmaxf(s1[rg], s1[rg + 1]));
    pm = fmaxf(pm, __shfl_xor(pm, 32));
    pm *= AL2;

    if (!__all(pm - m <= DEFER_THR)) {
      float mn = fmaxf(m, pm);
      float al = fexp2(m - mn);
      m = mn; lsum *= al;
      #pragma unroll
      for (int rg = 0; rg < 16; rg++) {
        int qrow = (rg & 3) + 8 * (rg >> 2) + 4 * hi;
        float alr = __shfl(al, qrow);
        o0[rg] *= alr; o1[rg] *= alr; o2[rg] *= alr;
      }
    }

    float ts = 0.f;
    u32 wpk[2][4][2];
    #pragma unroll
    for (int kb2 = 0; kb2 < 2; kb2++)
      #pragma unroll
      for (int rr = 0; rr < 4; rr++)
        #pragma unroll
        for (int pp = 0; pp < 2; pp++) {
          float sA = kb2 ? s1[rr * 4 + 2 * pp]     : s0[rr * 4 + 2 * pp];
          float sB = kb2 ? s1[rr * 4 + 2 * pp + 1] : s0[rr * 4 + 2 * pp + 1];
          float eA = fexp2(fmaf(sA, AL2, -m));
          float eB = fexp2(fmaf(sB, AL2, -m));
          ts += eA + eB;
          wpk[kb2][rr][pp] = cvtpk(eA, eB);
        }
    lsum += ts;

    s16x8 pa[4];
    #pragma unroll
    for (int ks = 0; ks < 4; ks++) {
      int kb2 = ks >> 1;
      int rlo = (ks & 1) * 2, rhi = rlo + 1;
      u32 own_lo0 = wpk[kb2][rlo][0], own_lo1 = wpk[kb2][rlo][1];
      u32 own_hi0 = wpk[kb2][rhi][0], own_hi1 = wpk[kb2][rhi][1];
      u32 send0 = hi ? own_lo0 : own_hi0;
      u32 send1 = hi ? own_lo1 : own_hi1;
      u32 recv0 = (u32)__shfl_xor((int)send0, 32);
      u32 recv1 = (u32)__shfl_xor((int)send1, 32);
      union { s16x8 v; u32 u[4]; } pu;
      pu.u[0] = hi ? recv0 : own_lo0;
      pu.u[1] = hi ? recv1 : own_lo1;
      pu.u[2] = hi ? own_hi0 : recv0;
      pu.u[3] = hi ? own_hi1 : recv1;
      pa[ks] = pu.v;
    }

    #pragma unroll
    for (int ks = 0; ks < 4; ks++) {
      int pos = 8 * ((2 * ks + hi) ^ (lo & 7));
      s16x8 v0 = *(const s16x8*)&Vt[buf][lo][pos];
      s16x8 v1 = *(const s16x8*)&Vt[buf][32 + lo][pos];
      s16x8 v2 = *(const s16x8*)&Vt[buf][64 + lo][pos];
      o0 = __builtin_amdgcn_mfma_f32_32x32x16_bf16(pa[ks], v0, o0, 0, 0, 0);
      o1 = __builtin_amdgcn_mfma_f32_32x32x16_bf16(pa[ks], v1, o1, 0, 0, 0);
      o2 = __builtin_amdgcn_mfma_f32_32x32x16_bf16(pa[ks], v2, o2, 0, 0, 0);
    }
  }

  float lt = lsum + __shfl_xor(lsum, 32);
  #pragma unroll
  for (int rg = 0; rg < 16; rg++) {
    int qrow = (rg & 3) + 8 * (rg >> 2) + 4 * hi;
    float lv = __shfl(lt, qrow);
    int tok = b * NN + tok0 + qrow;
    int slot = tok * HH + h;
    float scl = gbuf[slot] / lv;
    int e = eids[slot];
    u16* zp = z + (size_t)tok * EC + e * HD + lo;
    zp[0]  = f2b(o0[rg] * scl);
    zp[32] = f2b(o1[rg] * scl);
    zp[64] = f2b(o2[rg] * scl);
  }
}

// ---------------- aux loss ----------------
__global__ void aux_kernel(const float* __restrict__ ws_f,
                           const int* __restrict__ ws_i, float* __restrict__ out)
{
  if (threadIdx.x == 0 && blockIdx.x == 0) {
    float sw = 0.f;
    for (int e = 0; e < EE; e++) {
      float imp = ws_f[WS_IMP / 4 + e * 16] / (float)NT;
      float load = (float)ws_i[e * 16] / (float)(NT * HH);
      sw += imp * load;
    }
    float zl = ws_f[WS_ZSUM / 4] / (float)NT;
    out[(size_t)NT * CC] = 0.1f * ((float)EE * sw) + 0.001f * zl;
  }
}

extern "C" void kernel_launch(void* const* d_in, const int* in_sizes, int n_in,
                              void* d_out, int out_size, void* d_ws, size_t ws_size,
                              hipStream_t stream)
{
  const float* x    = (const float*)d_in[0];
  const float* Wg   = (const float*)d_in[1];
  const float* Win  = (const float*)d_in[2];
  const float* Wout = (const float*)d_in[3];
  const float* Wkv  = (const float*)d_in[4];
  const int*   task = (const int*)d_in[5];
  float* out = (float*)d_out;
  float* ws_f = (float*)d_ws;
  int*   ws_i = (int*)d_ws;
  u8*  eids = (u8*)((char*)d_ws + WS_EID);
  u16* kvbk = (u16*)((char*)d_ws + WS_KVK);
  u16* vtb  = (u16*)((char*)d_ws + WS_VT);
  u16* winT = (u16*)((char*)d_ws + WS_WIN);
  u16* woutT= (u16*)((char*)d_ws + WS_WOUT);
  u16* wkvT = (u16*)((char*)d_ws + WS_WKV);
  u16* qall = (u16*)((char*)d_ws + WS_QA);
  u16* z    = (u16*)((char*)d_ws + WS_Z);
  u16* xb   = (u16*)((char*)d_ws + WS_XB);
  int* bucket = (int*)((char*)d_ws + WS_BUCKET);

  hipMemsetAsync(d_ws, 0, 4096, stream);

  transpose_kernel<<<dim3(CC/32, HD/32, EE), 256, 0, stream>>>(Win, winT, CC, HD, CC*HD, CC, HD*CC);
  transpose_kernel<<<dim3(HD/32, CC/32, EE), 256, 0, stream>>>(Wout, woutT, HD, CC, HD*CC, EC, HD);
  transpose_kernel<<<dim3(CC/32, 192/32, 1), 256, 0, stream>>>(Wkv, wkvT, CC, 192, 0, CC, 0);

  gate_kernel<<<NT / 16, 256, 0, stream>>>(x, Wg, task, ws_f, ws_i, eids, xb, bucket);

  // fused kvproj (192 blocks) + qproj (1536 blocks): independent, one dispatch
  proj_kernel<<<KVP_NWG + (NT/128) * EE, 256, 0, stream>>>(
      xb, wkvT, winT, ws_i, bucket, kvbk, vtb, qall);

  // z zero-fill folded into attn; xb/bucket dead by attn time.
  attn_kernel<<<dim3(NN/32, BB), 512, 0, stream>>>(qall, kvbk, vtb, eids, ws_f + WS_G/4, z);

  gemm_kernel<128, 64, true><<<dim3(CC/64, NT/128), 256, 0, stream>>>(
      z, woutT, out, NT, CC, EC);

  aux_kernel<<<1, 64, 0, stream>>>(ws_f, ws_i, out);
}

// Round 22
// 150.389 us; speedup vs baseline: 1.3726x; 1.0461x over previous
//
#include <hip/hip_runtime.h>
#include <hip/hip_bf16.h>
#include <math.h>

#define BB 8
#define NN 1024
#define CC 768
#define HH 8
#define HD 96
#define EE 24
#define NT (BB*NN)          // 8192 tokens
#define NSLOT (NT*HH)       // 65536 (token,h) slots
#define EC (EE*HD)          // 2304
#define CAPQ 8192           // per-expert bucket capacity
#define ASCALE 0.10206207261596575f  // 96^-0.5
#define AL2 0.14724446f              // ASCALE * log2(e)
#define DEFER_THR 11.5415603f        // 8 * log2(e)

typedef unsigned short u16;
typedef unsigned char u8;
typedef unsigned int u32;
typedef unsigned long long u64;
typedef __attribute__((ext_vector_type(8))) short s16x8;
typedef __attribute__((ext_vector_type(4))) float f32x4;
typedef __attribute__((ext_vector_type(16))) float f32x16;

__device__ __forceinline__ u16 f2b(float f) {  // RNE float->bf16 bits
  unsigned u = __builtin_bit_cast(unsigned, f);
  unsigned r = u + 0x7fffu + ((u >> 16) & 1u);
  return (u16)(r >> 16);
}

__device__ __forceinline__ float fexp2(float x) {  // native 2^x
  float r; asm("v_exp_f32 %0, %1" : "=v"(r) : "v"(x)); return r;
}

__device__ __forceinline__ u32 cvtpk(float a, float b) {  // HW RNE pack
  u32 d; asm("v_cvt_pk_bf16_f32 %0, %1, %2" : "=v"(d) : "v"(a), "v"(b)); return d;
}

__device__ __forceinline__ void gload16(const u16* g, u16* lds) {
  __builtin_amdgcn_global_load_lds(
      (const __attribute__((address_space(1))) void*)g,
      (__attribute__((address_space(3))) void*)lds, 16, 0, 0);
}

// bijective XCD remap (8 XCDs): contiguous logical chunks per XCD
__device__ __forceinline__ int xcd_remap(int bid, int nwg) {
  int q = nwg >> 3, r = nwg & 7;
  int xcd = bid & 7, idx = bid >> 3;
  return (xcd < r ? xcd * (q + 1) : r * (q + 1) + (xcd - r) * q) + idx;
}

// ws layout (bytes) — counters padded: one 64B cache line per counter
#define WS_CNT   0                             // 24 ints @ stride 16 (ws_i[e*16])
#define WS_IMP   1536                          // 24 f32 @ stride 16
#define WS_ZSUM  3072                          // 1 f32
#define WS_G     4096
#define WS_EID   (WS_G + NSLOT*4)
#define WS_KVK   (WS_EID + NSLOT)              // NT*128 u16 (K, padded+pre-swizzled)
#define WS_VT    (WS_KVK + NT*128*2)           // 96*NT u16 (V^T, in-block pre-swizzled)
#define WS_WIN   (WS_VT + (size_t)96*NT*2)
#define WS_WOUT  (WS_WIN + (size_t)EC*CC*2)
#define WS_WKV   (WS_WOUT + (size_t)CC*EC*2)
#define WS_QA    (WS_WKV + 192*CC*2)
#define WS_Z     (WS_QA + (size_t)NT*EC*2)
#define WS_XB    WS_Z                          // aliases z; xb dead before attn
#define WS_BUCKET (WS_Z + (size_t)16*1024*1024) // aliases z tail; dead before attn

#define GATE_NWG (NT/16)     // 512
#define TR1_NWG  (24*3*24)   // 1728 (W_in)
#define TR2_NWG  (3*24*24)   // 1728 (W_out)
#define TR3_NWG  (24*6)      // 144  (W_kv)

// ---- fused: gate (blocks 0..511) + weight transposes (blocks 512..4111) ----
__global__ __launch_bounds__(256) void gate_tr_kernel(
    const float* __restrict__ x, const float* __restrict__ Wg_all,
    const int* __restrict__ task_p,
    const float* __restrict__ Win, const float* __restrict__ Wout,
    const float* __restrict__ Wkv,
    float* __restrict__ ws_f, int* __restrict__ ws_i,
    u8* __restrict__ eids, u16* __restrict__ xb, int* __restrict__ bucket,
    u16* __restrict__ winT, u16* __restrict__ woutT, u16* __restrict__ wkvT)
{
  __shared__ float xs[16][68];
  __shared__ float wgt[24][68];
  __shared__ float scr[4][16][24];
  __shared__ float lgt[16][26];
  __shared__ float zlo[16];
  __shared__ int hist[EE];
  __shared__ int gbase[EE];
  __shared__ float tile[32][33];

  int bid = blockIdx.x;
  int t = threadIdx.x;

  if (bid < GATE_NWG) {
    // ------------------------- gate body -------------------------
    int w = t >> 6, l = t & 63;
    int pos = l & 15;
    int tg = pos >> 2, eg = pos & 3;
    int kq_low = (l >> 4) & 3;
    int cq = 16 * w + 4 * kq_low;
    int tok0 = bid * 16;
    const float* Wg = Wg_all + (size_t)task_p[0] * CC * EE;

    if (t < EE) hist[t] = 0;

    int rr_ = t >> 4, cc_ = (t & 15) << 2;
    int wkk_[6], we_[6];
    #pragma unroll
    for (int i = 0; i < 6; i++) {
      int f = t + i * 256;
      wkk_[i] = f / 24; we_[i] = f - wkk_[i] * 24;
    }

    float acc[4][6];
    #pragma unroll
    for (int i = 0; i < 4; i++)
      #pragma unroll
      for (int j = 0; j < 6; j++) acc[i][j] = 0.f;

    float4 xv[2]; float wgv[2][6];
    #pragma unroll
    for (int p = 0; p < 2; p++) {
      int kb = p * 64;
      xv[p] = *(const float4*)&x[(size_t)(tok0 + rr_) * CC + kb + cc_];
      #pragma unroll
      for (int i = 0; i < 6; i++)
        wgv[p][i] = Wg[(size_t)(kb + wkk_[i]) * EE + we_[i]];
    }

    #pragma unroll
    for (int s = 0; s < 12; s++) {
      int sl = s & 1;
      __syncthreads();
      *(float4*)&xs[rr_][cc_] = xv[sl];
      {
        float4 v = xv[sl];
        u64 pk = (u64)f2b(v.x) | ((u64)f2b(v.y) << 16) |
                 ((u64)f2b(v.z) << 32) | ((u64)f2b(v.w) << 48);
        *(u64*)&xb[(size_t)(tok0 + rr_) * CC + s * 64 + cc_] = pk;
      }
      #pragma unroll
      for (int i = 0; i < 6; i++) wgt[we_[i]][wkk_[i]] = wgv[sl][i];
      if (s + 2 < 12) {
        int kb = (s + 2) * 64;
        xv[sl] = *(const float4*)&x[(size_t)(tok0 + rr_) * CC + kb + cc_];
        #pragma unroll
        for (int i = 0; i < 6; i++)
          wgv[sl][i] = Wg[(size_t)(kb + wkk_[i]) * EE + we_[i]];
      }
      __syncthreads();
      float4 x4[4];
      #pragma unroll
      for (int i = 0; i < 4; i++) x4[i] = *(const float4*)&xs[tg * 4 + i][cq];
      #pragma unroll
      for (int j = 0; j < 6; j++) {
        float4 w4 = *(const float4*)&wgt[eg * 6 + j][cq];
        #pragma unroll
        for (int i = 0; i < 4; i++) {
          float a = acc[i][j];
          a = fmaf(x4[i].x, w4.x, a);
          a = fmaf(x4[i].y, w4.y, a);
          a = fmaf(x4[i].z, w4.z, a);
          a = fmaf(x4[i].w, w4.w, a);
          acc[i][j] = a;
        }
      }
    }
    #pragma unroll
    for (int i = 0; i < 4; i++)
      #pragma unroll
      for (int j = 0; j < 6; j++) {
        float v = acc[i][j];
        v += __shfl_xor(v, 16);
        v += __shfl_xor(v, 32);
        acc[i][j] = v;
      }
    if (l < 16) {
      #pragma unroll
      for (int i = 0; i < 4; i++)
        #pragma unroll
        for (int j = 0; j < 6; j++) scr[w][pos][i * 6 + j] = acc[i][j];
    }
    __syncthreads();
    if (w == 0 && l < 16) {
      #pragma unroll
      for (int i = 0; i < 4; i++)
        #pragma unroll
        for (int j = 0; j < 6; j++) {
          float s = scr[0][pos][i * 6 + j] + scr[1][pos][i * 6 + j] +
                    scr[2][pos][i * 6 + j] + scr[3][pos][i * 6 + j];
          lgt[tg * 4 + i][eg * 6 + j] = s;
        }
    }
    __syncthreads();

    int my_e[8], loc[8];
    if (t < 16) {
      int token = tok0 + t;
      float lg[EE];
      #pragma unroll
      for (int e = 0; e < EE; e++) lg[e] = lgt[t][e];
      float mx = lg[0];
      #pragma unroll
      for (int e = 1; e < EE; e++) mx = fmaxf(mx, lg[e]);
      float se = 0.f; float probs[EE];
      #pragma unroll
      for (int e = 0; e < EE; e++) { probs[e] = __expf(lg[e] - mx); se += probs[e]; }
      float inv = 1.f / se;
      #pragma unroll
      for (int e = 0; e < EE; e++) probs[e] *= inv;
      float lse = mx + __logf(se);
      zlo[t] = lse * lse;

      unsigned taken = 0u;
      float gsum = 0.f;
      float my_g[8];
      #pragma unroll
      for (int h = 0; h < HH; h++) {
        float best = -1.f; int bi = 0;
        #pragma unroll
        for (int e = 0; e < EE; e++) {
          bool ok = !((taken >> e) & 1u) && (probs[e] > best);
          best = ok ? probs[e] : best;
          bi   = ok ? e : bi;
        }
        taken |= 1u << bi;
        gsum += best;
        my_g[h] = best; my_e[h] = bi;
      }
      float ginv = 1.f / (gsum + 1e-6f);
      float4 g0, g1;
      g0.x = my_g[0] * ginv; g0.y = my_g[1] * ginv; g0.z = my_g[2] * ginv; g0.w = my_g[3] * ginv;
      g1.x = my_g[4] * ginv; g1.y = my_g[5] * ginv; g1.z = my_g[6] * ginv; g1.w = my_g[7] * ginv;
      float* gbuf = ws_f + WS_G / 4;
      *(float4*)&gbuf[(size_t)token * HH]     = g0;
      *(float4*)&gbuf[(size_t)token * HH + 4] = g1;
      u64 pk = 0;
      #pragma unroll
      for (int h = 0; h < HH; h++) pk |= (u64)(u8)my_e[h] << (8 * h);
      *(u64*)&eids[(size_t)token * HH] = pk;
      #pragma unroll
      for (int h = 0; h < HH; h++) loc[h] = atomicAdd(&hist[my_e[h]], 1);
      #pragma unroll
      for (int e = 0; e < EE; e++) lgt[t][e] = probs[e];
    }
    __syncthreads();
    if (t < EE) {
      float s = 0.f;
      #pragma unroll 8
      for (int rr = 0; rr < 16; rr++) s += lgt[rr][t];
      atomicAdd(ws_f + WS_IMP / 4 + t * 16, s);
      gbase[t] = atomicAdd(&ws_i[t * 16], hist[t]);
    } else if (t == 32) {
      float s = 0.f;
      #pragma unroll 8
      for (int rr = 0; rr < 16; rr++) s += zlo[rr];
      atomicAdd(ws_f + WS_ZSUM / 4, s);
    }
    __syncthreads();
    if (t < 16) {
      int token = tok0 + t;
      #pragma unroll
      for (int h = 0; h < HH; h++)
        bucket[my_e[h] * CAPQ + gbase[my_e[h]] + loc[h]] = token;
    }
  } else {
    // ------------------------- transpose body -------------------------
    int lb = bid - GATE_NWG;
    const float* src; u16* dst;
    int C, sB, dR, dB, bx, by, bz;
    if (lb < TR1_NWG) {            // W_in: (24, 3, 24)
      src = Win; dst = winT; C = HD; sB = CC * HD; dR = CC; dB = HD * CC;
      bx = lb % 24; by = (lb / 24) % 3; bz = lb / 72;
    } else if (lb < TR1_NWG + TR2_NWG) {   // W_out: (3, 24, 24)
      lb -= TR1_NWG;
      src = Wout; dst = woutT; C = CC; sB = HD * CC; dR = EC; dB = HD;
      bx = lb % 3; by = (lb / 3) % 24; bz = lb / 72;
    } else {                        // W_kv: (24, 6, 1)
      lb -= TR1_NWG + TR2_NWG;
      src = Wkv; dst = wkvT; C = 192; sB = 0; dR = CC; dB = 0;
      bx = lb % 24; by = lb / 24; bz = 0;
    }
    const float* s = src + (size_t)bz * sB;
    int tr = t >> 5, tc = t & 31;
    #pragma unroll
    for (int i = 0; i < 4; i++) {
      int r = bx * 32 + tr + i * 8;
      int c = by * 32 + tc;
      tile[tr + i * 8][tc] = s[(size_t)r * C + c];
    }
    __syncthreads();
    #pragma unroll
    for (int i = 0; i < 4; i++) {
      int sc_ = by * 32 + tr + i * 8;
      int sr_ = bx * 32 + tc;
      dst[(size_t)bz * dB + (size_t)sc_ * dR + sr_] = f2b(tile[tc][tr + i * 8]);
    }
  }
}

// -------- dense MFMA GEMM (oproj), bf16 A/B, gload_lds, XCD-swizzled --------
template<int BM, int BN, bool OUT_F32>
__global__ __launch_bounds__(256) void gemm_kernel(
    const u16* __restrict__ A, const u16* __restrict__ Bt,
    void* __restrict__ Cp, int M, int N, int K)
{
  constexpr int WM = BM / 2, WN = BN / 2;
  constexpr int FM = WM / 16, FN = WN / 16;
  __shared__ u16 As[BM][64];
  __shared__ u16 Bs[BN][64];
  int t = threadIdx.x;
  int w = t >> 6, l = t & 63;
  int lr = l & 15, lg = l >> 4;
  int wr = w >> 1, wc = w & 1;
  int nwg = gridDim.x * gridDim.y;
  int logical = xcd_remap(blockIdx.y * gridDim.x + blockIdx.x, nwg);
  int col0 = (logical % gridDim.x) * BN, row0 = (logical / gridDim.x) * BM;

  f32x4 acc[FM][FN];
  #pragma unroll
  for (int i = 0; i < FM; i++)
    #pragma unroll
    for (int j = 0; j < FN; j++) acc[i][j] = (f32x4)(0.f);

  int sr = t >> 3;
  int sc = t & 7;
  for (int kb = 0; kb < K; kb += 64) {
    __syncthreads();
    #pragma unroll
    for (int i = 0; i < BM / 32; i++) {
      int rr = i * 32 + sr;
      int ch = sc ^ (rr & 7);
      gload16(A + (size_t)(row0 + rr) * K + kb + ch * 8, &As[rr][sc * 8]);
    }
    #pragma unroll
    for (int i = 0; i < BN / 32; i++) {
      int rr = i * 32 + sr;
      int ch = sc ^ (rr & 7);
      gload16(Bt + (size_t)(col0 + rr) * K + kb + ch * 8, &Bs[rr][sc * 8]);
    }
    __syncthreads();
    #pragma unroll
    for (int ks = 0; ks < 2; ks++) {
      s16x8 af[FM], bf[FN];
      #pragma unroll
      for (int i = 0; i < FM; i++)
        af[i] = *(const s16x8*)&As[wr * WM + i * 16 + lr][8 * ((ks * 4 + lg) ^ (lr & 7))];
      #pragma unroll
      for (int j = 0; j < FN; j++)
        bf[j] = *(const s16x8*)&Bs[wc * WN + j * 16 + lr][8 * ((ks * 4 + lg) ^ (lr & 7))];
      #pragma unroll
      for (int i = 0; i < FM; i++)
        #pragma unroll
        for (int j = 0; j < FN; j++)
          acc[i][j] = __builtin_amdgcn_mfma_f32_16x16x32_bf16(af[i], bf[j], acc[i][j], 0, 0, 0);
    }
  }
  #pragma unroll
  for (int i = 0; i < FM; i++)
    #pragma unroll
    for (int j = 0; j < FN; j++)
      #pragma unroll
      for (int reg = 0; reg < 4; reg++) {
        int rr = row0 + wr * WM + i * 16 + lg * 4 + reg;
        int cc = col0 + wc * WN + j * 16 + lr;
        if (OUT_F32) ((float*)Cp)[(size_t)rr * N + cc] = acc[i][j][reg];
        else ((u16*)Cp)[(size_t)rr * N + cc] = f2b(acc[i][j][reg]);
      }
}

// -------- fused projection kernel: blocks 0..191 = kvproj, 192..1727 = qproj
#define KVP_NWG 192
__global__ __launch_bounds__(256) void proj_kernel(
    const u16* __restrict__ xb, const u16* __restrict__ wkvT,
    const u16* __restrict__ winT, const int* __restrict__ ws_i,
    const int* __restrict__ bucket, u16* __restrict__ kvbk,
    u16* __restrict__ vtb, u16* __restrict__ qall)
{
  __shared__ u16 As[128][64];
  __shared__ u16 Bs[96][64];
  __shared__ int tok_s[128];
  int t = threadIdx.x;
  int w = t >> 6, l = t & 63;
  int lr = l & 15, lg = l >> 4;
  int wr = w >> 1, wc = w & 1;
  int sr = t >> 3, sc = t & 7;
  int bid = blockIdx.x;

  if (bid < KVP_NWG) {
    // ---------------- kvproj body ----------------
    int logical = xcd_remap(bid, KVP_NWG);
    int col0 = (logical % 3) * 64, row0 = (logical / 3) * 128;

    f32x4 acc[4][2];
    #pragma unroll
    for (int i = 0; i < 4; i++)
      #pragma unroll
      for (int j = 0; j < 2; j++) acc[i][j] = (f32x4)(0.f);

    for (int kb = 0; kb < CC; kb += 64) {
      __syncthreads();
      #pragma unroll
      for (int i = 0; i < 4; i++) {
        int rr = i * 32 + sr;
        int ch = sc ^ (rr & 7);
        gload16(xb + (size_t)(row0 + rr) * CC + kb + ch * 8, &As[rr][sc * 8]);
      }
      #pragma unroll
      for (int i = 0; i < 2; i++) {
        int rr = i * 32 + sr;
        int ch = sc ^ (rr & 7);
        gload16(wkvT + (size_t)(col0 + rr) * CC + kb + ch * 8, &Bs[rr][sc * 8]);
      }
      __syncthreads();
      #pragma unroll
      for (int ks = 0; ks < 2; ks++) {
        s16x8 af[4], bf[2];
        #pragma unroll
        for (int i = 0; i < 4; i++)
          af[i] = *(const s16x8*)&As[wr * 64 + i * 16 + lr][8 * ((ks * 4 + lg) ^ (lr & 7))];
        #pragma unroll
        for (int j = 0; j < 2; j++)
          bf[j] = *(const s16x8*)&Bs[wc * 32 + j * 16 + lr][8 * ((ks * 4 + lg) ^ (lr & 7))];
        #pragma unroll
        for (int i = 0; i < 4; i++)
          #pragma unroll
          for (int j = 0; j < 2; j++)
            acc[i][j] = __builtin_amdgcn_mfma_f32_16x16x32_bf16(af[i], bf[j], acc[i][j], 0, 0, 0);
      }
    }
    #pragma unroll
    for (int i = 0; i < 4; i++)
      #pragma unroll
      for (int j = 0; j < 2; j++) {
        int cb = col0 + wc * 32 + j * 16 + lr;
        int rb = row0 + wr * 64 + i * 16 + lg * 4;
        if (cb < 96) {
          int ch = cb >> 3, ci = cb & 7;
          #pragma unroll
          for (int reg = 0; reg < 4; reg++) {
            int tok = rb + reg;
            kvbk[(size_t)tok * 128 + 8 * (ch ^ (tok & 7)) + ci] = f2b(acc[i][j][reg]);
          }
        } else {
          int d = cb - 96;
          u64 pk = (u64)f2b(acc[i][j][0]) | ((u64)f2b(acc[i][j][1]) << 16) |
                   ((u64)f2b(acc[i][j][2]) << 32) | ((u64)f2b(acc[i][j][3]) << 48);
          int blkbase = rb & ~63;
          int ch = (rb & 63) >> 3;
          *(u64*)&vtb[(size_t)d * NT + blkbase + 8 * (ch ^ (d & 7)) + (rb & 7)] = pk;
        }
      }
  } else {
    // ---------------- qproj body ----------------
    int qbid = bid - KVP_NWG;
    int e = qbid >> 6;
    int t0 = (qbid & 63) * 128;
    int cnt = ws_i[e * 16];
    if (t0 >= cnt) return;
    if (t < 128) tok_s[t] = bucket[e * CAPQ + min(t0 + t, cnt - 1)];
    __syncthreads();
    const u16* Bt = winT + (size_t)e * HD * CC;

    f32x4 acc[4][3];
    #pragma unroll
    for (int i = 0; i < 4; i++)
      #pragma unroll
      for (int j = 0; j < 3; j++) acc[i][j] = (f32x4)(0.f);

    int atok[4];
    #pragma unroll
    for (int i = 0; i < 4; i++) atok[i] = tok_s[i * 32 + sr];

    for (int kb = 0; kb < CC; kb += 64) {
      __syncthreads();
      #pragma unroll
      for (int i = 0; i < 4; i++) {
        int rr = i * 32 + sr;
        int ch = sc ^ (rr & 7);
        gload16(xb + (size_t)atok[i] * CC + kb + ch * 8, &As[rr][sc * 8]);
      }
      #pragma unroll
      for (int i = 0; i < 3; i++) {
        int rr = i * 32 + sr;
        int ch = sc ^ (rr & 7);
        gload16(Bt + (size_t)rr * CC + kb + ch * 8, &Bs[rr][sc * 8]);
      }
      __syncthreads();
      #pragma unroll
      for (int ks = 0; ks < 2; ks++) {
        s16x8 af[4], bf[3];
        #pragma unroll
        for (int i = 0; i < 4; i++)
          af[i] = *(const s16x8*)&As[wr * 64 + i * 16 + lr][8 * ((ks * 4 + lg) ^ (lr & 7))];
        #pragma unroll
        for (int j = 0; j < 3; j++)
          bf[j] = *(const s16x8*)&Bs[wc * 48 + j * 16 + lr][8 * ((ks * 4 + lg) ^ (lr & 7))];
        #pragma unroll
        for (int i = 0; i < 4; i++)
          #pragma unroll
          for (int j = 0; j < 3; j++)
            acc[i][j] = __builtin_amdgcn_mfma_f32_16x16x32_bf16(af[i], bf[j], acc[i][j], 0, 0, 0);
      }
    }
    #pragma unroll
    for (int i = 0; i < 4; i++)
      #pragma unroll
      for (int reg = 0; reg < 4; reg++) {
        int rr = wr * 64 + i * 16 + lg * 4 + reg;
        if (t0 + rr < cnt) {
          int tok = tok_s[rr];
          u16* qp = qall + (size_t)tok * EC + e * HD + wc * 48;
          #pragma unroll
          for (int j = 0; j < 3; j++)
            qp[j * 16 + lr] = f2b(acc[i][j][reg]);
        }
      }
  }
}

// ---- flash attention: 32x32x16 MFMA, 8 waves = 8 heads, 32 tokens/block ----
__global__ __launch_bounds__(512, 2) void attn_kernel(
    const u16* __restrict__ qall, const u16* __restrict__ kvbk,
    const u16* __restrict__ vtb, const u8* __restrict__ eids,
    const float* __restrict__ gbuf, u16* __restrict__ z)
{
  __shared__ u16 Ks[2][64][128];
  __shared__ u16 Vt[2][96][64];
  int b = blockIdx.y;
  int tok0 = blockIdx.x * 32;
  int t = threadIdx.x;
  int w = t >> 6, l = t & 63;
  int h = w;                    // wave = head (8 waves)
  int lo = l & 31, hi = l >> 5;

  s16x8 qf[6];
  {
    int tok = b * NN + tok0 + lo;
    int e = eids[tok * HH + h];
    const u16* qp = qall + (size_t)tok * EC + e * HD + hi * 8;
    #pragma unroll
    for (int ks = 0; ks < 6; ks++)
      qf[ks] = *(const s16x8*)(qp + ks * 16);
  }

  // zero unselected expert slots (first 256 threads; disjoint from all writes)
  if (t < 256) {
    int tk = t >> 3, s8 = t & 7;
    int tok = b * NN + tok0 + tk;
    u64 pk = *(const u64*)&eids[(size_t)tok * HH];
    u32 msk = 0;
    #pragma unroll
    for (int hh = 0; hh < 8; hh++) msk |= 1u << ((pk >> (8 * hh)) & 255u);
    u64* zrow = (u64*)(z + (size_t)tok * EC);
    #pragma unroll
    for (int e = 0; e < EE; e++) {
      if (!((msk >> e) & 1u)) {
        u64* p = zrow + e * 24 + s8 * 3;
        p[0] = 0; p[1] = 0; p[2] = 0;
      }
    }
  }

  const u16* kvwin = kvbk + (size_t)(b * NN) * 128;
  const u16* vwin  = vtb + (size_t)(b * NN);

  f32x16 o0 = (f32x16)(0.f), o1 = (f32x16)(0.f), o2 = (f32x16)(0.f);
  float m = -1e30f, lsum = 0.f;   // m in log2 units

  #pragma unroll
  for (int k2 = 0; k2 < 2; k2++) {
    int c = t + k2 * 512;
    gload16(kvwin + c * 8, &Ks[0][0][0] + c * 8);
  }
  {
    int c = t;
    gload16(vwin + (size_t)(c >> 3) * NT + (c & 7) * 8, &Vt[0][0][0] + c * 8);
    if (t < 256) {
      int c2 = t + 512;
      gload16(vwin + (size_t)(c2 >> 3) * NT + (c2 & 7) * 8, &Vt[0][0][0] + c2 * 8);
    }
  }

  for (int jt = 0; jt < 16; jt++) {
    __syncthreads();
    if (jt < 15) {
      int j0 = (jt + 1) * 64;
      int nb = (jt + 1) & 1;
      const u16* kb_ = kvwin + (size_t)j0 * 128;
      #pragma unroll
      for (int k2 = 0; k2 < 2; k2++) {
        int c = t + k2 * 512;
        gload16(kb_ + c * 8, &Ks[nb][0][0] + c * 8);
      }
      const u16* vb_ = vwin + j0;
      {
        int c = t;
        gload16(vb_ + (size_t)(c >> 3) * NT + (c & 7) * 8, &Vt[nb][0][0] + c * 8);
        if (t < 256) {
          int c2 = t + 512;
          gload16(vb_ + (size_t)(c2 >> 3) * NT + (c2 & 7) * 8, &Vt[nb][0][0] + c2 * 8);
        }
      }
    }
    int buf = jt & 1;

    f32x16 s0 = (f32x16)(0.f), s1 = (f32x16)(0.f);
    #pragma unroll
    for (int ks = 0; ks < 6; ks++) {
      int pos = 8 * ((2 * ks + hi) ^ (lo & 7));
      s16x8 a0 = *(const s16x8*)&Ks[buf][lo][pos];
      s16x8 a1 = *(const s16x8*)&Ks[buf][32 + lo][pos];
      s0 = __builtin_amdgcn_mfma_f32_32x32x16_bf16(a0, qf[ks], s0, 0, 0, 0);
      s1 = __builtin_amdgcn_mfma_f32_32x32x16_bf16(a1, qf[ks], s1, 0, 0, 0);
    }

    float pm = fmaxf(s0[0], s0[1]);
    #pragma unroll
    for (int rg = 2; rg < 16; rg += 2) pm = fmaxf(pm, fmaxf(s0[rg], s0[rg + 1]));
    #pragma unroll
    for (int rg = 0; rg < 16; rg += 2) pm = fmaxf(pm, fmaxf(s1[rg], s1[rg + 1]));
    pm = fmaxf(pm, __shfl_xor(pm, 32));
    pm *= AL2;

    if (!__all(pm - m <= DEFER_THR)) {
      float mn = fmaxf(m, pm);
      float al = fexp2(m - mn);
      m = mn; lsum *= al;
      #pragma unroll
      for (int rg = 0; rg < 16; rg++) {
        int qrow = (rg & 3) + 8 * (rg >> 2) + 4 * hi;
        float alr = __shfl(al, qrow);
        o0[rg] *= alr; o1[rg] *= alr; o2[rg] *= alr;
      }
    }

    float ts = 0.f;
    u32 wpk[2][4][2];
    #pragma unroll
    for (int kb2 = 0; kb2 < 2; kb2++)
      #pragma unroll
      for (int rr = 0; rr < 4; rr++)
        #pragma unroll
        for (int pp = 0; pp < 2; pp++) {
          float sA = kb2 ? s1[rr * 4 + 2 * pp]     : s0[rr * 4 + 2 * pp];
          float sB = kb2 ? s1[rr * 4 + 2 * pp + 1] : s0[rr * 4 + 2 * pp + 1];
          float eA = fexp2(fmaf(sA, AL2, -m));
          float eB = fexp2(fmaf(sB, AL2, -m));
          ts += eA + eB;
          wpk[kb2][rr][pp] = cvtpk(eA, eB);
        }
    lsum += ts;

    s16x8 pa[4];
    #pragma unroll
    for (int ks = 0; ks < 4; ks++) {
      int kb2 = ks >> 1;
      int rlo = (ks & 1) * 2, rhi = rlo + 1;
      u32 own_lo0 = wpk[kb2][rlo][0], own_lo1 = wpk[kb2][rlo][1];
      u32 own_hi0 = wpk[kb2][rhi][0], own_hi1 = wpk[kb2][rhi][1];
      u32 send0 = hi ? own_lo0 : own_hi0;
      u32 send1 = hi ? own_lo1 : own_hi1;
      u32 recv0 = (u32)__shfl_xor((int)send0, 32);
      u32 recv1 = (u32)__shfl_xor((int)send1, 32);
      union { s16x8 v; u32 u[4]; } pu;
      pu.u[0] = hi ? recv0 : own_lo0;
      pu.u[1] = hi ? recv1 : own_lo1;
      pu.u[2] = hi ? own_hi0 : recv0;
      pu.u[3] = hi ? own_hi1 : recv1;
      pa[ks] = pu.v;
    }

    #pragma unroll
    for (int ks = 0; ks < 4; ks++) {
      int pos = 8 * ((2 * ks + hi) ^ (lo & 7));
      s16x8 v0 = *(const s16x8*)&Vt[buf][lo][pos];
      s16x8 v1 = *(const s16x8*)&Vt[buf][32 + lo][pos];
      s16x8 v2 = *(const s16x8*)&Vt[buf][64 + lo][pos];
      o0 = __builtin_amdgcn_mfma_f32_32x32x16_bf16(pa[ks], v0, o0, 0, 0, 0);
      o1 = __builtin_amdgcn_mfma_f32_32x32x16_bf16(pa[ks], v1, o1, 0, 0, 0);
      o2 = __builtin_amdgcn_mfma_f32_32x32x16_bf16(pa[ks], v2, o2, 0, 0, 0);
    }
  }

  float lt = lsum + __shfl_xor(lsum, 32);
  #pragma unroll
  for (int rg = 0; rg < 16; rg++) {
    int qrow = (rg & 3) + 8 * (rg >> 2) + 4 * hi;
    float lv = __shfl(lt, qrow);
    int tok = b * NN + tok0 + qrow;
    int slot = tok * HH + h;
    float scl = gbuf[slot] / lv;
    int e = eids[slot];
    u16* zp = z + (size_t)tok * EC + e * HD + lo;
    zp[0]  = f2b(o0[rg] * scl);
    zp[32] = f2b(o1[rg] * scl);
    zp[64] = f2b(o2[rg] * scl);
  }
}

// ---------------- aux loss ----------------
__global__ void aux_kernel(const float* __restrict__ ws_f,
                           const int* __restrict__ ws_i, float* __restrict__ out)
{
  if (threadIdx.x == 0 && blockIdx.x == 0) {
    float sw = 0.f;
    for (int e = 0; e < EE; e++) {
      float imp = ws_f[WS_IMP / 4 + e * 16] / (float)NT;
      float load = (float)ws_i[e * 16] / (float)(NT * HH);
      sw += imp * load;
    }
    float zl = ws_f[WS_ZSUM / 4] / (float)NT;
    out[(size_t)NT * CC] = 0.1f * ((float)EE * sw) + 0.001f * zl;
  }
}

extern "C" void kernel_launch(void* const* d_in, const int* in_sizes, int n_in,
                              void* d_out, int out_size, void* d_ws, size_t ws_size,
                              hipStream_t stream)
{
  const float* x    = (const float*)d_in[0];
  const float* Wg   = (const float*)d_in[1];
  const float* Win  = (const float*)d_in[2];
  const float* Wout = (const float*)d_in[3];
  const float* Wkv  = (const float*)d_in[4];
  const int*   task = (const int*)d_in[5];
  float* out = (float*)d_out;
  float* ws_f = (float*)d_ws;
  int*   ws_i = (int*)d_ws;
  u8*  eids = (u8*)((char*)d_ws + WS_EID);
  u16* kvbk = (u16*)((char*)d_ws + WS_KVK);
  u16* vtb  = (u16*)((char*)d_ws + WS_VT);
  u16* winT = (u16*)((char*)d_ws + WS_WIN);
  u16* woutT= (u16*)((char*)d_ws + WS_WOUT);
  u16* wkvT = (u16*)((char*)d_ws + WS_WKV);
  u16* qall = (u16*)((char*)d_ws + WS_QA);
  u16* z    = (u16*)((char*)d_ws + WS_Z);
  u16* xb   = (u16*)((char*)d_ws + WS_XB);
  int* bucket = (int*)((char*)d_ws + WS_BUCKET);

  hipMemsetAsync(d_ws, 0, 4096, stream);

  // fused gate (512) + Win/Wout/Wkv transposes (3600): one dispatch
  gate_tr_kernel<<<GATE_NWG + TR1_NWG + TR2_NWG + TR3_NWG, 256, 0, stream>>>(
      x, Wg, task, Win, Wout, Wkv, ws_f, ws_i, eids, xb, bucket,
      winT, woutT, wkvT);

  // fused kvproj (192 blocks) + qproj (1536 blocks): one dispatch
  proj_kernel<<<KVP_NWG + (NT/128) * EE, 256, 0, stream>>>(
      xb, wkvT, winT, ws_i, bucket, kvbk, vtb, qall);

  // z zero-fill folded into attn; xb/bucket dead by attn time.
  attn_kernel<<<dim3(NN/32, BB), 512, 0, stream>>>(qall, kvbk, vtb, eids, ws_f + WS_G/4, z);

  gemm_kernel<128, 64, true><<<dim3(CC/64, NT/128), 256, 0, stream>>>(
      z, woutT, out, NT, CC, EC);

  aux_kernel<<<1, 64, 0, stream>>>(ws_f, ws_i, out);
}

// Round 23
// 149.667 us; speedup vs baseline: 1.3792x; 1.0048x over previous
//
#include <hip/hip_runtime.h>
#include <hip/hip_bf16.h>
#include <math.h>

#define BB 8
#define NN 1024
#define CC 768
#define HH 8
#define HD 96
#define EE 24
#define NT (BB*NN)          // 8192 tokens
#define NSLOT (NT*HH)       // 65536 (token,h) slots
#define EC (EE*HD)          // 2304
#define CAPQ 8192           // per-expert bucket capacity
#define ASCALE 0.10206207261596575f  // 96^-0.5
#define AL2 0.14724446f              // ASCALE * log2(e)
#define DEFER_THR 11.5415603f        // 8 * log2(e)

typedef unsigned short u16;
typedef unsigned char u8;
typedef unsigned int u32;
typedef unsigned long long u64;
typedef __attribute__((ext_vector_type(8))) short s16x8;
typedef __attribute__((ext_vector_type(4))) float f32x4;
typedef __attribute__((ext_vector_type(16))) float f32x16;

__device__ __forceinline__ u16 f2b(float f) {  // RNE float->bf16 bits
  unsigned u = __builtin_bit_cast(unsigned, f);
  unsigned r = u + 0x7fffu + ((u >> 16) & 1u);
  return (u16)(r >> 16);
}

__device__ __forceinline__ float fexp2(float x) {  // native 2^x
  float r; asm("v_exp_f32 %0, %1" : "=v"(r) : "v"(x)); return r;
}

__device__ __forceinline__ u32 cvtpk(float a, float b) {  // HW RNE pack
  u32 d; asm("v_cvt_pk_bf16_f32 %0, %1, %2" : "=v"(d) : "v"(a), "v"(b)); return d;
}

__device__ __forceinline__ void gload16(const u16* g, u16* lds) {
  __builtin_amdgcn_global_load_lds(
      (const __attribute__((address_space(1))) void*)g,
      (__attribute__((address_space(3))) void*)lds, 16, 0, 0);
}

// bijective XCD remap (8 XCDs): contiguous logical chunks per XCD
__device__ __forceinline__ int xcd_remap(int bid, int nwg) {
  int q = nwg >> 3, r = nwg & 7;
  int xcd = bid & 7, idx = bid >> 3;
  return (xcd < r ? xcd * (q + 1) : r * (q + 1) + (xcd - r) * q) + idx;
}

// ws layout (bytes) — counters padded: one 64B cache line per counter
#define WS_CNT   0                             // 24 ints @ stride 16 (ws_i[e*16])
#define WS_IMP   1536                          // 24 f32 @ stride 16
#define WS_ZSUM  3072                          // 1 f32
#define WS_G     4096
#define WS_EID   (WS_G + NSLOT*4)
#define WS_KVK   (WS_EID + NSLOT)              // NT*128 u16 (K, padded+pre-swizzled)
#define WS_VT    (WS_KVK + NT*128*2)           // 96*NT u16 (V^T, in-block pre-swizzled)
#define WS_WIN   (WS_VT + (size_t)96*NT*2)
#define WS_WOUT  (WS_WIN + (size_t)EC*CC*2)
#define WS_WKV   (WS_WOUT + (size_t)CC*EC*2)
#define WS_QA    (WS_WKV + 192*CC*2)
#define WS_Z     (WS_QA + (size_t)NT*EC*2)
#define WS_XB    WS_Z                          // aliases z; xb dead before attn
#define WS_BUCKET (WS_Z + (size_t)16*1024*1024) // aliases z tail; dead before attn

#define GATE_NWG (NT/16)     // 512
#define TR1_NWG  (24*3*24)   // 1728 (W_in)
#define TR2_NWG  (3*24*24)   // 1728 (W_out)
#define TR3_NWG  (24*6)      // 144  (W_kv)

// ---- fused: gate (blocks 0..511) + weight transposes (blocks 512..4111) ----
__global__ __launch_bounds__(256) void gate_tr_kernel(
    const float* __restrict__ x, const float* __restrict__ Wg_all,
    const int* __restrict__ task_p,
    const float* __restrict__ Win, const float* __restrict__ Wout,
    const float* __restrict__ Wkv,
    float* __restrict__ ws_f, int* __restrict__ ws_i,
    u8* __restrict__ eids, u16* __restrict__ xb, int* __restrict__ bucket,
    u16* __restrict__ winT, u16* __restrict__ woutT, u16* __restrict__ wkvT)
{
  __shared__ float xs[16][68];
  __shared__ float wgt[24][68];
  __shared__ float scr[4][16][24];
  __shared__ float lgt[16][26];
  __shared__ float zlo[16];
  __shared__ int hist[EE];
  __shared__ int gbase[EE];
  __shared__ float tile[32][33];

  int bid = blockIdx.x;
  int t = threadIdx.x;

  if (bid < GATE_NWG) {
    // ------------------------- gate body -------------------------
    int w = t >> 6, l = t & 63;
    int pos = l & 15;
    int tg = pos >> 2, eg = pos & 3;
    int kq_low = (l >> 4) & 3;
    int cq = 16 * w + 4 * kq_low;
    int tok0 = bid * 16;
    const float* Wg = Wg_all + (size_t)task_p[0] * CC * EE;

    if (t < EE) hist[t] = 0;

    int rr_ = t >> 4, cc_ = (t & 15) << 2;
    int wkk_[6], we_[6];
    #pragma unroll
    for (int i = 0; i < 6; i++) {
      int f = t + i * 256;
      wkk_[i] = f / 24; we_[i] = f - wkk_[i] * 24;
    }

    float acc[4][6];
    #pragma unroll
    for (int i = 0; i < 4; i++)
      #pragma unroll
      for (int j = 0; j < 6; j++) acc[i][j] = 0.f;

    float4 xv[2]; float wgv[2][6];
    #pragma unroll
    for (int p = 0; p < 2; p++) {
      int kb = p * 64;
      xv[p] = *(const float4*)&x[(size_t)(tok0 + rr_) * CC + kb + cc_];
      #pragma unroll
      for (int i = 0; i < 6; i++)
        wgv[p][i] = Wg[(size_t)(kb + wkk_[i]) * EE + we_[i]];
    }

    #pragma unroll
    for (int s = 0; s < 12; s++) {
      int sl = s & 1;
      __syncthreads();
      *(float4*)&xs[rr_][cc_] = xv[sl];
      {
        float4 v = xv[sl];
        u64 pk = (u64)f2b(v.x) | ((u64)f2b(v.y) << 16) |
                 ((u64)f2b(v.z) << 32) | ((u64)f2b(v.w) << 48);
        *(u64*)&xb[(size_t)(tok0 + rr_) * CC + s * 64 + cc_] = pk;
      }
      #pragma unroll
      for (int i = 0; i < 6; i++) wgt[we_[i]][wkk_[i]] = wgv[sl][i];
      if (s + 2 < 12) {
        int kb = (s + 2) * 64;
        xv[sl] = *(const float4*)&x[(size_t)(tok0 + rr_) * CC + kb + cc_];
        #pragma unroll
        for (int i = 0; i < 6; i++)
          wgv[sl][i] = Wg[(size_t)(kb + wkk_[i]) * EE + we_[i]];
      }
      __syncthreads();
      float4 x4[4];
      #pragma unroll
      for (int i = 0; i < 4; i++) x4[i] = *(const float4*)&xs[tg * 4 + i][cq];
      #pragma unroll
      for (int j = 0; j < 6; j++) {
        float4 w4 = *(const float4*)&wgt[eg * 6 + j][cq];
        #pragma unroll
        for (int i = 0; i < 4; i++) {
          float a = acc[i][j];
          a = fmaf(x4[i].x, w4.x, a);
          a = fmaf(x4[i].y, w4.y, a);
          a = fmaf(x4[i].z, w4.z, a);
          a = fmaf(x4[i].w, w4.w, a);
          acc[i][j] = a;
        }
      }
    }
    #pragma unroll
    for (int i = 0; i < 4; i++)
      #pragma unroll
      for (int j = 0; j < 6; j++) {
        float v = acc[i][j];
        v += __shfl_xor(v, 16);
        v += __shfl_xor(v, 32);
        acc[i][j] = v;
      }
    if (l < 16) {
      #pragma unroll
      for (int i = 0; i < 4; i++)
        #pragma unroll
        for (int j = 0; j < 6; j++) scr[w][pos][i * 6 + j] = acc[i][j];
    }
    __syncthreads();
    if (w == 0 && l < 16) {
      #pragma unroll
      for (int i = 0; i < 4; i++)
        #pragma unroll
        for (int j = 0; j < 6; j++) {
          float s = scr[0][pos][i * 6 + j] + scr[1][pos][i * 6 + j] +
                    scr[2][pos][i * 6 + j] + scr[3][pos][i * 6 + j];
          lgt[tg * 4 + i][eg * 6 + j] = s;
        }
    }
    __syncthreads();

    int my_e[8], loc[8];
    if (t < 16) {
      int token = tok0 + t;
      float lg[EE];
      #pragma unroll
      for (int e = 0; e < EE; e++) lg[e] = lgt[t][e];
      float mx = lg[0];
      #pragma unroll
      for (int e = 1; e < EE; e++) mx = fmaxf(mx, lg[e]);
      float se = 0.f; float probs[EE];
      #pragma unroll
      for (int e = 0; e < EE; e++) { probs[e] = __expf(lg[e] - mx); se += probs[e]; }
      float inv = 1.f / se;
      #pragma unroll
      for (int e = 0; e < EE; e++) probs[e] *= inv;
      float lse = mx + __logf(se);
      zlo[t] = lse * lse;

      unsigned taken = 0u;
      float gsum = 0.f;
      float my_g[8];
      #pragma unroll
      for (int h = 0; h < HH; h++) {
        float best = -1.f; int bi = 0;
        #pragma unroll
        for (int e = 0; e < EE; e++) {
          bool ok = !((taken >> e) & 1u) && (probs[e] > best);
          best = ok ? probs[e] : best;
          bi   = ok ? e : bi;
        }
        taken |= 1u << bi;
        gsum += best;
        my_g[h] = best; my_e[h] = bi;
      }
      float ginv = 1.f / (gsum + 1e-6f);
      float4 g0, g1;
      g0.x = my_g[0] * ginv; g0.y = my_g[1] * ginv; g0.z = my_g[2] * ginv; g0.w = my_g[3] * ginv;
      g1.x = my_g[4] * ginv; g1.y = my_g[5] * ginv; g1.z = my_g[6] * ginv; g1.w = my_g[7] * ginv;
      float* gbuf = ws_f + WS_G / 4;
      *(float4*)&gbuf[(size_t)token * HH]     = g0;
      *(float4*)&gbuf[(size_t)token * HH + 4] = g1;
      u64 pk = 0;
      #pragma unroll
      for (int h = 0; h < HH; h++) pk |= (u64)(u8)my_e[h] << (8 * h);
      *(u64*)&eids[(size_t)token * HH] = pk;
      #pragma unroll
      for (int h = 0; h < HH; h++) loc[h] = atomicAdd(&hist[my_e[h]], 1);
      #pragma unroll
      for (int e = 0; e < EE; e++) lgt[t][e] = probs[e];
    }
    __syncthreads();
    if (t < EE) {
      float s = 0.f;
      #pragma unroll 8
      for (int rr = 0; rr < 16; rr++) s += lgt[rr][t];
      atomicAdd(ws_f + WS_IMP / 4 + t * 16, s);
      gbase[t] = atomicAdd(&ws_i[t * 16], hist[t]);
    } else if (t == 32) {
      float s = 0.f;
      #pragma unroll 8
      for (int rr = 0; rr < 16; rr++) s += zlo[rr];
      atomicAdd(ws_f + WS_ZSUM / 4, s);
    }
    __syncthreads();
    if (t < 16) {
      int token = tok0 + t;
      #pragma unroll
      for (int h = 0; h < HH; h++)
        bucket[my_e[h] * CAPQ + gbase[my_e[h]] + loc[h]] = token;
    }
  } else {
    // ------------------------- transpose body -------------------------
    int lb = bid - GATE_NWG;
    const float* src; u16* dst;
    int C, sB, dR, dB, bx, by, bz;
    if (lb < TR1_NWG) {            // W_in: (24, 3, 24)
      src = Win; dst = winT; C = HD; sB = CC * HD; dR = CC; dB = HD * CC;
      bx = lb % 24; by = (lb / 24) % 3; bz = lb / 72;
    } else if (lb < TR1_NWG + TR2_NWG) {   // W_out: (3, 24, 24)
      lb -= TR1_NWG;
      src = Wout; dst = woutT; C = CC; sB = HD * CC; dR = EC; dB = HD;
      bx = lb % 3; by = (lb / 3) % 24; bz = lb / 72;
    } else {                        // W_kv: (24, 6, 1)
      lb -= TR1_NWG + TR2_NWG;
      src = Wkv; dst = wkvT; C = 192; sB = 0; dR = CC; dB = 0;
      bx = lb % 24; by = lb / 24; bz = 0;
    }
    const float* s = src + (size_t)bz * sB;
    int tr = t >> 5, tc = t & 31;
    #pragma unroll
    for (int i = 0; i < 4; i++) {
      int r = bx * 32 + tr + i * 8;
      int c = by * 32 + tc;
      tile[tr + i * 8][tc] = s[(size_t)r * C + c];
    }
    __syncthreads();
    #pragma unroll
    for (int i = 0; i < 4; i++) {
      int sc_ = by * 32 + tr + i * 8;
      int sr_ = bx * 32 + tc;
      dst[(size_t)bz * dB + (size_t)sc_ * dR + sr_] = f2b(tile[tc][tr + i * 8]);
    }
  }
}

// -------- dense MFMA GEMM (oproj), bf16 A/B, gload_lds, XCD-swizzled --------
// block with logical==0, thread 0 also computes the aux loss (out[NT*CC]).
template<int BM, int BN, bool OUT_F32>
__global__ __launch_bounds__(256) void gemm_kernel(
    const u16* __restrict__ A, const u16* __restrict__ Bt,
    void* __restrict__ Cp, int M, int N, int K,
    const float* __restrict__ ws_f, const int* __restrict__ ws_i)
{
  constexpr int WM = BM / 2, WN = BN / 2;
  constexpr int FM = WM / 16, FN = WN / 16;
  __shared__ u16 As[BM][64];
  __shared__ u16 Bs[BN][64];
  int t = threadIdx.x;
  int w = t >> 6, l = t & 63;
  int lr = l & 15, lg = l >> 4;
  int wr = w >> 1, wc = w & 1;
  int nwg = gridDim.x * gridDim.y;
  int logical = xcd_remap(blockIdx.y * gridDim.x + blockIdx.x, nwg);
  int col0 = (logical % gridDim.x) * BN, row0 = (logical / gridDim.x) * BM;

  f32x4 acc[FM][FN];
  #pragma unroll
  for (int i = 0; i < FM; i++)
    #pragma unroll
    for (int j = 0; j < FN; j++) acc[i][j] = (f32x4)(0.f);

  int sr = t >> 3;
  int sc = t & 7;
  for (int kb = 0; kb < K; kb += 64) {
    __syncthreads();
    #pragma unroll
    for (int i = 0; i < BM / 32; i++) {
      int rr = i * 32 + sr;
      int ch = sc ^ (rr & 7);
      gload16(A + (size_t)(row0 + rr) * K + kb + ch * 8, &As[rr][sc * 8]);
    }
    #pragma unroll
    for (int i = 0; i < BN / 32; i++) {
      int rr = i * 32 + sr;
      int ch = sc ^ (rr & 7);
      gload16(Bt + (size_t)(col0 + rr) * K + kb + ch * 8, &Bs[rr][sc * 8]);
    }
    __syncthreads();
    #pragma unroll
    for (int ks = 0; ks < 2; ks++) {
      s16x8 af[FM], bf[FN];
      #pragma unroll
      for (int i = 0; i < FM; i++)
        af[i] = *(const s16x8*)&As[wr * WM + i * 16 + lr][8 * ((ks * 4 + lg) ^ (lr & 7))];
      #pragma unroll
      for (int j = 0; j < FN; j++)
        bf[j] = *(const s16x8*)&Bs[wc * WN + j * 16 + lr][8 * ((ks * 4 + lg) ^ (lr & 7))];
      #pragma unroll
      for (int i = 0; i < FM; i++)
        #pragma unroll
        for (int j = 0; j < FN; j++)
          acc[i][j] = __builtin_amdgcn_mfma_f32_16x16x32_bf16(af[i], bf[j], acc[i][j], 0, 0, 0);
    }
  }
  #pragma unroll
  for (int i = 0; i < FM; i++)
    #pragma unroll
    for (int j = 0; j < FN; j++)
      #pragma unroll
      for (int reg = 0; reg < 4; reg++) {
        int rr = row0 + wr * WM + i * 16 + lg * 4 + reg;
        int cc = col0 + wc * WN + j * 16 + lr;
        if (OUT_F32) ((float*)Cp)[(size_t)rr * N + cc] = acc[i][j][reg];
        else ((u16*)Cp)[(size_t)rr * N + cc] = f2b(acc[i][j][reg]);
      }

  // ---- aux loss tail (one thread of one block; disjoint output element)
  if (OUT_F32 && logical == 0 && t == 0) {
    float sw = 0.f;
    for (int e = 0; e < EE; e++) {
      float imp = ws_f[WS_IMP / 4 + e * 16] / (float)NT;
      float load = (float)ws_i[e * 16] / (float)(NT * HH);
      sw += imp * load;
    }
    float zl = ws_f[WS_ZSUM / 4] / (float)NT;
    ((float*)Cp)[(size_t)NT * CC] = 0.1f * ((float)EE * sw) + 0.001f * zl;
  }
}

// -------- fused projection kernel: blocks 0..191 = kvproj, 192..1727 = qproj
#define KVP_NWG 192
__global__ __launch_bounds__(256) void proj_kernel(
    const u16* __restrict__ xb, const u16* __restrict__ wkvT,
    const u16* __restrict__ winT, const int* __restrict__ ws_i,
    const int* __restrict__ bucket, u16* __restrict__ kvbk,
    u16* __restrict__ vtb, u16* __restrict__ qall)
{
  __shared__ u16 As[128][64];
  __shared__ u16 Bs[96][64];
  __shared__ int tok_s[128];
  int t = threadIdx.x;
  int w = t >> 6, l = t & 63;
  int lr = l & 15, lg = l >> 4;
  int wr = w >> 1, wc = w & 1;
  int sr = t >> 3, sc = t & 7;
  int bid = blockIdx.x;

  if (bid < KVP_NWG) {
    // ---------------- kvproj body ----------------
    int logical = xcd_remap(bid, KVP_NWG);
    int col0 = (logical % 3) * 64, row0 = (logical / 3) * 128;

    f32x4 acc[4][2];
    #pragma unroll
    for (int i = 0; i < 4; i++)
      #pragma unroll
      for (int j = 0; j < 2; j++) acc[i][j] = (f32x4)(0.f);

    for (int kb = 0; kb < CC; kb += 64) {
      __syncthreads();
      #pragma unroll
      for (int i = 0; i < 4; i++) {
        int rr = i * 32 + sr;
        int ch = sc ^ (rr & 7);
        gload16(xb + (size_t)(row0 + rr) * CC + kb + ch * 8, &As[rr][sc * 8]);
      }
      #pragma unroll
      for (int i = 0; i < 2; i++) {
        int rr = i * 32 + sr;
        int ch = sc ^ (rr & 7);
        gload16(wkvT + (size_t)(col0 + rr) * CC + kb + ch * 8, &Bs[rr][sc * 8]);
      }
      __syncthreads();
      #pragma unroll
      for (int ks = 0; ks < 2; ks++) {
        s16x8 af[4], bf[2];
        #pragma unroll
        for (int i = 0; i < 4; i++)
          af[i] = *(const s16x8*)&As[wr * 64 + i * 16 + lr][8 * ((ks * 4 + lg) ^ (lr & 7))];
        #pragma unroll
        for (int j = 0; j < 2; j++)
          bf[j] = *(const s16x8*)&Bs[wc * 32 + j * 16 + lr][8 * ((ks * 4 + lg) ^ (lr & 7))];
        #pragma unroll
        for (int i = 0; i < 4; i++)
          #pragma unroll
          for (int j = 0; j < 2; j++)
            acc[i][j] = __builtin_amdgcn_mfma_f32_16x16x32_bf16(af[i], bf[j], acc[i][j], 0, 0, 0);
      }
    }
    #pragma unroll
    for (int i = 0; i < 4; i++)
      #pragma unroll
      for (int j = 0; j < 2; j++) {
        int cb = col0 + wc * 32 + j * 16 + lr;
        int rb = row0 + wr * 64 + i * 16 + lg * 4;
        if (cb < 96) {
          int ch = cb >> 3, ci = cb & 7;
          #pragma unroll
          for (int reg = 0; reg < 4; reg++) {
            int tok = rb + reg;
            kvbk[(size_t)tok * 128 + 8 * (ch ^ (tok & 7)) + ci] = f2b(acc[i][j][reg]);
          }
        } else {
          int d = cb - 96;
          u64 pk = (u64)f2b(acc[i][j][0]) | ((u64)f2b(acc[i][j][1]) << 16) |
                   ((u64)f2b(acc[i][j][2]) << 32) | ((u64)f2b(acc[i][j][3]) << 48);
          int blkbase = rb & ~63;
          int ch = (rb & 63) >> 3;
          *(u64*)&vtb[(size_t)d * NT + blkbase + 8 * (ch ^ (d & 7)) + (rb & 7)] = pk;
        }
      }
  } else {
    // ---------------- qproj body ----------------
    int qbid = bid - KVP_NWG;
    int e = qbid >> 6;
    int t0 = (qbid & 63) * 128;
    int cnt = ws_i[e * 16];
    if (t0 >= cnt) return;
    if (t < 128) tok_s[t] = bucket[e * CAPQ + min(t0 + t, cnt - 1)];
    __syncthreads();
    const u16* Bt = winT + (size_t)e * HD * CC;

    f32x4 acc[4][3];
    #pragma unroll
    for (int i = 0; i < 4; i++)
      #pragma unroll
      for (int j = 0; j < 3; j++) acc[i][j] = (f32x4)(0.f);

    int atok[4];
    #pragma unroll
    for (int i = 0; i < 4; i++) atok[i] = tok_s[i * 32 + sr];

    for (int kb = 0; kb < CC; kb += 64) {
      __syncthreads();
      #pragma unroll
      for (int i = 0; i < 4; i++) {
        int rr = i * 32 + sr;
        int ch = sc ^ (rr & 7);
        gload16(xb + (size_t)atok[i] * CC + kb + ch * 8, &As[rr][sc * 8]);
      }
      #pragma unroll
      for (int i = 0; i < 3; i++) {
        int rr = i * 32 + sr;
        int ch = sc ^ (rr & 7);
        gload16(Bt + (size_t)rr * CC + kb + ch * 8, &Bs[rr][sc * 8]);
      }
      __syncthreads();
      #pragma unroll
      for (int ks = 0; ks < 2; ks++) {
        s16x8 af[4], bf[3];
        #pragma unroll
        for (int i = 0; i < 4; i++)
          af[i] = *(const s16x8*)&As[wr * 64 + i * 16 + lr][8 * ((ks * 4 + lg) ^ (lr & 7))];
        #pragma unroll
        for (int j = 0; j < 3; j++)
          bf[j] = *(const s16x8*)&Bs[wc * 48 + j * 16 + lr][8 * ((ks * 4 + lg) ^ (lr & 7))];
        #pragma unroll
        for (int i = 0; i < 4; i++)
          #pragma unroll
          for (int j = 0; j < 3; j++)
            acc[i][j] = __builtin_amdgcn_mfma_f32_16x16x32_bf16(af[i], bf[j], acc[i][j], 0, 0, 0);
      }
    }
    #pragma unroll
    for (int i = 0; i < 4; i++)
      #pragma unroll
      for (int reg = 0; reg < 4; reg++) {
        int rr = wr * 64 + i * 16 + lg * 4 + reg;
        if (t0 + rr < cnt) {
          int tok = tok_s[rr];
          u16* qp = qall + (size_t)tok * EC + e * HD + wc * 48;
          #pragma unroll
          for (int j = 0; j < 3; j++)
            qp[j * 16 + lr] = f2b(acc[i][j][reg]);
        }
      }
  }
}

// ---- flash attention: 32x32x16 MFMA, 8 waves = 8 heads, 32 tokens/block ----
__global__ __launch_bounds__(512, 2) void attn_kernel(
    const u16* __restrict__ qall, const u16* __restrict__ kvbk,
    const u16* __restrict__ vtb, const u8* __restrict__ eids,
    const float* __restrict__ gbuf, u16* __restrict__ z)
{
  __shared__ u16 Ks[2][64][128];
  __shared__ u16 Vt[2][96][64];
  int b = blockIdx.y;
  int tok0 = blockIdx.x * 32;
  int t = threadIdx.x;
  int w = t >> 6, l = t & 63;
  int h = w;                    // wave = head (8 waves)
  int lo = l & 31, hi = l >> 5;

  s16x8 qf[6];
  {
    int tok = b * NN + tok0 + lo;
    int e = eids[tok * HH + h];
    const u16* qp = qall + (size_t)tok * EC + e * HD + hi * 8;
    #pragma unroll
    for (int ks = 0; ks < 6; ks++)
      qf[ks] = *(const s16x8*)(qp + ks * 16);
  }

  // zero unselected expert slots (first 256 threads; disjoint from all writes)
  if (t < 256) {
    int tk = t >> 3, s8 = t & 7;
    int tok = b * NN + tok0 + tk;
    u64 pk = *(const u64*)&eids[(size_t)tok * HH];
    u32 msk = 0;
    #pragma unroll
    for (int hh = 0; hh < 8; hh++) msk |= 1u << ((pk >> (8 * hh)) & 255u);
    u64* zrow = (u64*)(z + (size_t)tok * EC);
    #pragma unroll
    for (int e = 0; e < EE; e++) {
      if (!((msk >> e) & 1u)) {
        u64* p = zrow + e * 24 + s8 * 3;
        p[0] = 0; p[1] = 0; p[2] = 0;
      }
    }
  }

  const u16* kvwin = kvbk + (size_t)(b * NN) * 128;
  const u16* vwin  = vtb + (size_t)(b * NN);

  f32x16 o0 = (f32x16)(0.f), o1 = (f32x16)(0.f), o2 = (f32x16)(0.f);
  float m = -1e30f, lsum = 0.f;   // m in log2 units

  #pragma unroll
  for (int k2 = 0; k2 < 2; k2++) {
    int c = t + k2 * 512;
    gload16(kvwin + c * 8, &Ks[0][0][0] + c * 8);
  }
  {
    int c = t;
    gload16(vwin + (size_t)(c >> 3) * NT + (c & 7) * 8, &Vt[0][0][0] + c * 8);
    if (t < 256) {
      int c2 = t + 512;
      gload16(vwin + (size_t)(c2 >> 3) * NT + (c2 & 7) * 8, &Vt[0][0][0] + c2 * 8);
    }
  }

  for (int jt = 0; jt < 16; jt++) {
    __syncthreads();
    if (jt < 15) {
      int j0 = (jt + 1) * 64;
      int nb = (jt + 1) & 1;
      const u16* kb_ = kvwin + (size_t)j0 * 128;
      #pragma unroll
      for (int k2 = 0; k2 < 2; k2++) {
        int c = t + k2 * 512;
        gload16(kb_ + c * 8, &Ks[nb][0][0] + c * 8);
      }
      const u16* vb_ = vwin + j0;
      {
        int c = t;
        gload16(vb_ + (size_t)(c >> 3) * NT + (c & 7) * 8, &Vt[nb][0][0] + c * 8);
        if (t < 256) {
          int c2 = t + 512;
          gload16(vb_ + (size_t)(c2 >> 3) * NT + (c2 & 7) * 8, &Vt[nb][0][0] + c2 * 8);
        }
      }
    }
    int buf = jt & 1;

    f32x16 s0 = (f32x16)(0.f), s1 = (f32x16)(0.f);
    #pragma unroll
    for (int ks = 0; ks < 6; ks++) {
      int pos = 8 * ((2 * ks + hi) ^ (lo & 7));
      s16x8 a0 = *(const s16x8*)&Ks[buf][lo][pos];
      s16x8 a1 = *(const s16x8*)&Ks[buf][32 + lo][pos];
      s0 = __builtin_amdgcn_mfma_f32_32x32x16_bf16(a0, qf[ks], s0, 0, 0, 0);
      s1 = __builtin_amdgcn_mfma_f32_32x32x16_bf16(a1, qf[ks], s1, 0, 0, 0);
    }

    float pm = fmaxf(s0[0], s0[1]);
    #pragma unroll
    for (int rg = 2; rg < 16; rg += 2) pm = fmaxf(pm, fmaxf(s0[rg], s0[rg + 1]));
    #pragma unroll
    for (int rg = 0; rg < 16; rg += 2) pm = fmaxf(pm, fmaxf(s1[rg], s1[rg + 1]));
    pm = fmaxf(pm, __shfl_xor(pm, 32));
    pm *= AL2;

    if (!__all(pm - m <= DEFER_THR)) {
      float mn = fmaxf(m, pm);
      float al = fexp2(m - mn);
      m = mn; lsum *= al;
      #pragma unroll
      for (int rg = 0; rg < 16; rg++) {
        int qrow = (rg & 3) + 8 * (rg >> 2) + 4 * hi;
        float alr = __shfl(al, qrow);
        o0[rg] *= alr; o1[rg] *= alr; o2[rg] *= alr;
      }
    }

    float ts = 0.f;
    u32 wpk[2][4][2];
    #pragma unroll
    for (int kb2 = 0; kb2 < 2; kb2++)
      #pragma unroll
      for (int rr = 0; rr < 4; rr++)
        #pragma unroll
        for (int pp = 0; pp < 2; pp++) {
          float sA = kb2 ? s1[rr * 4 + 2 * pp]     : s0[rr * 4 + 2 * pp];
          float sB = kb2 ? s1[rr * 4 + 2 * pp + 1] : s0[rr * 4 + 2 * pp + 1];
          float eA = fexp2(fmaf(sA, AL2, -m));
          float eB = fexp2(fmaf(sB, AL2, -m));
          ts += eA + eB;
          wpk[kb2][rr][pp] = cvtpk(eA, eB);
        }
    lsum += ts;

    s16x8 pa[4];
    #pragma unroll
    for (int ks = 0; ks < 4; ks++) {
      int kb2 = ks >> 1;
      int rlo = (ks & 1) * 2, rhi = rlo + 1;
      u32 own_lo0 = wpk[kb2][rlo][0], own_lo1 = wpk[kb2][rlo][1];
      u32 own_hi0 = wpk[kb2][rhi][0], own_hi1 = wpk[kb2][rhi][1];
      u32 send0 = hi ? own_lo0 : own_hi0;
      u32 send1 = hi ? own_lo1 : own_hi1;
      u32 recv0 = (u32)__shfl_xor((int)send0, 32);
      u32 recv1 = (u32)__shfl_xor((int)send1, 32);
      union { s16x8 v; u32 u[4]; } pu;
      pu.u[0] = hi ? recv0 : own_lo0;
      pu.u[1] = hi ? recv1 : own_lo1;
      pu.u[2] = hi ? own_hi0 : recv0;
      pu.u[3] = hi ? own_hi1 : recv1;
      pa[ks] = pu.v;
    }

    #pragma unroll
    for (int ks = 0; ks < 4; ks++) {
      int pos = 8 * ((2 * ks + hi) ^ (lo & 7));
      s16x8 v0 = *(const s16x8*)&Vt[buf][lo][pos];
      s16x8 v1 = *(const s16x8*)&Vt[buf][32 + lo][pos];
      s16x8 v2 = *(const s16x8*)&Vt[buf][64 + lo][pos];
      o0 = __builtin_amdgcn_mfma_f32_32x32x16_bf16(pa[ks], v0, o0, 0, 0, 0);
      o1 = __builtin_amdgcn_mfma_f32_32x32x16_bf16(pa[ks], v1, o1, 0, 0, 0);
      o2 = __builtin_amdgcn_mfma_f32_32x32x16_bf16(pa[ks], v2, o2, 0, 0, 0);
    }
  }

  float lt = lsum + __shfl_xor(lsum, 32);
  #pragma unroll
  for (int rg = 0; rg < 16; rg++) {
    int qrow = (rg & 3) + 8 * (rg >> 2) + 4 * hi;
    float lv = __shfl(lt, qrow);
    int tok = b * NN + tok0 + qrow;
    int slot = tok * HH + h;
    float scl = gbuf[slot] / lv;
    int e = eids[slot];
    u16* zp = z + (size_t)tok * EC + e * HD + lo;
    zp[0]  = f2b(o0[rg] * scl);
    zp[32] = f2b(o1[rg] * scl);
    zp[64] = f2b(o2[rg] * scl);
  }
}

extern "C" void kernel_launch(void* const* d_in, const int* in_sizes, int n_in,
                              void* d_out, int out_size, void* d_ws, size_t ws_size,
                              hipStream_t stream)
{
  const float* x    = (const float*)d_in[0];
  const float* Wg   = (const float*)d_in[1];
  const float* Win  = (const float*)d_in[2];
  const float* Wout = (const float*)d_in[3];
  const float* Wkv  = (const float*)d_in[4];
  const int*   task = (const int*)d_in[5];
  float* out = (float*)d_out;
  float* ws_f = (float*)d_ws;
  int*   ws_i = (int*)d_ws;
  u8*  eids = (u8*)((char*)d_ws + WS_EID);
  u16* kvbk = (u16*)((char*)d_ws + WS_KVK);
  u16* vtb  = (u16*)((char*)d_ws + WS_VT);
  u16* winT = (u16*)((char*)d_ws + WS_WIN);
  u16* woutT= (u16*)((char*)d_ws + WS_WOUT);
  u16* wkvT = (u16*)((char*)d_ws + WS_WKV);
  u16* qall = (u16*)((char*)d_ws + WS_QA);
  u16* z    = (u16*)((char*)d_ws + WS_Z);
  u16* xb   = (u16*)((char*)d_ws + WS_XB);
  int* bucket = (int*)((char*)d_ws + WS_BUCKET);

  hipMemsetAsync(d_ws, 0, 4096, stream);

  // fused gate (512) + Win/Wout/Wkv transposes (3600): one dispatch
  gate_tr_kernel<<<GATE_NWG + TR1_NWG + TR2_NWG + TR3_NWG, 256, 0, stream>>>(
      x, Wg, task, Win, Wout, Wkv, ws_f, ws_i, eids, xb, bucket,
      winT, woutT, wkvT);

  // fused kvproj (192 blocks) + qproj (1536 blocks): one dispatch
  proj_kernel<<<KVP_NWG + (NT/128) * EE, 256, 0, stream>>>(
      xb, wkvT, winT, ws_i, bucket, kvbk, vtb, qall);

  // z zero-fill folded into attn; xb/bucket dead by attn time.
  attn_kernel<<<dim3(NN/32, BB), 512, 0, stream>>>(qall, kvbk, vtb, eids, ws_f + WS_G/4, z);

  // oproj GEMM (+ aux loss folded into the logical==0 block's epilogue)
  gemm_kernel<128, 64, true><<<dim3(CC/64, NT/128), 256, 0, stream>>>(
      z, woutT, out, NT, CC, EC, ws_f, ws_i);
}

// Round 24
// 149.251 us; speedup vs baseline: 1.3830x; 1.0028x over previous
//
#include <hip/hip_runtime.h>
#include <hip/hip_bf16.h>
#include <math.h>

#define BB 8
#define NN 1024
#define CC 768
#define HH 8
#define HD 96
#define EE 24
#define NT (BB*NN)          // 8192 tokens
#define NSLOT (NT*HH)       // 65536 (token,h) slots
#define EC (EE*HD)          // 2304
#define CAPQ 8192           // per-expert bucket capacity
#define ASCALE 0.10206207261596575f  // 96^-0.5
#define AL2 0.14724446f              // ASCALE * log2(e)
#define DEFER_THR 11.5415603f        // 8 * log2(e)

typedef unsigned short u16;
typedef unsigned char u8;
typedef unsigned int u32;
typedef unsigned long long u64;
typedef __attribute__((ext_vector_type(8))) short s16x8;
typedef __attribute__((ext_vector_type(4))) float f32x4;
typedef __attribute__((ext_vector_type(16))) float f32x16;

__device__ __forceinline__ u16 f2b(float f) {  // RNE float->bf16 bits
  unsigned u = __builtin_bit_cast(unsigned, f);
  unsigned r = u + 0x7fffu + ((u >> 16) & 1u);
  return (u16)(r >> 16);
}

__device__ __forceinline__ float fexp2(float x) {  // native 2^x
  float r; asm("v_exp_f32 %0, %1" : "=v"(r) : "v"(x)); return r;
}

__device__ __forceinline__ u32 cvtpk(float a, float b) {  // HW RNE pack
  u32 d; asm("v_cvt_pk_bf16_f32 %0, %1, %2" : "=v"(d) : "v"(a), "v"(b)); return d;
}

__device__ __forceinline__ void gload16(const u16* g, u16* lds) {
  __builtin_amdgcn_global_load_lds(
      (const __attribute__((address_space(1))) void*)g,
      (__attribute__((address_space(3))) void*)lds, 16, 0, 0);
}

// bijective XCD remap (8 XCDs): contiguous logical chunks per XCD
__device__ __forceinline__ int xcd_remap(int bid, int nwg) {
  int q = nwg >> 3, r = nwg & 7;
  int xcd = bid & 7, idx = bid >> 3;
  return (xcd < r ? xcd * (q + 1) : r * (q + 1) + (xcd - r) * q) + idx;
}

// ws layout (bytes) — counters padded: one 64B cache line per counter
#define WS_CNT   0                             // 24 ints @ stride 16 (ws_i[e*16])
#define WS_IMP   1536                          // 24 f32 @ stride 16
#define WS_ZSUM  3072                          // 1 f32
#define WS_G     4096
#define WS_EID   (WS_G + NSLOT*4)
#define WS_KVK   (WS_EID + NSLOT)              // NT*128 u16 (K, padded+pre-swizzled)
#define WS_VT    (WS_KVK + NT*128*2)           // 96*NT u16 (V^T, in-block pre-swizzled)
#define WS_WIN   (WS_VT + (size_t)96*NT*2)
#define WS_WOUT  (WS_WIN + (size_t)EC*CC*2)
#define WS_WKV   (WS_WOUT + (size_t)CC*EC*2)
#define WS_QA    (WS_WKV + 192*CC*2)
#define WS_Z     (WS_QA + (size_t)NT*EC*2)
#define WS_XB    WS_Z                          // aliases z; xb dead before attn
#define WS_BUCKET (WS_Z + (size_t)16*1024*1024) // aliases z tail; dead before attn

#define GATE_NWG (NT/16)     // 512
#define TR1_NWG  (24*3*24)   // 1728 (W_in)
#define TR2_NWG  (3*24*24)   // 1728 (W_out)
#define TR3_NWG  (24*6)      // 144  (W_kv)

// ---- fused: gate (blocks 0..511) + weight transposes (blocks 512..4111) ----
__global__ __launch_bounds__(256) void gate_tr_kernel(
    const float* __restrict__ x, const float* __restrict__ Wg_all,
    const int* __restrict__ task_p,
    const float* __restrict__ Win, const float* __restrict__ Wout,
    const float* __restrict__ Wkv,
    float* __restrict__ ws_f, int* __restrict__ ws_i,
    u8* __restrict__ eids, u16* __restrict__ xb, int* __restrict__ bucket,
    u16* __restrict__ winT, u16* __restrict__ woutT, u16* __restrict__ wkvT)
{
  __shared__ float xs[16][68];
  __shared__ float wgt[24][68];
  __shared__ float scr[4][16][24];
  __shared__ float lgt[16][26];
  __shared__ float zlo[16];
  __shared__ int hist[EE];
  __shared__ int gbase[EE];
  __shared__ float tile[32][33];

  int bid = blockIdx.x;
  int t = threadIdx.x;

  if (bid < GATE_NWG) {
    // ------------------------- gate body -------------------------
    int w = t >> 6, l = t & 63;
    int pos = l & 15;
    int tg = pos >> 2, eg = pos & 3;
    int kq_low = (l >> 4) & 3;
    int cq = 16 * w + 4 * kq_low;
    int tok0 = bid * 16;
    const float* Wg = Wg_all + (size_t)task_p[0] * CC * EE;

    if (t < EE) hist[t] = 0;

    int rr_ = t >> 4, cc_ = (t & 15) << 2;
    int wkk_[6], we_[6];
    #pragma unroll
    for (int i = 0; i < 6; i++) {
      int f = t + i * 256;
      wkk_[i] = f / 24; we_[i] = f - wkk_[i] * 24;
    }

    float acc[4][6];
    #pragma unroll
    for (int i = 0; i < 4; i++)
      #pragma unroll
      for (int j = 0; j < 6; j++) acc[i][j] = 0.f;

    float4 xv[2]; float wgv[2][6];
    #pragma unroll
    for (int p = 0; p < 2; p++) {
      int kb = p * 64;
      xv[p] = *(const float4*)&x[(size_t)(tok0 + rr_) * CC + kb + cc_];
      #pragma unroll
      for (int i = 0; i < 6; i++)
        wgv[p][i] = Wg[(size_t)(kb + wkk_[i]) * EE + we_[i]];
    }

    #pragma unroll
    for (int s = 0; s < 12; s++) {
      int sl = s & 1;
      __syncthreads();
      *(float4*)&xs[rr_][cc_] = xv[sl];
      {
        float4 v = xv[sl];
        u64 pk = (u64)f2b(v.x) | ((u64)f2b(v.y) << 16) |
                 ((u64)f2b(v.z) << 32) | ((u64)f2b(v.w) << 48);
        *(u64*)&xb[(size_t)(tok0 + rr_) * CC + s * 64 + cc_] = pk;
      }
      #pragma unroll
      for (int i = 0; i < 6; i++) wgt[we_[i]][wkk_[i]] = wgv[sl][i];
      if (s + 2 < 12) {
        int kb = (s + 2) * 64;
        xv[sl] = *(const float4*)&x[(size_t)(tok0 + rr_) * CC + kb + cc_];
        #pragma unroll
        for (int i = 0; i < 6; i++)
          wgv[sl][i] = Wg[(size_t)(kb + wkk_[i]) * EE + we_[i]];
      }
      __syncthreads();
      float4 x4[4];
      #pragma unroll
      for (int i = 0; i < 4; i++) x4[i] = *(const float4*)&xs[tg * 4 + i][cq];
      #pragma unroll
      for (int j = 0; j < 6; j++) {
        float4 w4 = *(const float4*)&wgt[eg * 6 + j][cq];
        #pragma unroll
        for (int i = 0; i < 4; i++) {
          float a = acc[i][j];
          a = fmaf(x4[i].x, w4.x, a);
          a = fmaf(x4[i].y, w4.y, a);
          a = fmaf(x4[i].z, w4.z, a);
          a = fmaf(x4[i].w, w4.w, a);
          acc[i][j] = a;
        }
      }
    }
    #pragma unroll
    for (int i = 0; i < 4; i++)
      #pragma unroll
      for (int j = 0; j < 6; j++) {
        float v = acc[i][j];
        v += __shfl_xor(v, 16);
        v += __shfl_xor(v, 32);
        acc[i][j] = v;
      }
    if (l < 16) {
      #pragma unroll
      for (int i = 0; i < 4; i++)
        #pragma unroll
        for (int j = 0; j < 6; j++) scr[w][pos][i * 6 + j] = acc[i][j];
    }
    __syncthreads();
    if (w == 0 && l < 16) {
      #pragma unroll
      for (int i = 0; i < 4; i++)
        #pragma unroll
        for (int j = 0; j < 6; j++) {
          float s = scr[0][pos][i * 6 + j] + scr[1][pos][i * 6 + j] +
                    scr[2][pos][i * 6 + j] + scr[3][pos][i * 6 + j];
          lgt[tg * 4 + i][eg * 6 + j] = s;
        }
    }
    __syncthreads();

    int my_e[8], loc[8];
    if (t < 16) {
      int token = tok0 + t;
      float lg[EE];
      #pragma unroll
      for (int e = 0; e < EE; e++) lg[e] = lgt[t][e];
      float mx = lg[0];
      #pragma unroll
      for (int e = 1; e < EE; e++) mx = fmaxf(mx, lg[e]);
      float se = 0.f; float probs[EE];
      #pragma unroll
      for (int e = 0; e < EE; e++) { probs[e] = __expf(lg[e] - mx); se += probs[e]; }
      float inv = 1.f / se;
      #pragma unroll
      for (int e = 0; e < EE; e++) probs[e] *= inv;
      float lse = mx + __logf(se);
      zlo[t] = lse * lse;

      unsigned taken = 0u;
      float gsum = 0.f;
      float my_g[8];
      #pragma unroll
      for (int h = 0; h < HH; h++) {
        float best = -1.f; int bi = 0;
        #pragma unroll
        for (int e = 0; e < EE; e++) {
          bool ok = !((taken >> e) & 1u) && (probs[e] > best);
          best = ok ? probs[e] : best;
          bi   = ok ? e : bi;
        }
        taken |= 1u << bi;
        gsum += best;
        my_g[h] = best; my_e[h] = bi;
      }
      float ginv = 1.f / (gsum + 1e-6f);
      float4 g0, g1;
      g0.x = my_g[0] * ginv; g0.y = my_g[1] * ginv; g0.z = my_g[2] * ginv; g0.w = my_g[3] * ginv;
      g1.x = my_g[4] * ginv; g1.y = my_g[5] * ginv; g1.z = my_g[6] * ginv; g1.w = my_g[7] * ginv;
      float* gbuf = ws_f + WS_G / 4;
      *(float4*)&gbuf[(size_t)token * HH]     = g0;
      *(float4*)&gbuf[(size_t)token * HH + 4] = g1;
      u64 pk = 0;
      #pragma unroll
      for (int h = 0; h < HH; h++) pk |= (u64)(u8)my_e[h] << (8 * h);
      *(u64*)&eids[(size_t)token * HH] = pk;
      #pragma unroll
      for (int h = 0; h < HH; h++) loc[h] = atomicAdd(&hist[my_e[h]], 1);
      #pragma unroll
      for (int e = 0; e < EE; e++) lgt[t][e] = probs[e];
    }
    __syncthreads();
    if (t < EE) {
      float s = 0.f;
      #pragma unroll 8
      for (int rr = 0; rr < 16; rr++) s += lgt[rr][t];
      atomicAdd(ws_f + WS_IMP / 4 + t * 16, s);
      gbase[t] = atomicAdd(&ws_i[t * 16], hist[t]);
    } else if (t == 32) {
      float s = 0.f;
      #pragma unroll 8
      for (int rr = 0; rr < 16; rr++) s += zlo[rr];
      atomicAdd(ws_f + WS_ZSUM / 4, s);
    }
    __syncthreads();
    if (t < 16) {
      int token = tok0 + t;
      #pragma unroll
      for (int h = 0; h < HH; h++)
        bucket[my_e[h] * CAPQ + gbase[my_e[h]] + loc[h]] = token;
    }
  } else {
    // ------------------------- transpose body -------------------------
    int lb = bid - GATE_NWG;
    const float* src; u16* dst;
    int C, sB, dR, dB, bx, by, bz;
    if (lb < TR1_NWG) {            // W_in: (24, 3, 24)
      src = Win; dst = winT; C = HD; sB = CC * HD; dR = CC; dB = HD * CC;
      bx = lb % 24; by = (lb / 24) % 3; bz = lb / 72;
    } else if (lb < TR1_NWG + TR2_NWG) {   // W_out: (3, 24, 24)
      lb -= TR1_NWG;
      src = Wout; dst = woutT; C = CC; sB = HD * CC; dR = EC; dB = HD;
      bx = lb % 3; by = (lb / 3) % 24; bz = lb / 72;
    } else {                        // W_kv: (24, 6, 1)
      lb -= TR1_NWG + TR2_NWG;
      src = Wkv; dst = wkvT; C = 192; sB = 0; dR = CC; dB = 0;
      bx = lb % 24; by = lb / 24; bz = 0;
    }
    const float* s = src + (size_t)bz * sB;
    int tr = t >> 5, tc = t & 31;
    #pragma unroll
    for (int i = 0; i < 4; i++) {
      int r = bx * 32 + tr + i * 8;
      int c = by * 32 + tc;
      tile[tr + i * 8][tc] = s[(size_t)r * C + c];
    }
    __syncthreads();
    #pragma unroll
    for (int i = 0; i < 4; i++) {
      int sc_ = by * 32 + tr + i * 8;
      int sr_ = bx * 32 + tc;
      dst[(size_t)bz * dB + (size_t)sc_ * dR + sr_] = f2b(tile[tc][tr + i * 8]);
    }
  }
}

// -------- dense MFMA GEMM (oproj), bf16 A/B, gload_lds, XCD-swizzled --------
// block with logical==0, thread 0 also computes the aux loss (out[NT*CC]).
template<int BM, int BN, bool OUT_F32>
__global__ __launch_bounds__(256) void gemm_kernel(
    const u16* __restrict__ A, const u16* __restrict__ Bt,
    void* __restrict__ Cp, int M, int N, int K,
    const float* __restrict__ ws_f, const int* __restrict__ ws_i)
{
  constexpr int WM = BM / 2, WN = BN / 2;
  constexpr int FM = WM / 16, FN = WN / 16;
  __shared__ u16 As[BM][64];
  __shared__ u16 Bs[BN][64];
  int t = threadIdx.x;
  int w = t >> 6, l = t & 63;
  int lr = l & 15, lg = l >> 4;
  int wr = w >> 1, wc = w & 1;
  int nwg = gridDim.x * gridDim.y;
  int logical = xcd_remap(blockIdx.y * gridDim.x + blockIdx.x, nwg);
  int col0 = (logical % gridDim.x) * BN, row0 = (logical / gridDim.x) * BM;

  f32x4 acc[FM][FN];
  #pragma unroll
  for (int i = 0; i < FM; i++)
    #pragma unroll
    for (int j = 0; j < FN; j++) acc[i][j] = (f32x4)(0.f);

  int sr = t >> 3;
  int sc = t & 7;
  for (int kb = 0; kb < K; kb += 64) {
    __syncthreads();
    #pragma unroll
    for (int i = 0; i < BM / 32; i++) {
      int rr = i * 32 + sr;
      int ch = sc ^ (rr & 7);
      gload16(A + (size_t)(row0 + rr) * K + kb + ch * 8, &As[rr][sc * 8]);
    }
    #pragma unroll
    for (int i = 0; i < BN / 32; i++) {
      int rr = i * 32 + sr;
      int ch = sc ^ (rr & 7);
      gload16(Bt + (size_t)(col0 + rr) * K + kb + ch * 8, &Bs[rr][sc * 8]);
    }
    __syncthreads();
    #pragma unroll
    for (int ks = 0; ks < 2; ks++) {
      s16x8 af[FM], bf[FN];
      #pragma unroll
      for (int i = 0; i < FM; i++)
        af[i] = *(const s16x8*)&As[wr * WM + i * 16 + lr][8 * ((ks * 4 + lg) ^ (lr & 7))];
      #pragma unroll
      for (int j = 0; j < FN; j++)
        bf[j] = *(const s16x8*)&Bs[wc * WN + j * 16 + lr][8 * ((ks * 4 + lg) ^ (lr & 7))];
      #pragma unroll
      for (int i = 0; i < FM; i++)
        #pragma unroll
        for (int j = 0; j < FN; j++)
          acc[i][j] = __builtin_amdgcn_mfma_f32_16x16x32_bf16(af[i], bf[j], acc[i][j], 0, 0, 0);
    }
  }
  #pragma unroll
  for (int i = 0; i < FM; i++)
    #pragma unroll
    for (int j = 0; j < FN; j++)
      #pragma unroll
      for (int reg = 0; reg < 4; reg++) {
        int rr = row0 + wr * WM + i * 16 + lg * 4 + reg;
        int cc = col0 + wc * WN + j * 16 + lr;
        if (OUT_F32) ((float*)Cp)[(size_t)rr * N + cc] = acc[i][j][reg];
        else ((u16*)Cp)[(size_t)rr * N + cc] = f2b(acc[i][j][reg]);
      }

  // ---- aux loss tail (one thread of one block; disjoint output element)
  if (OUT_F32 && logical == 0 && t == 0) {
    float sw = 0.f;
    for (int e = 0; e < EE; e++) {
      float imp = ws_f[WS_IMP / 4 + e * 16] / (float)NT;
      float load = (float)ws_i[e * 16] / (float)(NT * HH);
      sw += imp * load;
    }
    float zl = ws_f[WS_ZSUM / 4] / (float)NT;
    ((float*)Cp)[(size_t)NT * CC] = 0.1f * ((float)EE * sw) + 0.001f * zl;
  }
}

// -------- fused projection kernel: blocks 0..191 = kvproj, 192..1727 = qproj
#define KVP_NWG 192
__global__ __launch_bounds__(256) void proj_kernel(
    const u16* __restrict__ xb, const u16* __restrict__ wkvT,
    const u16* __restrict__ winT, const int* __restrict__ ws_i,
    const int* __restrict__ bucket, u16* __restrict__ kvbk,
    u16* __restrict__ vtb, u16* __restrict__ qall)
{
  __shared__ u16 As[128][64];
  __shared__ u16 Bs[96][64];
  __shared__ int tok_s[128];
  int t = threadIdx.x;
  int w = t >> 6, l = t & 63;
  int lr = l & 15, lg = l >> 4;
  int wr = w >> 1, wc = w & 1;
  int sr = t >> 3, sc = t & 7;
  int bid = blockIdx.x;

  if (bid < KVP_NWG) {
    // ---------------- kvproj body ----------------
    int logical = xcd_remap(bid, KVP_NWG);
    int col0 = (logical % 3) * 64, row0 = (logical / 3) * 128;

    f32x4 acc[4][2];
    #pragma unroll
    for (int i = 0; i < 4; i++)
      #pragma unroll
      for (int j = 0; j < 2; j++) acc[i][j] = (f32x4)(0.f);

    for (int kb = 0; kb < CC; kb += 64) {
      __syncthreads();
      #pragma unroll
      for (int i = 0; i < 4; i++) {
        int rr = i * 32 + sr;
        int ch = sc ^ (rr & 7);
        gload16(xb + (size_t)(row0 + rr) * CC + kb + ch * 8, &As[rr][sc * 8]);
      }
      #pragma unroll
      for (int i = 0; i < 2; i++) {
        int rr = i * 32 + sr;
        int ch = sc ^ (rr & 7);
        gload16(wkvT + (size_t)(col0 + rr) * CC + kb + ch * 8, &Bs[rr][sc * 8]);
      }
      __syncthreads();
      #pragma unroll
      for (int ks = 0; ks < 2; ks++) {
        s16x8 af[4], bf[2];
        #pragma unroll
        for (int i = 0; i < 4; i++)
          af[i] = *(const s16x8*)&As[wr * 64 + i * 16 + lr][8 * ((ks * 4 + lg) ^ (lr & 7))];
        #pragma unroll
        for (int j = 0; j < 2; j++)
          bf[j] = *(const s16x8*)&Bs[wc * 32 + j * 16 + lr][8 * ((ks * 4 + lg) ^ (lr & 7))];
        #pragma unroll
        for (int i = 0; i < 4; i++)
          #pragma unroll
          for (int j = 0; j < 2; j++)
            acc[i][j] = __builtin_amdgcn_mfma_f32_16x16x32_bf16(af[i], bf[j], acc[i][j], 0, 0, 0);
      }
    }
    #pragma unroll
    for (int i = 0; i < 4; i++)
      #pragma unroll
      for (int j = 0; j < 2; j++) {
        int cb = col0 + wc * 32 + j * 16 + lr;
        int rb = row0 + wr * 64 + i * 16 + lg * 4;
        if (cb < 96) {
          int ch = cb >> 3, ci = cb & 7;
          #pragma unroll
          for (int reg = 0; reg < 4; reg++) {
            int tok = rb + reg;
            kvbk[(size_t)tok * 128 + 8 * (ch ^ (tok & 7)) + ci] = f2b(acc[i][j][reg]);
          }
        } else {
          int d = cb - 96;
          u64 pk = (u64)f2b(acc[i][j][0]) | ((u64)f2b(acc[i][j][1]) << 16) |
                   ((u64)f2b(acc[i][j][2]) << 32) | ((u64)f2b(acc[i][j][3]) << 48);
          int blkbase = rb & ~63;
          int ch = (rb & 63) >> 3;
          *(u64*)&vtb[(size_t)d * NT + blkbase + 8 * (ch ^ (d & 7)) + (rb & 7)] = pk;
        }
      }
  } else {
    // ---------------- qproj body ----------------
    int qbid = bid - KVP_NWG;
    int e = qbid >> 6;
    int t0 = (qbid & 63) * 128;
    int cnt = ws_i[e * 16];
    if (t0 >= cnt) return;
    if (t < 128) tok_s[t] = bucket[e * CAPQ + min(t0 + t, cnt - 1)];
    __syncthreads();
    const u16* Bt = winT + (size_t)e * HD * CC;

    f32x4 acc[4][3];
    #pragma unroll
    for (int i = 0; i < 4; i++)
      #pragma unroll
      for (int j = 0; j < 3; j++) acc[i][j] = (f32x4)(0.f);

    int atok[4];
    #pragma unroll
    for (int i = 0; i < 4; i++) atok[i] = tok_s[i * 32 + sr];

    for (int kb = 0; kb < CC; kb += 64) {
      __syncthreads();
      #pragma unroll
      for (int i = 0; i < 4; i++) {
        int rr = i * 32 + sr;
        int ch = sc ^ (rr & 7);
        gload16(xb + (size_t)atok[i] * CC + kb + ch * 8, &As[rr][sc * 8]);
      }
      #pragma unroll
      for (int i = 0; i < 3; i++) {
        int rr = i * 32 + sr;
        int ch = sc ^ (rr & 7);
        gload16(Bt + (size_t)rr * CC + kb + ch * 8, &Bs[rr][sc * 8]);
      }
      __syncthreads();
      #pragma unroll
      for (int ks = 0; ks < 2; ks++) {
        s16x8 af[4], bf[3];
        #pragma unroll
        for (int i = 0; i < 4; i++)
          af[i] = *(const s16x8*)&As[wr * 64 + i * 16 + lr][8 * ((ks * 4 + lg) ^ (lr & 7))];
        #pragma unroll
        for (int j = 0; j < 3; j++)
          bf[j] = *(const s16x8*)&Bs[wc * 48 + j * 16 + lr][8 * ((ks * 4 + lg) ^ (lr & 7))];
        #pragma unroll
        for (int i = 0; i < 4; i++)
          #pragma unroll
          for (int j = 0; j < 3; j++)
            acc[i][j] = __builtin_amdgcn_mfma_f32_16x16x32_bf16(af[i], bf[j], acc[i][j], 0, 0, 0);
      }
    }
    #pragma unroll
    for (int i = 0; i < 4; i++)
      #pragma unroll
      for (int reg = 0; reg < 4; reg++) {
        int rr = wr * 64 + i * 16 + lg * 4 + reg;
        if (t0 + rr < cnt) {
          int tok = tok_s[rr];
          u16* qp = qall + (size_t)tok * EC + e * HD + wc * 48;
          #pragma unroll
          for (int j = 0; j < 3; j++)
            qp[j * 16 + lr] = f2b(acc[i][j][reg]);
        }
      }
  }
}

// ---- flash attention: 32x32x16 MFMA, 4 waves = 4 heads (z splits 8 heads) ----
// blockIdx.z==0 blocks also zero-fill the 16 unselected expert slots of z.
__global__ __launch_bounds__(256, 2) void attn_kernel(
    const u16* __restrict__ qall, const u16* __restrict__ kvbk,
    const u16* __restrict__ vtb, const u8* __restrict__ eids,
    const float* __restrict__ gbuf, u16* __restrict__ z)
{
  __shared__ u16 Ks[2][64][128];
  __shared__ u16 Vt[2][96][64];
  int b = blockIdx.y;
  int tok0 = blockIdx.x * 32;
  int t = threadIdx.x;
  int w = t >> 6, l = t & 63;
  int h = blockIdx.z * 4 + w;
  int lo = l & 31, hi = l >> 5;

  s16x8 qf[6];
  {
    int tok = b * NN + tok0 + lo;
    int e = eids[tok * HH + h];
    const u16* qp = qall + (size_t)tok * EC + e * HD + hi * 8;
    #pragma unroll
    for (int ks = 0; ks < 6; ks++)
      qf[ks] = *(const s16x8*)(qp + ks * 16);
  }

  // zero unselected expert slots (z=0 blocks only; disjoint from all writes)
  if (blockIdx.z == 0) {
    int tk = t >> 3, s8 = t & 7;
    int tok = b * NN + tok0 + tk;
    u64 pk = *(const u64*)&eids[(size_t)tok * HH];
    u32 msk = 0;
    #pragma unroll
    for (int hh = 0; hh < 8; hh++) msk |= 1u << ((pk >> (8 * hh)) & 255u);
    u64* zrow = (u64*)(z + (size_t)tok * EC);
    #pragma unroll
    for (int e = 0; e < EE; e++) {
      if (!((msk >> e) & 1u)) {
        u64* p = zrow + e * 24 + s8 * 3;
        p[0] = 0; p[1] = 0; p[2] = 0;
      }
    }
  }

  const u16* kvwin = kvbk + (size_t)(b * NN) * 128;
  const u16* vwin  = vtb + (size_t)(b * NN);

  f32x16 o0 = (f32x16)(0.f), o1 = (f32x16)(0.f), o2 = (f32x16)(0.f);
  float m = -1e30f, lsum = 0.f;   // m in log2 units

  #pragma unroll
  for (int k2 = 0; k2 < 4; k2++) {
    int c = t + k2 * 256;
    gload16(kvwin + c * 8, &Ks[0][0][0] + c * 8);
  }
  #pragma unroll
  for (int k2 = 0; k2 < 3; k2++) {
    int c = t + k2 * 256;
    gload16(vwin + (size_t)(c >> 3) * NT + (c & 7) * 8, &Vt[0][0][0] + c * 8);
  }

  for (int jt = 0; jt < 16; jt++) {
    __syncthreads();
    if (jt < 15) {
      int j0 = (jt + 1) * 64;
      int nb = (jt + 1) & 1;
      const u16* kb_ = kvwin + (size_t)j0 * 128;
      #pragma unroll
      for (int k2 = 0; k2 < 4; k2++) {
        int c = t + k2 * 256;
        gload16(kb_ + c * 8, &Ks[nb][0][0] + c * 8);
      }
      const u16* vb_ = vwin + j0;
      #pragma unroll
      for (int k2 = 0; k2 < 3; k2++) {
        int c = t + k2 * 256;
        gload16(vb_ + (size_t)(c >> 3) * NT + (c & 7) * 8, &Vt[nb][0][0] + c * 8);
      }
    }
    int buf = jt & 1;

    f32x16 s0 = (f32x16)(0.f), s1 = (f32x16)(0.f);
    #pragma unroll
    for (int ks = 0; ks < 6; ks++) {
      int pos = 8 * ((2 * ks + hi) ^ (lo & 7));
      s16x8 a0 = *(const s16x8*)&Ks[buf][lo][pos];
      s16x8 a1 = *(const s16x8*)&Ks[buf][32 + lo][pos];
      s0 = __builtin_amdgcn_mfma_f32_32x32x16_bf16(a0, qf[ks], s0, 0, 0, 0);
      s1 = __builtin_amdgcn_mfma_f32_32x32x16_bf16(a1, qf[ks], s1, 0, 0, 0);
    }

    float pm = fmaxf(s0[0], s0[1]);
    #pragma unroll
    for (int rg = 2; rg < 16; rg += 2) pm = fmaxf(pm, fmaxf(s0[rg], s0[rg + 1]));
    #pragma unroll
    for (int rg = 0; rg < 16; rg += 2) pm = fmaxf(pm, fmaxf(s1[rg], s1[rg + 1]));
    pm = fmaxf(pm, __shfl_xor(pm, 32));
    pm *= AL2;

    if (!__all(pm - m <= DEFER_THR)) {
      float mn = fmaxf(m, pm);
      float al = fexp2(m - mn);
      m = mn; lsum *= al;
      #pragma unroll
      for (int rg = 0; rg < 16; rg++) {
        int qrow = (rg & 3) + 8 * (rg >> 2) + 4 * hi;
        float alr = __shfl(al, qrow);
        o0[rg] *= alr; o1[rg] *= alr; o2[rg] *= alr;
      }
    }

    float ts = 0.f;
    u32 wpk[2][4][2];
    #pragma unroll
    for (int kb2 = 0; kb2 < 2; kb2++)
      #pragma unroll
      for (int rr = 0; rr < 4; rr++)
        #pragma unroll
        for (int pp = 0; pp < 2; pp++) {
          float sA = kb2 ? s1[rr * 4 + 2 * pp]     : s0[rr * 4 + 2 * pp];
          float sB = kb2 ? s1[rr * 4 + 2 * pp + 1] : s0[rr * 4 + 2 * pp + 1];
          float eA = fexp2(fmaf(sA, AL2, -m));
          float eB = fexp2(fmaf(sB, AL2, -m));
          ts += eA + eB;
          wpk[kb2][rr][pp] = cvtpk(eA, eB);
        }
    lsum += ts;

    s16x8 pa[4];
    #pragma unroll
    for (int ks = 0; ks < 4; ks++) {
      int kb2 = ks >> 1;
      int rlo = (ks & 1) * 2, rhi = rlo + 1;
      u32 own_lo0 = wpk[kb2][rlo][0], own_lo1 = wpk[kb2][rlo][1];
      u32 own_hi0 = wpk[kb2][rhi][0], own_hi1 = wpk[kb2][rhi][1];
      u32 send0 = hi ? own_lo0 : own_hi0;
      u32 send1 = hi ? own_lo1 : own_hi1;
      u32 recv0 = (u32)__shfl_xor((int)send0, 32);
      u32 recv1 = (u32)__shfl_xor((int)send1, 32);
      union { s16x8 v; u32 u[4]; } pu;
      pu.u[0] = hi ? recv0 : own_lo0;
      pu.u[1] = hi ? recv1 : own_lo1;
      pu.u[2] = hi ? own_hi0 : recv0;
      pu.u[3] = hi ? own_hi1 : recv1;
      pa[ks] = pu.v;
    }

    #pragma unroll
    for (int ks = 0; ks < 4; ks++) {
      int pos = 8 * ((2 * ks + hi) ^ (lo & 7));
      s16x8 v0 = *(const s16x8*)&Vt[buf][lo][pos];
      s16x8 v1 = *(const s16x8*)&Vt[buf][32 + lo][pos];
      s16x8 v2 = *(const s16x8*)&Vt[buf][64 + lo][pos];
      o0 = __builtin_amdgcn_mfma_f32_32x32x16_bf16(pa[ks], v0, o0, 0, 0, 0);
      o1 = __builtin_amdgcn_mfma_f32_32x32x16_bf16(pa[ks], v1, o1, 0, 0, 0);
      o2 = __builtin_amdgcn_mfma_f32_32x32x16_bf16(pa[ks], v2, o2, 0, 0, 0);
    }
  }

  float lt = lsum + __shfl_xor(lsum, 32);
  #pragma unroll
  for (int rg = 0; rg < 16; rg++) {
    int qrow = (rg & 3) + 8 * (rg >> 2) + 4 * hi;
    float lv = __shfl(lt, qrow);
    int tok = b * NN + tok0 + qrow;
    int slot = tok * HH + h;
    float scl = gbuf[slot] / lv;
    int e = eids[slot];
    u16* zp = z + (size_t)tok * EC + e * HD + lo;
    zp[0]  = f2b(o0[rg] * scl);
    zp[32] = f2b(o1[rg] * scl);
    zp[64] = f2b(o2[rg] * scl);
  }
}

extern "C" void kernel_launch(void* const* d_in, const int* in_sizes, int n_in,
                              void* d_out, int out_size, void* d_ws, size_t ws_size,
                              hipStream_t stream)
{
  const float* x    = (const float*)d_in[0];
  const float* Wg   = (const float*)d_in[1];
  const float* Win  = (const float*)d_in[2];
  const float* Wout = (const float*)d_in[3];
  const float* Wkv  = (const float*)d_in[4];
  const int*   task = (const int*)d_in[5];
  float* out = (float*)d_out;
  float* ws_f = (float*)d_ws;
  int*   ws_i = (int*)d_ws;
  u8*  eids = (u8*)((char*)d_ws + WS_EID);
  u16* kvbk = (u16*)((char*)d_ws + WS_KVK);
  u16* vtb  = (u16*)((char*)d_ws + WS_VT);
  u16* winT = (u16*)((char*)d_ws + WS_WIN);
  u16* woutT= (u16*)((char*)d_ws + WS_WOUT);
  u16* wkvT = (u16*)((char*)d_ws + WS_WKV);
  u16* qall = (u16*)((char*)d_ws + WS_QA);
  u16* z    = (u16*)((char*)d_ws + WS_Z);
  u16* xb   = (u16*)((char*)d_ws + WS_XB);
  int* bucket = (int*)((char*)d_ws + WS_BUCKET);

  hipMemsetAsync(d_ws, 0, 4096, stream);

  // fused gate (512) + Win/Wout/Wkv transposes (3600): one dispatch
  gate_tr_kernel<<<GATE_NWG + TR1_NWG + TR2_NWG + TR3_NWG, 256, 0, stream>>>(
      x, Wg, task, Win, Wout, Wkv, ws_f, ws_i, eids, xb, bucket,
      winT, woutT, wkvT);

  // fused kvproj (192 blocks) + qproj (1536 blocks): one dispatch
  proj_kernel<<<KVP_NWG + (NT/128) * EE, 256, 0, stream>>>(
      xb, wkvT, winT, ws_i, bucket, kvbk, vtb, qall);

  // z zero-fill folded into attn; xb/bucket dead by attn time.
  attn_kernel<<<dim3(NN/32, BB, 2), 256, 0, stream>>>(qall, kvbk, vtb, eids, ws_f + WS_G/4, z);

  // oproj GEMM (+ aux loss folded into the logical==0 block's epilogue)
  gemm_kernel<128, 64, true><<<dim3(CC/64, NT/128), 256, 0, stream>>>(
      z, woutT, out, NT, CC, EC, ws_f, ws_i);
}